// Round 1
// baseline (1224.259 us; speedup 1.0000x reference)
//
#include <hip/hip_runtime.h>
#include <hip/hip_bf16.h>

// Problem constants (fixed by reference)
#define BB 8
#define LL 4096
#define CC 552      // DIM
#define EE 1104     // EXP
#define DSS 16
#define KT 409      // top-k
#define M1 32768    // B*L
#define M2 3272     // B*KT

// ---------------- w_in' = w_in * norm_w ----------------
__global__ void winp_kernel(const float* __restrict__ w_in, const float* __restrict__ norm_w,
                            float* __restrict__ winp, int n) {
    int i = blockIdx.x * blockDim.x + threadIdx.x;
    if (i < n) winp[i] = w_in[i] * norm_w[i % CC];
}

// ---------------- per-row 1/(rms+eps) ----------------
__global__ __launch_bounds__(256) void rowinv_kernel(const float* __restrict__ x,
                                                     float* __restrict__ inv) {
    __shared__ float red[4];
    int r = blockIdx.x;
    const float* xr = x + (size_t)r * CC;
    float s = 0.f;
    for (int c = threadIdx.x; c < CC; c += 256) { float v = xr[c]; s += v * v; }
#pragma unroll
    for (int o = 32; o > 0; o >>= 1) s += __shfl_down(s, o, 64);
    int wave = threadIdx.x >> 6;
    if ((threadIdx.x & 63) == 0) red[wave] = s;
    __syncthreads();
    if (threadIdx.x == 0) {
        float tot = red[0] + red[1] + red[2] + red[3];
        inv[r] = 1.f / (sqrtf(tot / (float)CC) + 1e-6f);
    }
}

// ---------------- fp32 GEMM  C[m,n] = rowscale[m] * sum_k A[m,k]*B[n,k] + bias[n] ----------------
// 128x128 tile, BK=8, 256 threads, 8x8 per thread. K % 8 == 0 required.
__global__ __launch_bounds__(256) void gemm_abt_kernel(
    const float* __restrict__ A, const float* __restrict__ B, float* __restrict__ C,
    int M, int N, int K, const float* __restrict__ rowscale, const float* __restrict__ bias) {
    __shared__ __align__(16) float As[8][132];
    __shared__ __align__(16) float Bs[8][132];
    const int tid = threadIdx.x;
    const int row0 = blockIdx.x * 128, col0 = blockIdx.y * 128;
    const int tx = tid & 15, ty = tid >> 4;
    const int lr = tid >> 1, lk = (tid & 1) << 2;

    float acc[8][8];
#pragma unroll
    for (int i = 0; i < 8; i++)
#pragma unroll
        for (int j = 0; j < 8; j++) acc[i][j] = 0.f;

    for (int k0 = 0; k0 < K; k0 += 8) {
        float4 va = make_float4(0.f, 0.f, 0.f, 0.f), vb = va;
        int gr = row0 + lr;
        if (gr < M) va = *reinterpret_cast<const float4*>(A + (size_t)gr * K + (k0 + lk));
        int gc = col0 + lr;
        if (gc < N) vb = *reinterpret_cast<const float4*>(B + (size_t)gc * K + (k0 + lk));
        __syncthreads();  // previous tile fully consumed
        As[lk + 0][lr] = va.x; As[lk + 1][lr] = va.y; As[lk + 2][lr] = va.z; As[lk + 3][lr] = va.w;
        Bs[lk + 0][lr] = vb.x; Bs[lk + 1][lr] = vb.y; Bs[lk + 2][lr] = vb.z; Bs[lk + 3][lr] = vb.w;
        __syncthreads();
#pragma unroll
        for (int k = 0; k < 8; k++) {
            float4 a0 = *reinterpret_cast<const float4*>(&As[k][ty * 8]);
            float4 a1 = *reinterpret_cast<const float4*>(&As[k][ty * 8 + 4]);
            float4 b0 = *reinterpret_cast<const float4*>(&Bs[k][tx * 8]);
            float4 b1 = *reinterpret_cast<const float4*>(&Bs[k][tx * 8 + 4]);
            float av[8] = {a0.x, a0.y, a0.z, a0.w, a1.x, a1.y, a1.z, a1.w};
            float bv[8] = {b0.x, b0.y, b0.z, b0.w, b1.x, b1.y, b1.z, b1.w};
#pragma unroll
            for (int i = 0; i < 8; i++)
#pragma unroll
                for (int j = 0; j < 8; j++) acc[i][j] += av[i] * bv[j];
        }
    }
#pragma unroll
    for (int i = 0; i < 8; i++) {
        int gm = row0 + ty * 8 + i;
        if (gm < M) {
            float rs = rowscale ? rowscale[gm] : 1.f;
#pragma unroll
            for (int jj = 0; jj < 2; jj++) {
                int gn = col0 + tx * 8 + jj * 4;
                if (gn < N) {
                    float4 o;
                    o.x = acc[i][jj * 4 + 0] * rs + (bias ? bias[gn + 0] : 0.f);
                    o.y = acc[i][jj * 4 + 1] * rs + (bias ? bias[gn + 1] : 0.f);
                    o.z = acc[i][jj * 4 + 2] * rs + (bias ? bias[gn + 2] : 0.f);
                    o.w = acc[i][jj * 4 + 3] * rs + (bias ? bias[gn + 3] : 0.f);
                    *reinterpret_cast<float4*>(C + (size_t)gm * N + gn) = o;
                }
            }
        }
    }
}

// ---------------- sim'[r] = <xproj[r], center[b]> / max(||xproj[r]||, 1e-12) ----------------
// (divides out ||center|| and softmax: both monotone per batch -> same top-k order)
__global__ __launch_bounds__(256) void sim_kernel(const float* __restrict__ xproj,
                                                  float* __restrict__ sim) {
    __shared__ float redd[4], reds[4];
    int r = blockIdx.x;
    int b = r >> 12;  // L = 4096
    const float* xr = xproj + (size_t)r * EE;
    const float* cr = xproj + ((size_t)(b * LL + LL / 2)) * EE;
    float d = 0.f, ss = 0.f;
    for (int e = threadIdx.x; e < EE; e += 256) {
        float v = xr[e];
        d += v * cr[e];
        ss += v * v;
    }
#pragma unroll
    for (int o = 32; o > 0; o >>= 1) { d += __shfl_down(d, o, 64); ss += __shfl_down(ss, o, 64); }
    int wave = threadIdx.x >> 6;
    if ((threadIdx.x & 63) == 0) { redd[wave] = d; reds[wave] = ss; }
    __syncthreads();
    if (threadIdx.x == 0) {
        float dt = redd[0] + redd[1] + redd[2] + redd[3];
        float st = reds[0] + reds[1] + reds[2] + reds[3];
        sim[r] = dt / fmaxf(sqrtf(st), 1e-12f);
    }
}

// ---------------- top-k via full bitonic sort of (value desc, idx asc) keys ----------------
__global__ __launch_bounds__(1024) void topk_kernel(const float* __restrict__ sim,
                                                    int* __restrict__ idx) {
    __shared__ unsigned long long keys[4096];
    const int b = blockIdx.x;
    for (int i = threadIdx.x; i < 4096; i += 1024) {
        unsigned u = __float_as_uint(sim[b * 4096 + i]);
        u = (u & 0x80000000u) ? ~u : (u | 0x80000000u);  // ascending-sortable float bits
        keys[i] = ((unsigned long long)(~u) << 32) | (unsigned)i; // asc key64 = desc value, asc idx
    }
    __syncthreads();
    for (int size = 2; size <= 4096; size <<= 1) {
        for (int stride = size >> 1; stride > 0; stride >>= 1) {
#pragma unroll 1
            for (int t = threadIdx.x; t < 2048; t += 1024) {
                int low = t & (stride - 1);
                int pos = ((t - low) << 1) + low;
                bool up = ((pos & size) == 0);
                unsigned long long ka = keys[pos], kb = keys[pos + stride];
                if ((ka > kb) == up) { keys[pos] = kb; keys[pos + stride] = ka; }
            }
            __syncthreads();
        }
    }
    for (int t = threadIdx.x; t < KT; t += 1024) idx[b * KT + t] = (int)(keys[t] & 0xffffffffu);
}

// ---------------- gather top-k rows + depthwise causal conv (len 4) ----------------
__global__ __launch_bounds__(256) void gatherconv_kernel(const float* __restrict__ xproj,
                                                         const int* __restrict__ idx,
                                                         const float* __restrict__ conv_w,
                                                         float* __restrict__ xconv) {
    int t = blockIdx.x, b = blockIdx.y;
    int rows[4];
#pragma unroll
    for (int j = 0; j < 4; j++) {
        int tt = t - 3 + j;
        rows[j] = (tt >= 0) ? idx[b * KT + tt] : -1;
    }
    for (int e = threadIdx.x; e < EE; e += 256) {
        float s = 0.f;
#pragma unroll
        for (int j = 0; j < 4; j++) {
            if (rows[j] >= 0)
                s += conv_w[e * 4 + j] * xproj[((size_t)(b * LL + rows[j])) * EE + e];
        }
        xconv[((size_t)(b * KT + t)) * EE + e] = s;
    }
}

// ---------------- SSM scan: one thread per (b,e), 16 states in regs ----------------
__global__ __launch_bounds__(256) void scan_kernel(const float* __restrict__ xconv,
                                                   const float* __restrict__ A,
                                                   const float* __restrict__ Bp,
                                                   const float* __restrict__ Cp,
                                                   float* __restrict__ outs) {
    __shared__ float Ash[256];
    __shared__ float sB[16];
    int tid = threadIdx.x;
    Ash[tid] = A[tid];
    if (tid < 16) sB[tid] = 1.f / (1.f + expf(-Bp[tid]));
    __syncthreads();
    int g = blockIdx.x * 256 + tid;
    if (g >= BB * EE) return;
    int b = g / EE, e = g - b * EE;
    float sC[16];
#pragma unroll
    for (int s = 0; s < 16; s++) sC[s] = 1.f / (1.f + expf(-Cp[e * 16 + s]));
    float h[16];
#pragma unroll
    for (int s = 0; s < 16; s++) h[s] = 0.f;
    const float* xc = xconv + (size_t)b * KT * EE + e;
    float* yo = outs + (size_t)b * KT * EE + e;
    for (int t = 0; t < KT; t++) {
        float xv = xc[(size_t)t * EE];
        float hn[16];
#pragma unroll
        for (int s = 0; s < 16; s++) {
            float a = sB[s] * xv;
#pragma unroll
            for (int s2 = 0; s2 < 16; s2++) a += Ash[s * 16 + s2] * h[s2];
            hn[s] = a;
        }
        float y = 0.f;
#pragma unroll
        for (int s = 0; s < 16; s++) { h[s] = hn[s]; y += hn[s] * sC[s]; }
        yo[(size_t)t * EE] = y;
    }
}

// ---------------- out = x (copy), then scatter-add x_proc rows ----------------
__global__ void copy4_kernel(const float4* __restrict__ src, float4* __restrict__ dst, int n4) {
    int i = blockIdx.x * blockDim.x + threadIdx.x;
    int stride = gridDim.x * blockDim.x;
    for (; i < n4; i += stride) dst[i] = src[i];
}

__global__ __launch_bounds__(256) void scatter_kernel(const float* __restrict__ xproc,
                                                      const int* __restrict__ idx,
                                                      float* __restrict__ out) {
    int t = blockIdx.x, b = blockIdx.y;
    int row = idx[b * KT + t];
    const float* src = xproc + ((size_t)(b * KT + t)) * CC;
    float* dst = out + ((size_t)(b * LL + row)) * CC;
    for (int d = threadIdx.x; d < CC; d += 256) dst[d] += src[d];
}

extern "C" void kernel_launch(void* const* d_in, const int* in_sizes, int n_in,
                              void* d_out, int out_size, void* d_ws, size_t ws_size,
                              hipStream_t stream) {
    const float* x      = (const float*)d_in[0];
    const float* norm_w = (const float*)d_in[1];
    const float* w_in   = (const float*)d_in[2];
    const float* b_in   = (const float*)d_in[3];
    const float* w_out  = (const float*)d_in[4];
    const float* b_out  = (const float*)d_in[5];
    const float* Amat   = (const float*)d_in[6];
    const float* Bp     = (const float*)d_in[7];
    const float* Cp     = (const float*)d_in[8];
    const float* conv_w = (const float*)d_in[9];
    float* out = (float*)d_out;

    char* wsb = (char*)d_ws;
    size_t off = 0;
    auto take = [&](size_t bytes) {
        void* p = wsb + off;
        off += (bytes + 255) & ~(size_t)255;
        return p;
    };
    float* xproj = (float*)take((size_t)M1 * EE * 4);   // 144.7 MB
    float* winp  = (float*)take((size_t)EE * CC * 4);
    float* inv   = (float*)take((size_t)M1 * 4);
    float* simv  = (float*)take((size_t)M1 * 4);
    int*   idxb  = (int*)take((size_t)BB * KT * 4);
    float* xconv = (float*)take((size_t)BB * KT * EE * 4);
    float* outsb = (float*)take((size_t)BB * KT * EE * 4);
    float* xproc = (float*)take((size_t)BB * KT * CC * 4);
    (void)ws_size;

    winp_kernel<<<(EE * CC + 255) / 256, 256, 0, stream>>>(w_in, norm_w, winp, EE * CC);
    rowinv_kernel<<<M1, 256, 0, stream>>>(x, inv);

    dim3 g1(M1 / 128, (EE + 127) / 128);  // 256 x 9
    gemm_abt_kernel<<<g1, 256, 0, stream>>>(x, winp, xproj, M1, EE, CC, inv, b_in);

    sim_kernel<<<M1, 256, 0, stream>>>(xproj, simv);
    topk_kernel<<<BB, 1024, 0, stream>>>(simv, idxb);

    dim3 g2(KT, BB);
    gatherconv_kernel<<<g2, 256, 0, stream>>>(xproj, idxb, conv_w, xconv);

    scan_kernel<<<(BB * EE + 255) / 256, 256, 0, stream>>>(xconv, Amat, Bp, Cp, outsb);

    dim3 g3((M2 + 127) / 128, (CC + 127) / 128);  // 26 x 5
    gemm_abt_kernel<<<g3, 256, 0, stream>>>(outsb, w_out, xproc, M2, CC, EE, nullptr, b_out);

    copy4_kernel<<<2048, 256, 0, stream>>>((const float4*)x, (float4*)out, out_size / 4);
    scatter_kernel<<<g2, 256, 0, stream>>>(xproc, idxb, out);
}

// Round 3
// 1223.367 us; speedup vs baseline: 1.0007x; 1.0007x over previous
//
#include <hip/hip_runtime.h>
#include <hip/hip_bf16.h>

// Problem constants (fixed by reference)
#define BB 8
#define LL 4096
#define CC 552      // DIM
#define EE 1104     // EXP
#define KT 409      // top-k
#define M1 32768    // B*L
#define M2 3272     // B*KT
#define KP 576      // K padded to multiple of 32
#define CHUNK 8192
#define NCH 4

typedef __attribute__((ext_vector_type(8))) short bf16x8;
typedef __attribute__((ext_vector_type(4))) float f32x4;

__device__ __forceinline__ ushort f2bf(float f) {
    unsigned u = __float_as_uint(f);
    return (ushort)((u + 0x7FFFu + ((u >> 16) & 1u)) >> 16);  // RNE
}
__device__ __forceinline__ float bf2f(ushort h) {
    return __uint_as_float(((unsigned)h) << 16);
}

// ---------- W' = w_in * norm_w (fp32, materialized; feeds convw + gram) ----------
__global__ void winp_kernel(const float* __restrict__ w_in, const float* __restrict__ norm_w,
                            float* __restrict__ winp, int n) {
    int i = blockIdx.x * blockDim.x + threadIdx.x;
    if (i < n) winp[i] = w_in[i] * norm_w[i % CC];
}

// ---------- convert x rows -> bf16 hi/lo (K padded to 576) + fused 1/(rms+eps) ----------
__global__ __launch_bounds__(256) void convx_kernel(const float* __restrict__ x, int r0,
                                                    ushort* __restrict__ xh, ushort* __restrict__ xl,
                                                    float* __restrict__ inv) {
    __shared__ float red[4];
    const int r = r0 + blockIdx.x;
    const float* xr = x + (size_t)r * CC;
    ushort* oh = xh + (size_t)blockIdx.x * KP;
    ushort* ol = xl + (size_t)blockIdx.x * KP;
    const int t = threadIdx.x;
    float s = 0.f;
    if (t < 144) {  // 144 chunks of 4 = 576; first 138 are real data (552)
        float4 v = make_float4(0.f, 0.f, 0.f, 0.f);
        if (t < 138) v = reinterpret_cast<const float4*>(xr)[t];
        s = v.x * v.x + v.y * v.y + v.z * v.z + v.w * v.w;
        ushort4 h, l;
        h.x = f2bf(v.x); l.x = f2bf(v.x - bf2f(h.x));
        h.y = f2bf(v.y); l.y = f2bf(v.y - bf2f(h.y));
        h.z = f2bf(v.z); l.z = f2bf(v.z - bf2f(h.z));
        h.w = f2bf(v.w); l.w = f2bf(v.w - bf2f(h.w));
        reinterpret_cast<ushort4*>(oh)[t] = h;
        reinterpret_cast<ushort4*>(ol)[t] = l;
    }
#pragma unroll
    for (int o = 32; o > 0; o >>= 1) s += __shfl_down(s, o, 64);
    if ((t & 63) == 0) red[t >> 6] = s;
    __syncthreads();
    if (t == 0) {
        float tot = red[0] + red[1] + red[2] + red[3];
        inv[r] = 1.f / (sqrtf(tot / (float)CC) + 1e-6f);
    }
}

// ---------- convert W' rows -> bf16 hi/lo (K padded) ----------
__global__ __launch_bounds__(256) void convw_kernel(const float* __restrict__ winp,
                                                    ushort* __restrict__ wh, ushort* __restrict__ wl) {
    const int n = blockIdx.x, t = threadIdx.x;
    if (t >= 144) return;
    float4 v = make_float4(0.f, 0.f, 0.f, 0.f);
    if (t < 138) v = reinterpret_cast<const float4*>(winp + (size_t)n * CC)[t];
    ushort4 h, l;
    h.x = f2bf(v.x); l.x = f2bf(v.x - bf2f(h.x));
    h.y = f2bf(v.y); l.y = f2bf(v.y - bf2f(h.y));
    h.z = f2bf(v.z); l.z = f2bf(v.z - bf2f(h.z));
    h.w = f2bf(v.w); l.w = f2bf(v.w - bf2f(h.w));
    reinterpret_cast<ushort4*>(wh + (size_t)n * KP)[t] = h;
    reinterpret_cast<ushort4*>(wl + (size_t)n * KP)[t] = l;
}

// ---------- split-bf16 MFMA GEMM: C[m,n] = inv[m] * sum_k A[m,k]*B[n,k] + bias[n] ----------
// 128x128 tile, BK=32, 4 waves each 64x64 (4x4 frags of 16x16x32), 3 MFMA per frag pair.
__global__ __launch_bounds__(256) void gemm1_mfma(
    const ushort* __restrict__ Ah, const ushort* __restrict__ Al,   // [CHUNK][KP]
    const ushort* __restrict__ Bh, const ushort* __restrict__ Bl,   // [EE][KP]
    const float* __restrict__ inv, const float* __restrict__ bias,
    float* __restrict__ C, int r0) {
    __shared__ ushort As_h[128][40];
    __shared__ ushort As_l[128][40];
    __shared__ ushort Bs_h[128][40];
    __shared__ ushort Bs_l[128][40];
    const int tid = threadIdx.x;
    const int col0 = blockIdx.x * 128;     // over EE (last tile partial: 1104..1151 masked)
    const int row0 = blockIdx.y * 128;     // local row within chunk
    const int wave = tid >> 6, lane = tid & 63;
    const int wr = (wave >> 1) * 64, wc = (wave & 1) * 64;
    const int sr = tid >> 2, sk = (tid & 3) * 8;   // staging: row, k-offset (halfs)
    const int lrow = lane & 15, kb = (lane >> 4) * 8;

    f32x4 acc[4][4];
    const f32x4 zero = {0.f, 0.f, 0.f, 0.f};
#pragma unroll
    for (int i = 0; i < 4; i++)
#pragma unroll
        for (int j = 0; j < 4; j++) acc[i][j] = zero;

    const int4 zi4 = make_int4(0, 0, 0, 0);
    for (int k0 = 0; k0 < KP; k0 += 32) {
        int4 vah0 = *reinterpret_cast<const int4*>(Ah + (size_t)(row0 + sr) * KP + k0 + sk);
        int4 vah1 = *reinterpret_cast<const int4*>(Ah + (size_t)(row0 + sr + 64) * KP + k0 + sk);
        int4 val0 = *reinterpret_cast<const int4*>(Al + (size_t)(row0 + sr) * KP + k0 + sk);
        int4 val1 = *reinterpret_cast<const int4*>(Al + (size_t)(row0 + sr + 64) * KP + k0 + sk);
        int4 vbh0 = (col0 + sr < EE)
                        ? *reinterpret_cast<const int4*>(Bh + (size_t)(col0 + sr) * KP + k0 + sk) : zi4;
        int4 vbh1 = (col0 + sr + 64 < EE)
                        ? *reinterpret_cast<const int4*>(Bh + (size_t)(col0 + sr + 64) * KP + k0 + sk) : zi4;
        int4 vbl0 = (col0 + sr < EE)
                        ? *reinterpret_cast<const int4*>(Bl + (size_t)(col0 + sr) * KP + k0 + sk) : zi4;
        int4 vbl1 = (col0 + sr + 64 < EE)
                        ? *reinterpret_cast<const int4*>(Bl + (size_t)(col0 + sr + 64) * KP + k0 + sk) : zi4;
        __syncthreads();  // previous tile fully consumed
        *reinterpret_cast<int4*>(&As_h[sr][sk]) = vah0;
        *reinterpret_cast<int4*>(&As_h[sr + 64][sk]) = vah1;
        *reinterpret_cast<int4*>(&As_l[sr][sk]) = val0;
        *reinterpret_cast<int4*>(&As_l[sr + 64][sk]) = val1;
        *reinterpret_cast<int4*>(&Bs_h[sr][sk]) = vbh0;
        *reinterpret_cast<int4*>(&Bs_h[sr + 64][sk]) = vbh1;
        *reinterpret_cast<int4*>(&Bs_l[sr][sk]) = vbl0;
        *reinterpret_cast<int4*>(&Bs_l[sr + 64][sk]) = vbl1;
        __syncthreads();
        bf16x8 ah[4], al[4], bh[4], bl[4];
#pragma unroll
        for (int i = 0; i < 4; i++) {
            ah[i] = *reinterpret_cast<const bf16x8*>(&As_h[wr + i * 16 + lrow][kb]);
            al[i] = *reinterpret_cast<const bf16x8*>(&As_l[wr + i * 16 + lrow][kb]);
            bh[i] = *reinterpret_cast<const bf16x8*>(&Bs_h[wc + i * 16 + lrow][kb]);
            bl[i] = *reinterpret_cast<const bf16x8*>(&Bs_l[wc + i * 16 + lrow][kb]);
        }
#pragma unroll
        for (int i = 0; i < 4; i++)
#pragma unroll
            for (int j = 0; j < 4; j++) {
                acc[i][j] = __builtin_amdgcn_mfma_f32_16x16x32_bf16(ah[i], bh[j], acc[i][j], 0, 0, 0);
                acc[i][j] = __builtin_amdgcn_mfma_f32_16x16x32_bf16(ah[i], bl[j], acc[i][j], 0, 0, 0);
                acc[i][j] = __builtin_amdgcn_mfma_f32_16x16x32_bf16(al[i], bh[j], acc[i][j], 0, 0, 0);
            }
    }
    // epilogue: C/D layout col=lane&15, row=(lane>>4)*4+reg  [m89-verified]
#pragma unroll
    for (int i = 0; i < 4; i++) {
        const int gmb = r0 + row0 + wr + i * 16 + (lane >> 4) * 4;
#pragma unroll
        for (int reg = 0; reg < 4; reg++) {
            const int gm = gmb + reg;
            const float rs = inv[gm];
#pragma unroll
            for (int j = 0; j < 4; j++) {
                const int gn = col0 + wc + j * 16 + lrow;
                if (gn < EE) C[(size_t)gm * EE + gn] = acc[i][j][reg] * rs + bias[gn];
            }
        }
    }
}

// ---------- g_b = W'^T (W' (x_center * inv_center)) in fp64, one block per batch ----------
__global__ __launch_bounds__(256) void gram_kernel(const float* __restrict__ x,
                                                   const float* __restrict__ winp,
                                                   double* __restrict__ g) {
    __shared__ double t1[EE];
    __shared__ double xcn[CC];
    __shared__ double red[4];
    const int b = blockIdx.x, tid = threadIdx.x;
    const float* xc = x + ((size_t)(b * LL + LL / 2)) * CC;
    double s = 0.0;
    for (int c = tid; c < CC; c += 256) { double v = xc[c]; s += v * v; }
#pragma unroll
    for (int o = 32; o > 0; o >>= 1) s += __shfl_down(s, o, 64);
    if ((tid & 63) == 0) red[tid >> 6] = s;
    __syncthreads();
    const double tot = red[0] + red[1] + red[2] + red[3];
    const double invc = 1.0 / (sqrt(tot / (double)CC) + 1e-6);
    for (int c = tid; c < CC; c += 256) xcn[c] = (double)xc[c] * invc;
    __syncthreads();
    for (int e = tid; e < EE; e += 256) {
        const float* wr = winp + (size_t)e * CC;
        double a = 0.0;
        for (int c = 0; c < CC; c++) a += (double)wr[c] * xcn[c];
        t1[e] = a;
    }
    __syncthreads();
    for (int c = tid; c < CC; c += 256) {
        double a = 0.0;
        for (int e = 0; e < EE; e++) a += (double)winp[(size_t)e * CC + c] * t1[e];
        g[(size_t)b * CC + c] = a;
    }
}

// ---------- sim_r = inv_r * <x_r, g_b> / ||xproj_r||  (fp64 numerator; norm multiplicative) ----------
__global__ __launch_bounds__(256) void dotsim_kernel(const float* __restrict__ x,
                                                     const double* __restrict__ g,
                                                     const float* __restrict__ xproj,
                                                     const float* __restrict__ inv,
                                                     float* __restrict__ sim) {
    __shared__ double redd[4];
    __shared__ float redn[4];
    const int r = blockIdx.x, tid = threadIdx.x;
    const int b = r >> 12;
    const float* xr = x + (size_t)r * CC;
    const double* gb = g + (size_t)b * CC;
    double d = 0.0;
    for (int c = tid; c < CC; c += 256) d += (double)xr[c] * gb[c];
    const float* pr = xproj + (size_t)r * EE;
    float ns = 0.f;
    for (int e = tid; e < EE; e += 256) { float v = pr[e]; ns += v * v; }
#pragma unroll
    for (int o = 32; o > 0; o >>= 1) { d += __shfl_down(d, o, 64); ns += __shfl_down(ns, o, 64); }
    if ((tid & 63) == 0) { redd[tid >> 6] = d; redn[tid >> 6] = ns; }
    __syncthreads();
    if (tid == 0) {
        double dt = redd[0] + redd[1] + redd[2] + redd[3];
        double nt = (double)(redn[0] + redn[1] + redn[2] + redn[3]);
        sim[r] = (float)((double)inv[r] * dt / sqrt(fmax(nt, 1e-24)));
    }
}

// ---------------- top-k via full bitonic sort of (value desc, idx asc) keys ----------------
__global__ __launch_bounds__(1024) void topk_kernel(const float* __restrict__ sim,
                                                    int* __restrict__ idx) {
    __shared__ unsigned long long keys[4096];
    const int b = blockIdx.x;
    for (int i = threadIdx.x; i < 4096; i += 1024) {
        unsigned u = __float_as_uint(sim[b * 4096 + i]);
        u = (u & 0x80000000u) ? ~u : (u | 0x80000000u);
        keys[i] = ((unsigned long long)(~u) << 32) | (unsigned)i;
    }
    __syncthreads();
    for (int size = 2; size <= 4096; size <<= 1) {
        for (int stride = size >> 1; stride > 0; stride >>= 1) {
#pragma unroll 1
            for (int t = threadIdx.x; t < 2048; t += 1024) {
                int low = t & (stride - 1);
                int pos = ((t - low) << 1) + low;
                bool up = ((pos & size) == 0);
                unsigned long long ka = keys[pos], kb = keys[pos + stride];
                if ((ka > kb) == up) { keys[pos] = kb; keys[pos + stride] = ka; }
            }
            __syncthreads();
        }
    }
    for (int t = threadIdx.x; t < KT; t += 1024) idx[b * KT + t] = (int)(keys[t] & 0xffffffffu);
}

// ---------------- gather top-k rows + depthwise causal conv (len 4) ----------------
__global__ __launch_bounds__(256) void gatherconv_kernel(const float* __restrict__ xproj,
                                                         const int* __restrict__ idx,
                                                         const float* __restrict__ conv_w,
                                                         float* __restrict__ xconv) {
    int t = blockIdx.x, b = blockIdx.y;
    int rows[4];
#pragma unroll
    for (int j = 0; j < 4; j++) {
        int tt = t - 3 + j;
        rows[j] = (tt >= 0) ? idx[b * KT + tt] : -1;
    }
    for (int e = threadIdx.x; e < EE; e += 256) {
        float s = 0.f;
#pragma unroll
        for (int j = 0; j < 4; j++) {
            if (rows[j] >= 0)
                s += conv_w[e * 4 + j] * xproj[((size_t)(b * LL + rows[j])) * EE + e];
        }
        xconv[((size_t)(b * KT + t)) * EE + e] = s;
    }
}

// ---------------- SSM scan: one thread per (b,e), 16 states in regs ----------------
__global__ __launch_bounds__(256) void scan_kernel(const float* __restrict__ xconv,
                                                   const float* __restrict__ A,
                                                   const float* __restrict__ Bp,
                                                   const float* __restrict__ Cp,
                                                   float* __restrict__ outs) {
    __shared__ float Ash[256];
    __shared__ float sB[16];
    int tid = threadIdx.x;
    Ash[tid] = A[tid];
    if (tid < 16) sB[tid] = 1.f / (1.f + expf(-Bp[tid]));
    __syncthreads();
    int g = blockIdx.x * 256 + tid;
    if (g >= BB * EE) return;
    int b = g / EE, e = g - b * EE;
    float sC[16];
#pragma unroll
    for (int s = 0; s < 16; s++) sC[s] = 1.f / (1.f + expf(-Cp[e * 16 + s]));
    float h[16];
#pragma unroll
    for (int s = 0; s < 16; s++) h[s] = 0.f;
    const float* xc = xconv + (size_t)b * KT * EE + e;
    float* yo = outs + (size_t)b * KT * EE + e;
    for (int t = 0; t < KT; t++) {
        float xv = xc[(size_t)t * EE];
        float hn[16];
#pragma unroll
        for (int s = 0; s < 16; s++) {
            float a = sB[s] * xv;
#pragma unroll
            for (int s2 = 0; s2 < 16; s2++) a += Ash[s * 16 + s2] * h[s2];
            hn[s] = a;
        }
        float y = 0.f;
#pragma unroll
        for (int s = 0; s < 16; s++) { h[s] = hn[s]; y += hn[s] * sC[s]; }
        yo[(size_t)t * EE] = y;
    }
}

// ---------------- fp32 GEMM (GEMM2): C[m,n] = sum_k A[m,k]*B[n,k] + bias[n] ----------------
__global__ __launch_bounds__(256) void gemm_abt_kernel(
    const float* __restrict__ A, const float* __restrict__ B, float* __restrict__ C,
    int M, int N, int K, const float* __restrict__ rowscale, const float* __restrict__ bias) {
    __shared__ __align__(16) float As[8][132];
    __shared__ __align__(16) float Bs[8][132];
    const int tid = threadIdx.x;
    const int row0 = blockIdx.x * 128, col0 = blockIdx.y * 128;
    const int tx = tid & 15, ty = tid >> 4;
    const int lr = tid >> 1, lk = (tid & 1) << 2;

    float acc[8][8];
#pragma unroll
    for (int i = 0; i < 8; i++)
#pragma unroll
        for (int j = 0; j < 8; j++) acc[i][j] = 0.f;

    for (int k0 = 0; k0 < K; k0 += 8) {
        float4 va = make_float4(0.f, 0.f, 0.f, 0.f), vb = va;
        int gr = row0 + lr;
        if (gr < M) va = *reinterpret_cast<const float4*>(A + (size_t)gr * K + (k0 + lk));
        int gc = col0 + lr;
        if (gc < N) vb = *reinterpret_cast<const float4*>(B + (size_t)gc * K + (k0 + lk));
        __syncthreads();
        As[lk + 0][lr] = va.x; As[lk + 1][lr] = va.y; As[lk + 2][lr] = va.z; As[lk + 3][lr] = va.w;
        Bs[lk + 0][lr] = vb.x; Bs[lk + 1][lr] = vb.y; Bs[lk + 2][lr] = vb.z; Bs[lk + 3][lr] = vb.w;
        __syncthreads();
#pragma unroll
        for (int k = 0; k < 8; k++) {
            float4 a0 = *reinterpret_cast<const float4*>(&As[k][ty * 8]);
            float4 a1 = *reinterpret_cast<const float4*>(&As[k][ty * 8 + 4]);
            float4 b0 = *reinterpret_cast<const float4*>(&Bs[k][tx * 8]);
            float4 b1 = *reinterpret_cast<const float4*>(&Bs[k][tx * 8 + 4]);
            float av[8] = {a0.x, a0.y, a0.z, a0.w, a1.x, a1.y, a1.z, a1.w};
            float bv[8] = {b0.x, b0.y, b0.z, b0.w, b1.x, b1.y, b1.z, b1.w};
#pragma unroll
            for (int i = 0; i < 8; i++)
#pragma unroll
                for (int j = 0; j < 8; j++) acc[i][j] += av[i] * bv[j];
        }
    }
#pragma unroll
    for (int i = 0; i < 8; i++) {
        int gm = row0 + ty * 8 + i;
        if (gm < M) {
            float rs = rowscale ? rowscale[gm] : 1.f;
#pragma unroll
            for (int jj = 0; jj < 2; jj++) {
                int gn = col0 + tx * 8 + jj * 4;
                if (gn < N) {
                    float4 o;
                    o.x = acc[i][jj * 4 + 0] * rs + (bias ? bias[gn + 0] : 0.f);
                    o.y = acc[i][jj * 4 + 1] * rs + (bias ? bias[gn + 1] : 0.f);
                    o.z = acc[i][jj * 4 + 2] * rs + (bias ? bias[gn + 2] : 0.f);
                    o.w = acc[i][jj * 4 + 3] * rs + (bias ? bias[gn + 3] : 0.f);
                    *reinterpret_cast<float4*>(C + (size_t)gm * N + gn) = o;
                }
            }
        }
    }
}

// ---------------- out = x (copy), then scatter-add x_proc rows ----------------
__global__ void copy4_kernel(const float4* __restrict__ src, float4* __restrict__ dst, int n4) {
    int i = blockIdx.x * blockDim.x + threadIdx.x;
    int stride = gridDim.x * blockDim.x;
    for (; i < n4; i += stride) dst[i] = src[i];
}

__global__ __launch_bounds__(256) void scatter_kernel(const float* __restrict__ xproc,
                                                      const int* __restrict__ idx,
                                                      float* __restrict__ out) {
    int t = blockIdx.x, b = blockIdx.y;
    int row = idx[b * KT + t];
    const float* src = xproc + ((size_t)(b * KT + t)) * CC;
    float* dst = out + ((size_t)(b * LL + row)) * CC;
    for (int d = threadIdx.x; d < CC; d += 256) dst[d] += src[d];
}

extern "C" void kernel_launch(void* const* d_in, const int* in_sizes, int n_in,
                              void* d_out, int out_size, void* d_ws, size_t ws_size,
                              hipStream_t stream) {
    const float* x      = (const float*)d_in[0];
    const float* norm_w = (const float*)d_in[1];
    const float* w_in   = (const float*)d_in[2];
    const float* b_in   = (const float*)d_in[3];
    const float* w_out  = (const float*)d_in[4];
    const float* b_out  = (const float*)d_in[5];
    const float* Amat   = (const float*)d_in[6];
    const float* Bp     = (const float*)d_in[7];
    const float* Cp     = (const float*)d_in[8];
    const float* conv_w = (const float*)d_in[9];
    float* out = (float*)d_out;

    char* wsb = (char*)d_ws;
    size_t off = 0;
    auto take = [&](size_t bytes) {
        void* p = wsb + off;
        off += (bytes + 255) & ~(size_t)255;
        return p;
    };
    float*  xproj = (float*)take((size_t)M1 * EE * 4);      // 144.7 MB
    float*  winp  = (float*)take((size_t)EE * CC * 4);      // 2.44 MB
    ushort* wh    = (ushort*)take((size_t)EE * KP * 2);     // 1.27 MB
    ushort* wl    = (ushort*)take((size_t)EE * KP * 2);
    float*  inv   = (float*)take((size_t)M1 * 4);
    float*  simv  = (float*)take((size_t)M1 * 4);
    int*    idxb  = (int*)take((size_t)BB * KT * 4);
    double* gbuf  = (double*)take((size_t)BB * CC * 8);     // 35 KB
    size_t ovl = off;
    ushort* xh    = (ushort*)take((size_t)CHUNK * KP * 2);  // 9.44 MB (per-chunk, dead after gemm1)
    ushort* xl    = (ushort*)take((size_t)CHUNK * KP * 2);
    off = ovl;  // overlay: conv/scan buffers reuse the xh/xl region
    float* xconv = (float*)take((size_t)BB * KT * EE * 4);  // 14.45 MB
    float* outsb = (float*)take((size_t)BB * KT * EE * 4);
    float* xproc = (float*)take((size_t)BB * KT * CC * 4);
    (void)ws_size; (void)b_in;

    winp_kernel<<<(EE * CC + 255) / 256, 256, 0, stream>>>(w_in, norm_w, winp, EE * CC);
    convw_kernel<<<EE, 256, 0, stream>>>(winp, wh, wl);
    for (int c = 0; c < NCH; c++) {
        convx_kernel<<<CHUNK, 256, 0, stream>>>(x, c * CHUNK, xh, xl, inv);
        dim3 g1(9, CHUNK / 128);
        gemm1_mfma<<<g1, 256, 0, stream>>>(xh, xl, wh, wl, inv, (const float*)d_in[3], xproj, c * CHUNK);
    }

    gram_kernel<<<BB, 256, 0, stream>>>(x, winp, gbuf);
    dotsim_kernel<<<M1, 256, 0, stream>>>(x, gbuf, xproj, inv, simv);
    topk_kernel<<<BB, 1024, 0, stream>>>(simv, idxb);

    dim3 g2(KT, BB);
    gatherconv_kernel<<<g2, 256, 0, stream>>>(xproj, idxb, conv_w, xconv);

    scan_kernel<<<(BB * EE + 255) / 256, 256, 0, stream>>>(xconv, Amat, Bp, Cp, outsb);

    dim3 g3((M2 + 127) / 128, (CC + 127) / 128);
    gemm_abt_kernel<<<g3, 256, 0, stream>>>(outsb, w_out, xproc, M2, CC, EE, nullptr, b_out);

    copy4_kernel<<<2048, 256, 0, stream>>>((const float4*)x, (float4*)out, out_size / 4);
    scatter_kernel<<<g2, 256, 0, stream>>>(xproc, idxb, out);
}

// Round 4
// 782.186 us; speedup vs baseline: 1.5652x; 1.5640x over previous
//
#include <hip/hip_runtime.h>
#include <hip/hip_bf16.h>

// Problem constants (fixed by reference)
#define BB 8
#define LL 4096
#define CC 552      // DIM
#define EE 1104     // EXP
#define KT 409      // top-k
#define M1 32768    // B*L
#define M2 3272     // B*KT
#define KP 576      // K padded (gemm1)
#define KP2 1120    // K padded (gemm2)
#define M2P 3328    // M2 padded to 26*128
#define NP2 640     // CC padded to 5*128
#define JT 16       // SSM truncation taps (||A||^16 ~ 2e-13)
#define CHUNK 8192
#define NCH 4

typedef __attribute__((ext_vector_type(8))) short bf16x8;
typedef __attribute__((ext_vector_type(4))) float f32x4;

__device__ __forceinline__ ushort f2bf(float f) {
    unsigned u = __float_as_uint(f);
    return (ushort)((u + 0x7FFFu + ((u >> 16) & 1u)) >> 16);  // RNE
}
__device__ __forceinline__ float bf2f(ushort h) {
    return __uint_as_float(((unsigned)h) << 16);
}

// ---------- W' = w_in * norm_w (fp32; feeds convw + gram) ----------
__global__ void winp_kernel(const float* __restrict__ w_in, const float* __restrict__ norm_w,
                            float* __restrict__ winp, int n) {
    int i = blockIdx.x * blockDim.x + threadIdx.x;
    if (i < n) winp[i] = w_in[i] * norm_w[i % CC];
}

// ---------- convert x rows -> bf16 hi/lo (K padded to 576) + fused 1/(rms+eps) ----------
__global__ __launch_bounds__(256) void convx_kernel(const float* __restrict__ x, int r0,
                                                    ushort* __restrict__ xh, ushort* __restrict__ xl,
                                                    float* __restrict__ inv) {
    __shared__ float red[4];
    const int r = r0 + blockIdx.x;
    const float* xr = x + (size_t)r * CC;
    ushort* oh = xh + (size_t)blockIdx.x * KP;
    ushort* ol = xl + (size_t)blockIdx.x * KP;
    const int t = threadIdx.x;
    float s = 0.f;
    if (t < 144) {
        float4 v = make_float4(0.f, 0.f, 0.f, 0.f);
        if (t < 138) v = reinterpret_cast<const float4*>(xr)[t];
        s = v.x * v.x + v.y * v.y + v.z * v.z + v.w * v.w;
        ushort4 h, l;
        h.x = f2bf(v.x); l.x = f2bf(v.x - bf2f(h.x));
        h.y = f2bf(v.y); l.y = f2bf(v.y - bf2f(h.y));
        h.z = f2bf(v.z); l.z = f2bf(v.z - bf2f(h.z));
        h.w = f2bf(v.w); l.w = f2bf(v.w - bf2f(h.w));
        reinterpret_cast<ushort4*>(oh)[t] = h;
        reinterpret_cast<ushort4*>(ol)[t] = l;
    }
#pragma unroll
    for (int o = 32; o > 0; o >>= 1) s += __shfl_down(s, o, 64);
    if ((t & 63) == 0) red[t >> 6] = s;
    __syncthreads();
    if (t == 0) {
        float tot = red[0] + red[1] + red[2] + red[3];
        inv[r] = 1.f / (sqrtf(tot / (float)CC) + 1e-6f);
    }
}

// ---------- convert W' rows -> bf16 hi/lo, rows zero-padded to 1152 ----------
__global__ __launch_bounds__(256) void convw_kernel(const float* __restrict__ winp,
                                                    ushort* __restrict__ wh, ushort* __restrict__ wl) {
    const int n = blockIdx.x, t = threadIdx.x;
    if (t >= 144) return;
    float4 v = make_float4(0.f, 0.f, 0.f, 0.f);
    if (n < EE && t < 138) v = reinterpret_cast<const float4*>(winp + (size_t)n * CC)[t];
    ushort4 h, l;
    h.x = f2bf(v.x); l.x = f2bf(v.x - bf2f(h.x));
    h.y = f2bf(v.y); l.y = f2bf(v.y - bf2f(h.y));
    h.z = f2bf(v.z); l.z = f2bf(v.z - bf2f(h.z));
    h.w = f2bf(v.w); l.w = f2bf(v.w - bf2f(h.w));
    reinterpret_cast<ushort4*>(wh + (size_t)n * KP)[t] = h;
    reinterpret_cast<ushort4*>(wl + (size_t)n * KP)[t] = l;
}

// ---------- convert w_out rows -> bf16 hi/lo [NP2=640][KP2=1120], zero-padded ----------
__global__ __launch_bounds__(256) void w2conv_kernel(const float* __restrict__ w_out,
                                                     ushort* __restrict__ wh, ushort* __restrict__ wl) {
    const int n = blockIdx.x, t = threadIdx.x;
    for (int i = t; i < KP2 / 4; i += 256) {
        float4 v = make_float4(0.f, 0.f, 0.f, 0.f);
        if (n < CC && i < EE / 4) v = reinterpret_cast<const float4*>(w_out + (size_t)n * EE)[i];
        ushort4 h, l;
        h.x = f2bf(v.x); l.x = f2bf(v.x - bf2f(h.x));
        h.y = f2bf(v.y); l.y = f2bf(v.y - bf2f(h.y));
        h.z = f2bf(v.z); l.z = f2bf(v.z - bf2f(h.z));
        h.w = f2bf(v.w); l.w = f2bf(v.w - bf2f(h.w));
        reinterpret_cast<ushort4*>(wh + (size_t)n * KP2)[i] = h;
        reinterpret_cast<ushort4*>(wl + (size_t)n * KP2)[i] = l;
    }
}

// ---------- unified split-bf16 MFMA GEMM ----------
// C[gm,gn] = rowscale[gm] * sum_k A[gm,k]*B[gn,k] + bias[gn], operands pre-padded (no staging masks).
__global__ __launch_bounds__(256) void gemm_mfma(
    const ushort* __restrict__ Ah, const ushort* __restrict__ Al,   // [Mp][Kp]
    const ushort* __restrict__ Bh, const ushort* __restrict__ Bl,   // [Np][Kp]
    const float* __restrict__ rowscale, const float* __restrict__ bias,
    float* __restrict__ C, int ldc, int M, int N, int Kp, int r0) {
    __shared__ ushort As_h[128][40];
    __shared__ ushort As_l[128][40];
    __shared__ ushort Bs_h[128][40];
    __shared__ ushort Bs_l[128][40];
    const int tid = threadIdx.x;
    const int col0 = blockIdx.x * 128;
    const int row0 = blockIdx.y * 128;     // local row within A buffer
    const int wave = tid >> 6, lane = tid & 63;
    const int wr = (wave >> 1) * 64, wc = (wave & 1) * 64;
    const int sr = tid >> 2, sk = (tid & 3) * 8;
    const int lrow = lane & 15, kb = (lane >> 4) * 8;

    f32x4 acc[4][4];
    const f32x4 zero = {0.f, 0.f, 0.f, 0.f};
#pragma unroll
    for (int i = 0; i < 4; i++)
#pragma unroll
        for (int j = 0; j < 4; j++) acc[i][j] = zero;

    for (int k0 = 0; k0 < Kp; k0 += 32) {
        int4 vah0 = *reinterpret_cast<const int4*>(Ah + (size_t)(row0 + sr) * Kp + k0 + sk);
        int4 vah1 = *reinterpret_cast<const int4*>(Ah + (size_t)(row0 + sr + 64) * Kp + k0 + sk);
        int4 val0 = *reinterpret_cast<const int4*>(Al + (size_t)(row0 + sr) * Kp + k0 + sk);
        int4 val1 = *reinterpret_cast<const int4*>(Al + (size_t)(row0 + sr + 64) * Kp + k0 + sk);
        int4 vbh0 = *reinterpret_cast<const int4*>(Bh + (size_t)(col0 + sr) * Kp + k0 + sk);
        int4 vbh1 = *reinterpret_cast<const int4*>(Bh + (size_t)(col0 + sr + 64) * Kp + k0 + sk);
        int4 vbl0 = *reinterpret_cast<const int4*>(Bl + (size_t)(col0 + sr) * Kp + k0 + sk);
        int4 vbl1 = *reinterpret_cast<const int4*>(Bl + (size_t)(col0 + sr + 64) * Kp + k0 + sk);
        __syncthreads();
        *reinterpret_cast<int4*>(&As_h[sr][sk]) = vah0;
        *reinterpret_cast<int4*>(&As_h[sr + 64][sk]) = vah1;
        *reinterpret_cast<int4*>(&As_l[sr][sk]) = val0;
        *reinterpret_cast<int4*>(&As_l[sr + 64][sk]) = val1;
        *reinterpret_cast<int4*>(&Bs_h[sr][sk]) = vbh0;
        *reinterpret_cast<int4*>(&Bs_h[sr + 64][sk]) = vbh1;
        *reinterpret_cast<int4*>(&Bs_l[sr][sk]) = vbl0;
        *reinterpret_cast<int4*>(&Bs_l[sr + 64][sk]) = vbl1;
        __syncthreads();
        bf16x8 ah[4], al[4], bh[4], bl[4];
#pragma unroll
        for (int i = 0; i < 4; i++) {
            ah[i] = *reinterpret_cast<const bf16x8*>(&As_h[wr + i * 16 + lrow][kb]);
            al[i] = *reinterpret_cast<const bf16x8*>(&As_l[wr + i * 16 + lrow][kb]);
            bh[i] = *reinterpret_cast<const bf16x8*>(&Bs_h[wc + i * 16 + lrow][kb]);
            bl[i] = *reinterpret_cast<const bf16x8*>(&Bs_l[wc + i * 16 + lrow][kb]);
        }
#pragma unroll
        for (int i = 0; i < 4; i++)
#pragma unroll
            for (int j = 0; j < 4; j++) {
                acc[i][j] = __builtin_amdgcn_mfma_f32_16x16x32_bf16(ah[i], bh[j], acc[i][j], 0, 0, 0);
                acc[i][j] = __builtin_amdgcn_mfma_f32_16x16x32_bf16(ah[i], bl[j], acc[i][j], 0, 0, 0);
                acc[i][j] = __builtin_amdgcn_mfma_f32_16x16x32_bf16(al[i], bh[j], acc[i][j], 0, 0, 0);
            }
    }
    // epilogue: C/D layout col=lane&15, row=(lane>>4)*4+reg  [m89-verified]
#pragma unroll
    for (int i = 0; i < 4; i++) {
        const int gmb = r0 + row0 + wr + i * 16 + (lane >> 4) * 4;
#pragma unroll
        for (int reg = 0; reg < 4; reg++) {
            const int gm = gmb + reg;
            if (gm < M) {
                const float rs = rowscale ? rowscale[gm] : 1.f;
#pragma unroll
                for (int j = 0; j < 4; j++) {
                    const int gn = col0 + wc + j * 16 + lrow;
                    if (gn < N) C[(size_t)gm * ldc + gn] = acc[i][j][reg] * rs + bias[gn];
                }
            }
        }
    }
}

// ---------- g_b = W'^T (W' (x_center * inv_center)) in fp64, one block per batch ----------
__global__ __launch_bounds__(256) void gram_kernel(const float* __restrict__ x,
                                                   const float* __restrict__ winp,
                                                   double* __restrict__ g) {
    __shared__ double t1[EE];
    __shared__ double xcn[CC];
    __shared__ double red[4];
    const int b = blockIdx.x, tid = threadIdx.x;
    const float* xc = x + ((size_t)(b * LL + LL / 2)) * CC;
    double s = 0.0;
    for (int c = tid; c < CC; c += 256) { double v = xc[c]; s += v * v; }
#pragma unroll
    for (int o = 32; o > 0; o >>= 1) s += __shfl_down(s, o, 64);
    if ((tid & 63) == 0) red[tid >> 6] = s;
    __syncthreads();
    const double tot = red[0] + red[1] + red[2] + red[3];
    const double invc = 1.0 / (sqrt(tot / (double)CC) + 1e-6);
    for (int c = tid; c < CC; c += 256) xcn[c] = (double)xc[c] * invc;
    __syncthreads();
    for (int e = tid; e < EE; e += 256) {
        const float* wr = winp + (size_t)e * CC;
        double a = 0.0;
        for (int c = 0; c < CC; c++) a += (double)wr[c] * xcn[c];
        t1[e] = a;
    }
    __syncthreads();
    for (int c = tid; c < CC; c += 256) {
        double a = 0.0;
        for (int e = 0; e < EE; e++) a += (double)winp[(size_t)e * CC + c] * t1[e];
        g[(size_t)b * CC + c] = a;
    }
}

// ---------- sim_r = inv_r * <x_r, g_b> / ||xproj_r|| ----------
__global__ __launch_bounds__(256) void dotsim_kernel(const float* __restrict__ x,
                                                     const double* __restrict__ g,
                                                     const float* __restrict__ xproj,
                                                     const float* __restrict__ inv,
                                                     float* __restrict__ sim) {
    __shared__ double redd[4];
    __shared__ float redn[4];
    const int r = blockIdx.x, tid = threadIdx.x;
    const int b = r >> 12;
    const float* xr = x + (size_t)r * CC;
    const double* gb = g + (size_t)b * CC;
    double d = 0.0;
    for (int c = tid; c < CC; c += 256) d += (double)xr[c] * gb[c];
    const float* pr = xproj + (size_t)r * EE;
    float ns = 0.f;
    for (int e = tid; e < EE; e += 256) { float v = pr[e]; ns += v * v; }
#pragma unroll
    for (int o = 32; o > 0; o >>= 1) { d += __shfl_down(d, o, 64); ns += __shfl_down(ns, o, 64); }
    if ((tid & 63) == 0) { redd[tid >> 6] = d; redn[tid >> 6] = ns; }
    __syncthreads();
    if (tid == 0) {
        double dt = redd[0] + redd[1] + redd[2] + redd[3];
        double nt = (double)(redn[0] + redn[1] + redn[2] + redn[3]);
        sim[r] = (float)((double)inv[r] * dt / sqrt(fmax(nt, 1e-24)));
    }
}

// ---------------- top-k via full bitonic sort of (value desc, idx asc) keys ----------------
__global__ __launch_bounds__(1024) void topk_kernel(const float* __restrict__ sim,
                                                    int* __restrict__ idx) {
    __shared__ unsigned long long keys[4096];
    const int b = blockIdx.x;
    for (int i = threadIdx.x; i < 4096; i += 1024) {
        unsigned u = __float_as_uint(sim[b * 4096 + i]);
        u = (u & 0x80000000u) ? ~u : (u | 0x80000000u);
        keys[i] = ((unsigned long long)(~u) << 32) | (unsigned)i;
    }
    __syncthreads();
    for (int size = 2; size <= 4096; size <<= 1) {
        for (int stride = size >> 1; stride > 0; stride >>= 1) {
#pragma unroll 1
            for (int t = threadIdx.x; t < 2048; t += 1024) {
                int low = t & (stride - 1);
                int pos = ((t - low) << 1) + low;
                bool up = ((pos & size) == 0);
                unsigned long long ka = keys[pos], kb = keys[pos + stride];
                if ((ka > kb) == up) { keys[pos] = kb; keys[pos + stride] = ka; }
            }
            __syncthreads();
        }
    }
    for (int t = threadIdx.x; t < KT; t += 1024) idx[b * KT + t] = (int)(keys[t] & 0xffffffffu);
}

// ---------------- gather top-k rows + depthwise causal conv (len 4) ----------------
__global__ __launch_bounds__(256) void gatherconv_kernel(const float* __restrict__ xproj,
                                                         const int* __restrict__ idx,
                                                         const float* __restrict__ conv_w,
                                                         float* __restrict__ xconv) {
    int t = blockIdx.x, b = blockIdx.y;
    int rows[4];
#pragma unroll
    for (int j = 0; j < 4; j++) {
        int tt = t - 3 + j;
        rows[j] = (tt >= 0) ? idx[b * KT + tt] : -1;
    }
    for (int e = threadIdx.x; e < EE; e += 256) {
        float s = 0.f;
#pragma unroll
        for (int j = 0; j < 4; j++) {
            if (rows[j] >= 0)
                s += conv_w[e * 4 + j] * xproj[((size_t)(b * LL + rows[j])) * EE + e];
        }
        xconv[((size_t)(b * KT + t)) * EE + e] = s;
    }
}

// ---------- SSM taps: ckT[j][e] = sigC[e] . A^j . sigB, j = 0..JT-1 ----------
__global__ __launch_bounds__(256) void ssmtaps_kernel(const float* __restrict__ A,
                                                      const float* __restrict__ Bp,
                                                      const float* __restrict__ Cp,
                                                      float* __restrict__ ckT) {
    __shared__ float Ash[256];
    __shared__ float vmat[JT][16];
    const int t = threadIdx.x;
    Ash[t] = A[t];
    __syncthreads();
    if (t < 16) vmat[0][t] = 1.f / (1.f + expf(-Bp[t]));
    __syncthreads();
    for (int j = 1; j < JT; j++) {
        float nv = 0.f;
        if (t < 16) {
#pragma unroll
            for (int s2 = 0; s2 < 16; s2++) nv += Ash[t * 16 + s2] * vmat[j - 1][s2];
        }
        __syncthreads();
        if (t < 16) vmat[j][t] = nv;
        __syncthreads();
    }
    for (int e = t; e < EE; e += 256) {
        float sc[16];
#pragma unroll
        for (int s = 0; s < 16; s++) sc[s] = 1.f / (1.f + expf(-Cp[e * 16 + s]));
#pragma unroll
        for (int j = 0; j < JT; j++) {
            float kk = 0.f;
#pragma unroll
            for (int s = 0; s < 16; s++) kk += sc[s] * vmat[j][s];
            ckT[j * EE + e] = kk;
        }
    }
}

// ---------- truncated-scan = 16-tap causal depthwise conv; emits bf16 hi/lo for GEMM2 ----------
__global__ __launch_bounds__(256) void conv16_kernel(const float* __restrict__ xconv,
                                                     const float* __restrict__ ckT,
                                                     ushort* __restrict__ oh,
                                                     ushort* __restrict__ ol) {
    const int r = blockIdx.x, t = threadIdx.x;
    ushort* ph = oh + (size_t)r * KP2;
    ushort* pl = ol + (size_t)r * KP2;
    if (r >= M2) {
        for (int e = t; e < KP2; e += 256) { ph[e] = 0; pl[e] = 0; }
        return;
    }
    const int b = r / KT, tt = r - b * KT;
    const int jmax = (tt < JT - 1) ? tt : (JT - 1);
    const float* base = xconv + (size_t)r * EE;
    for (int e = t; e < KP2; e += 256) {
        float y = 0.f;
        if (e < EE) {
            const float* bp = base + e;
            for (int j = 0; j <= jmax; j++) y += ckT[j * EE + e] * bp[-(ptrdiff_t)j * EE];
        }
        ushort h = f2bf(y);
        ph[e] = h;
        pl[e] = f2bf(y - bf2f(h));
    }
}

// ---------------- out = x (copy), then scatter-add x_proc rows ----------------
__global__ void copy4_kernel(const float4* __restrict__ src, float4* __restrict__ dst, int n4) {
    int i = blockIdx.x * blockDim.x + threadIdx.x;
    int stride = gridDim.x * blockDim.x;
    for (; i < n4; i += stride) dst[i] = src[i];
}

__global__ __launch_bounds__(256) void scatter_kernel(const float* __restrict__ xproc,
                                                      const int* __restrict__ idx,
                                                      float* __restrict__ out) {
    int t = blockIdx.x, b = blockIdx.y;
    int row = idx[b * KT + t];
    const float* src = xproc + ((size_t)(b * KT + t)) * CC;
    float* dst = out + ((size_t)(b * LL + row)) * CC;
    for (int d = threadIdx.x; d < CC; d += 256) dst[d] += src[d];
}

extern "C" void kernel_launch(void* const* d_in, const int* in_sizes, int n_in,
                              void* d_out, int out_size, void* d_ws, size_t ws_size,
                              hipStream_t stream) {
    const float* x      = (const float*)d_in[0];
    const float* norm_w = (const float*)d_in[1];
    const float* w_in   = (const float*)d_in[2];
    const float* b_in   = (const float*)d_in[3];
    const float* w_out  = (const float*)d_in[4];
    const float* b_out  = (const float*)d_in[5];
    const float* Amat   = (const float*)d_in[6];
    const float* Bp     = (const float*)d_in[7];
    const float* Cp     = (const float*)d_in[8];
    const float* conv_w = (const float*)d_in[9];
    float* out = (float*)d_out;

    char* wsb = (char*)d_ws;
    size_t off = 0;
    auto take = [&](size_t bytes) {
        void* p = wsb + off;
        off += (bytes + 255) & ~(size_t)255;
        return p;
    };
    float*  xproj = (float*)take((size_t)M1 * EE * 4);        // 144.7 MB
    float*  winp  = (float*)take((size_t)EE * CC * 4);        // 2.44 MB
    ushort* wh    = (ushort*)take((size_t)1152 * KP * 2);     // 1.33 MB
    ushort* wl    = (ushort*)take((size_t)1152 * KP * 2);
    ushort* w2h   = (ushort*)take((size_t)NP2 * KP2 * 2);     // 1.43 MB
    ushort* w2l   = (ushort*)take((size_t)NP2 * KP2 * 2);
    float*  inv   = (float*)take((size_t)M1 * 4);
    float*  simv  = (float*)take((size_t)M1 * 4);
    int*    idxb  = (int*)take((size_t)BB * KT * 4);
    double* gbuf  = (double*)take((size_t)BB * CC * 8);
    float*  ckT   = (float*)take((size_t)JT * EE * 4);        // 70 KB
    size_t ovl = off;
    ushort* xh    = (ushort*)take((size_t)CHUNK * KP * 2);    // 9.44 MB (dead after gemm1)
    ushort* xl    = (ushort*)take((size_t)CHUNK * KP * 2);
    off = ovl;  // overlay: later buffers reuse the xh/xl region
    float*  xconv = (float*)take((size_t)BB * KT * EE * 4);   // 14.45 MB
    ushort* o2h   = (ushort*)take((size_t)M2P * KP2 * 2);     // 7.46 MB
    ushort* o2l   = (ushort*)take((size_t)M2P * KP2 * 2);
    float*  xproc = (float*)take((size_t)BB * KT * CC * 4);   // 7.22 MB
    (void)ws_size;

    winp_kernel<<<(EE * CC + 255) / 256, 256, 0, stream>>>(w_in, norm_w, winp, EE * CC);
    convw_kernel<<<1152, 256, 0, stream>>>(winp, wh, wl);
    w2conv_kernel<<<NP2, 256, 0, stream>>>(w_out, w2h, w2l);
    ssmtaps_kernel<<<1, 256, 0, stream>>>(Amat, Bp, Cp, ckT);

    for (int c = 0; c < NCH; c++) {
        convx_kernel<<<CHUNK, 256, 0, stream>>>(x, c * CHUNK, xh, xl, inv);
        dim3 g1(9, CHUNK / 128);
        gemm_mfma<<<g1, 256, 0, stream>>>(xh, xl, wh, wl, inv, b_in, xproj,
                                          EE, M1, EE, KP, c * CHUNK);
    }

    gram_kernel<<<BB, 256, 0, stream>>>(x, winp, gbuf);
    dotsim_kernel<<<M1, 256, 0, stream>>>(x, gbuf, xproj, inv, simv);
    topk_kernel<<<BB, 1024, 0, stream>>>(simv, idxb);

    dim3 g2(KT, BB);
    gatherconv_kernel<<<g2, 256, 0, stream>>>(xproj, idxb, conv_w, xconv);

    conv16_kernel<<<M2P, 256, 0, stream>>>(xconv, ckT, o2h, o2l);

    dim3 g3(NP2 / 128, M2P / 128);  // 5 x 26
    gemm_mfma<<<g3, 256, 0, stream>>>(o2h, o2l, w2h, w2l, nullptr, b_out, xproc,
                                      CC, M2, CC, KP2, 0);

    copy4_kernel<<<2048, 256, 0, stream>>>((const float4*)x, (float4*)out, out_size / 4);
    scatter_kernel<<<g2, 256, 0, stream>>>(xproc, idxb, out);
}

// Round 5
// 634.184 us; speedup vs baseline: 1.9304x; 1.2334x over previous
//
#include <hip/hip_runtime.h>
#include <hip/hip_bf16.h>

// Problem constants (fixed by reference)
#define BB 8
#define LL 4096
#define CC 552      // DIM
#define EE 1104     // EXP
#define KT 409      // top-k
#define M1 32768    // B*L
#define M2 3272     // B*KT
#define KP 576      // K padded (gemm1)
#define KP2 1120    // K padded (gemm2)
#define M2P 3328    // M2 padded to 26*128
#define NP2 640     // CC padded to 5*128
#define JT 16       // SSM truncation taps (||A||^16 ~ 2e-13)
#define CHUNK 8192
#define NCH 4

typedef __attribute__((ext_vector_type(8))) short bf16x8;
typedef __attribute__((ext_vector_type(4))) float f32x4;

__device__ __forceinline__ ushort f2bf(float f) {
    unsigned u = __float_as_uint(f);
    return (ushort)((u + 0x7FFFu + ((u >> 16) & 1u)) >> 16);  // RNE
}
__device__ __forceinline__ float bf2f(ushort h) {
    return __uint_as_float(((unsigned)h) << 16);
}

// ---------- W' = w_in * norm_w (fp32) + transposed copy ----------
__global__ void winp_kernel(const float* __restrict__ w_in, const float* __restrict__ norm_w,
                            float* __restrict__ winp, float* __restrict__ winpT, int n) {
    int i = blockIdx.x * blockDim.x + threadIdx.x;
    if (i < n) {
        int c = i % CC, e = i / CC;
        float v = w_in[i] * norm_w[c];
        winp[i] = v;
        winpT[(size_t)c * EE + e] = v;
    }
}

// ---------- convert x rows -> bf16 hi/lo (K padded to 576) + fused 1/(rms+eps) ----------
__global__ __launch_bounds__(256) void convx_kernel(const float* __restrict__ x, int r0,
                                                    ushort* __restrict__ xh, ushort* __restrict__ xl,
                                                    float* __restrict__ inv) {
    __shared__ float red[4];
    const int r = r0 + blockIdx.x;
    const float* xr = x + (size_t)r * CC;
    ushort* oh = xh + (size_t)blockIdx.x * KP;
    ushort* ol = xl + (size_t)blockIdx.x * KP;
    const int t = threadIdx.x;
    float s = 0.f;
    if (t < 144) {
        float4 v = make_float4(0.f, 0.f, 0.f, 0.f);
        if (t < 138) v = reinterpret_cast<const float4*>(xr)[t];
        s = v.x * v.x + v.y * v.y + v.z * v.z + v.w * v.w;
        ushort4 h, l;
        h.x = f2bf(v.x); l.x = f2bf(v.x - bf2f(h.x));
        h.y = f2bf(v.y); l.y = f2bf(v.y - bf2f(h.y));
        h.z = f2bf(v.z); l.z = f2bf(v.z - bf2f(h.z));
        h.w = f2bf(v.w); l.w = f2bf(v.w - bf2f(h.w));
        reinterpret_cast<ushort4*>(oh)[t] = h;
        reinterpret_cast<ushort4*>(ol)[t] = l;
    }
#pragma unroll
    for (int o = 32; o > 0; o >>= 1) s += __shfl_down(s, o, 64);
    if ((t & 63) == 0) red[t >> 6] = s;
    __syncthreads();
    if (t == 0) {
        float tot = red[0] + red[1] + red[2] + red[3];
        inv[r] = 1.f / (sqrtf(tot / (float)CC) + 1e-6f);
    }
}

// ---------- convert W' rows -> bf16 hi/lo, rows zero-padded to 1152 ----------
__global__ __launch_bounds__(256) void convw_kernel(const float* __restrict__ winp,
                                                    ushort* __restrict__ wh, ushort* __restrict__ wl) {
    const int n = blockIdx.x, t = threadIdx.x;
    if (t >= 144) return;
    float4 v = make_float4(0.f, 0.f, 0.f, 0.f);
    if (n < EE && t < 138) v = reinterpret_cast<const float4*>(winp + (size_t)n * CC)[t];
    ushort4 h, l;
    h.x = f2bf(v.x); l.x = f2bf(v.x - bf2f(h.x));
    h.y = f2bf(v.y); l.y = f2bf(v.y - bf2f(h.y));
    h.z = f2bf(v.z); l.z = f2bf(v.z - bf2f(h.z));
    h.w = f2bf(v.w); l.w = f2bf(v.w - bf2f(h.w));
    reinterpret_cast<ushort4*>(wh + (size_t)n * KP)[t] = h;
    reinterpret_cast<ushort4*>(wl + (size_t)n * KP)[t] = l;
}

// ---------- convert w_out rows -> bf16 hi/lo [NP2=640][KP2=1120], zero-padded ----------
__global__ __launch_bounds__(256) void w2conv_kernel(const float* __restrict__ w_out,
                                                     ushort* __restrict__ wh, ushort* __restrict__ wl) {
    const int n = blockIdx.x, t = threadIdx.x;
    for (int i = t; i < KP2 / 4; i += 256) {
        float4 v = make_float4(0.f, 0.f, 0.f, 0.f);
        if (n < CC && i < EE / 4) v = reinterpret_cast<const float4*>(w_out + (size_t)n * EE)[i];
        ushort4 h, l;
        h.x = f2bf(v.x); l.x = f2bf(v.x - bf2f(h.x));
        h.y = f2bf(v.y); l.y = f2bf(v.y - bf2f(h.y));
        h.z = f2bf(v.z); l.z = f2bf(v.z - bf2f(h.z));
        h.w = f2bf(v.w); l.w = f2bf(v.w - bf2f(h.w));
        reinterpret_cast<ushort4*>(wh + (size_t)n * KP2)[i] = h;
        reinterpret_cast<ushort4*>(wl + (size_t)n * KP2)[i] = l;
    }
}

// ---------- unified split-bf16 MFMA GEMM ----------
__global__ __launch_bounds__(256) void gemm_mfma(
    const ushort* __restrict__ Ah, const ushort* __restrict__ Al,   // [Mp][Kp]
    const ushort* __restrict__ Bh, const ushort* __restrict__ Bl,   // [Np][Kp]
    const float* __restrict__ rowscale, const float* __restrict__ bias,
    float* __restrict__ C, int ldc, int M, int N, int Kp, int r0) {
    __shared__ ushort As_h[128][40];
    __shared__ ushort As_l[128][40];
    __shared__ ushort Bs_h[128][40];
    __shared__ ushort Bs_l[128][40];
    const int tid = threadIdx.x;
    const int col0 = blockIdx.x * 128;
    const int row0 = blockIdx.y * 128;
    const int wave = tid >> 6, lane = tid & 63;
    const int wr = (wave >> 1) * 64, wc = (wave & 1) * 64;
    const int sr = tid >> 2, sk = (tid & 3) * 8;
    const int lrow = lane & 15, kb = (lane >> 4) * 8;

    f32x4 acc[4][4];
    const f32x4 zero = {0.f, 0.f, 0.f, 0.f};
#pragma unroll
    for (int i = 0; i < 4; i++)
#pragma unroll
        for (int j = 0; j < 4; j++) acc[i][j] = zero;

    for (int k0 = 0; k0 < Kp; k0 += 32) {
        int4 vah0 = *reinterpret_cast<const int4*>(Ah + (size_t)(row0 + sr) * Kp + k0 + sk);
        int4 vah1 = *reinterpret_cast<const int4*>(Ah + (size_t)(row0 + sr + 64) * Kp + k0 + sk);
        int4 val0 = *reinterpret_cast<const int4*>(Al + (size_t)(row0 + sr) * Kp + k0 + sk);
        int4 val1 = *reinterpret_cast<const int4*>(Al + (size_t)(row0 + sr + 64) * Kp + k0 + sk);
        int4 vbh0 = *reinterpret_cast<const int4*>(Bh + (size_t)(col0 + sr) * Kp + k0 + sk);
        int4 vbh1 = *reinterpret_cast<const int4*>(Bh + (size_t)(col0 + sr + 64) * Kp + k0 + sk);
        int4 vbl0 = *reinterpret_cast<const int4*>(Bl + (size_t)(col0 + sr) * Kp + k0 + sk);
        int4 vbl1 = *reinterpret_cast<const int4*>(Bl + (size_t)(col0 + sr + 64) * Kp + k0 + sk);
        __syncthreads();
        *reinterpret_cast<int4*>(&As_h[sr][sk]) = vah0;
        *reinterpret_cast<int4*>(&As_h[sr + 64][sk]) = vah1;
        *reinterpret_cast<int4*>(&As_l[sr][sk]) = val0;
        *reinterpret_cast<int4*>(&As_l[sr + 64][sk]) = val1;
        *reinterpret_cast<int4*>(&Bs_h[sr][sk]) = vbh0;
        *reinterpret_cast<int4*>(&Bs_h[sr + 64][sk]) = vbh1;
        *reinterpret_cast<int4*>(&Bs_l[sr][sk]) = vbl0;
        *reinterpret_cast<int4*>(&Bs_l[sr + 64][sk]) = vbl1;
        __syncthreads();
        bf16x8 ah[4], al[4], bh[4], bl[4];
#pragma unroll
        for (int i = 0; i < 4; i++) {
            ah[i] = *reinterpret_cast<const bf16x8*>(&As_h[wr + i * 16 + lrow][kb]);
            al[i] = *reinterpret_cast<const bf16x8*>(&As_l[wr + i * 16 + lrow][kb]);
            bh[i] = *reinterpret_cast<const bf16x8*>(&Bs_h[wc + i * 16 + lrow][kb]);
            bl[i] = *reinterpret_cast<const bf16x8*>(&Bs_l[wc + i * 16 + lrow][kb]);
        }
#pragma unroll
        for (int i = 0; i < 4; i++)
#pragma unroll
            for (int j = 0; j < 4; j++) {
                acc[i][j] = __builtin_amdgcn_mfma_f32_16x16x32_bf16(ah[i], bh[j], acc[i][j], 0, 0, 0);
                acc[i][j] = __builtin_amdgcn_mfma_f32_16x16x32_bf16(ah[i], bl[j], acc[i][j], 0, 0, 0);
                acc[i][j] = __builtin_amdgcn_mfma_f32_16x16x32_bf16(al[i], bh[j], acc[i][j], 0, 0, 0);
            }
    }
#pragma unroll
    for (int i = 0; i < 4; i++) {
        const int gmb = r0 + row0 + wr + i * 16 + (lane >> 4) * 4;
#pragma unroll
        for (int reg = 0; reg < 4; reg++) {
            const int gm = gmb + reg;
            if (gm < M) {
                const float rs = rowscale ? rowscale[gm] : 1.f;
#pragma unroll
                for (int j = 0; j < 4; j++) {
                    const int gn = col0 + wc + j * 16 + lrow;
                    if (gn < N) C[(size_t)gm * ldc + gn] = acc[i][j][reg] * rs + bias[gn];
                }
            }
        }
    }
}

// ---------- center row -> fp64 normalized (one block per batch) ----------
__global__ __launch_bounds__(256) void center_kernel(const float* __restrict__ x,
                                                     double* __restrict__ xcn) {
    __shared__ double red[4];
    const int b = blockIdx.x, tid = threadIdx.x;
    const float* xc = x + ((size_t)(b * LL + LL / 2)) * CC;
    double s = 0.0;
    for (int c = tid; c < CC; c += 256) { double v = xc[c]; s += v * v; }
#pragma unroll
    for (int o = 32; o > 0; o >>= 1) s += __shfl_down(s, o, 64);
    if ((tid & 63) == 0) red[tid >> 6] = s;
    __syncthreads();
    const double tot = red[0] + red[1] + red[2] + red[3];
    const double invc = 1.0 / (sqrt(tot / (double)CC) + 1e-6);
    for (int c = tid; c < CC; c += 256) xcn[(size_t)b * CC + c] = (double)xc[c] * invc;
}

// ---------- t1[b][e] = <W'_e, xcn_b>, one wave per (b,e) ----------
__global__ __launch_bounds__(256) void gram1_kernel(const float* __restrict__ winp,
                                                    const double* __restrict__ xcn,
                                                    double* __restrict__ t1) {
    const int b = blockIdx.y;
    const int wave = threadIdx.x >> 6, lane = threadIdx.x & 63;
    const int e = blockIdx.x * 4 + wave;
    const float* wr = winp + (size_t)e * CC;
    const double* xb = xcn + (size_t)b * CC;
    double s = 0.0;
    for (int c = lane; c < CC; c += 64) s += (double)wr[c] * xb[c];
#pragma unroll
    for (int o = 32; o > 0; o >>= 1) s += __shfl_down(s, o, 64);
    if (lane == 0) t1[(size_t)b * EE + e] = s;
}

// ---------- g[b][c] = <W'T_c, t1_b>, one wave per (b,c) ----------
__global__ __launch_bounds__(256) void gram2_kernel(const float* __restrict__ winpT,
                                                    const double* __restrict__ t1,
                                                    double* __restrict__ g) {
    const int b = blockIdx.y;
    const int wave = threadIdx.x >> 6, lane = threadIdx.x & 63;
    const int c = blockIdx.x * 4 + wave;
    if (c >= CC) return;
    const float* wr = winpT + (size_t)c * EE;
    const double* tb = t1 + (size_t)b * EE;
    double s = 0.0;
    for (int e = lane; e < EE; e += 64) s += (double)wr[e] * tb[e];
#pragma unroll
    for (int o = 32; o > 0; o >>= 1) s += __shfl_down(s, o, 64);
    if (lane == 0) g[(size_t)b * CC + c] = s;
}

// ---------- sim_r = inv_r * <x_r, g_b> / ||xproj_r|| ----------
__global__ __launch_bounds__(256) void dotsim_kernel(const float* __restrict__ x,
                                                     const double* __restrict__ g,
                                                     const float* __restrict__ xproj,
                                                     const float* __restrict__ inv,
                                                     float* __restrict__ sim) {
    __shared__ double redd[4];
    __shared__ float redn[4];
    const int r = blockIdx.x, tid = threadIdx.x;
    const int b = r >> 12;
    const float* xr = x + (size_t)r * CC;
    const double* gb = g + (size_t)b * CC;
    double d = 0.0;
    for (int c = tid; c < CC; c += 256) d += (double)xr[c] * gb[c];
    const float* pr = xproj + (size_t)r * EE;
    float ns = 0.f;
    for (int e = tid; e < EE; e += 256) { float v = pr[e]; ns += v * v; }
#pragma unroll
    for (int o = 32; o > 0; o >>= 1) { d += __shfl_down(d, o, 64); ns += __shfl_down(ns, o, 64); }
    if ((tid & 63) == 0) { redd[tid >> 6] = d; redn[tid >> 6] = ns; }
    __syncthreads();
    if (tid == 0) {
        double dt = redd[0] + redd[1] + redd[2] + redd[3];
        double nt = (double)(redn[0] + redn[1] + redn[2] + redn[3]);
        sim[r] = (float)((double)inv[r] * dt / sqrt(fmax(nt, 1e-24)));
    }
}

// ---------------- top-k via full bitonic sort of (value desc, idx asc) keys ----------------
__global__ __launch_bounds__(1024) void topk_kernel(const float* __restrict__ sim,
                                                    int* __restrict__ idx) {
    __shared__ unsigned long long keys[4096];
    const int b = blockIdx.x;
    for (int i = threadIdx.x; i < 4096; i += 1024) {
        unsigned u = __float_as_uint(sim[b * 4096 + i]);
        u = (u & 0x80000000u) ? ~u : (u | 0x80000000u);
        keys[i] = ((unsigned long long)(~u) << 32) | (unsigned)i;
    }
    __syncthreads();
    for (int size = 2; size <= 4096; size <<= 1) {
        for (int stride = size >> 1; stride > 0; stride >>= 1) {
#pragma unroll 1
            for (int t = threadIdx.x; t < 2048; t += 1024) {
                int low = t & (stride - 1);
                int pos = ((t - low) << 1) + low;
                bool up = ((pos & size) == 0);
                unsigned long long ka = keys[pos], kb = keys[pos + stride];
                if ((ka > kb) == up) { keys[pos] = kb; keys[pos + stride] = ka; }
            }
            __syncthreads();
        }
    }
    for (int t = threadIdx.x; t < KT; t += 1024) idx[b * KT + t] = (int)(keys[t] & 0xffffffffu);
}

// ---------------- gather top-k rows + depthwise causal conv (len 4) ----------------
__global__ __launch_bounds__(256) void gatherconv_kernel(const float* __restrict__ xproj,
                                                         const int* __restrict__ idx,
                                                         const float* __restrict__ conv_w,
                                                         float* __restrict__ xconv) {
    int t = blockIdx.x, b = blockIdx.y;
    int rows[4];
#pragma unroll
    for (int j = 0; j < 4; j++) {
        int tt = t - 3 + j;
        rows[j] = (tt >= 0) ? idx[b * KT + tt] : -1;
    }
    for (int e = threadIdx.x; e < EE; e += 256) {
        float s = 0.f;
#pragma unroll
        for (int j = 0; j < 4; j++) {
            if (rows[j] >= 0)
                s += conv_w[e * 4 + j] * xproj[((size_t)(b * LL + rows[j])) * EE + e];
        }
        xconv[((size_t)(b * KT + t)) * EE + e] = s;
    }
}

// ---------- SSM taps: ckT[j][e] = sigC[e] . A^j . sigB, j = 0..JT-1 ----------
__global__ __launch_bounds__(256) void ssmtaps_kernel(const float* __restrict__ A,
                                                      const float* __restrict__ Bp,
                                                      const float* __restrict__ Cp,
                                                      float* __restrict__ ckT) {
    __shared__ float Ash[256];
    __shared__ float vmat[JT][16];
    const int t = threadIdx.x;
    Ash[t] = A[t];
    __syncthreads();
    if (t < 16) vmat[0][t] = 1.f / (1.f + expf(-Bp[t]));
    __syncthreads();
    for (int j = 1; j < JT; j++) {
        float nv = 0.f;
        if (t < 16) {
#pragma unroll
            for (int s2 = 0; s2 < 16; s2++) nv += Ash[t * 16 + s2] * vmat[j - 1][s2];
        }
        __syncthreads();
        if (t < 16) vmat[j][t] = nv;
        __syncthreads();
    }
    for (int e = t; e < EE; e += 256) {
        float sc[16];
#pragma unroll
        for (int s = 0; s < 16; s++) sc[s] = 1.f / (1.f + expf(-Cp[e * 16 + s]));
#pragma unroll
        for (int j = 0; j < JT; j++) {
            float kk = 0.f;
#pragma unroll
            for (int s = 0; s < 16; s++) kk += sc[s] * vmat[j][s];
            ckT[j * EE + e] = kk;
        }
    }
}

// ---------- truncated-scan = 16-tap causal depthwise conv; emits bf16 hi/lo for GEMM2 ----------
__global__ __launch_bounds__(256) void conv16_kernel(const float* __restrict__ xconv,
                                                     const float* __restrict__ ckT,
                                                     ushort* __restrict__ oh,
                                                     ushort* __restrict__ ol) {
    const int r = blockIdx.x, t = threadIdx.x;
    ushort* ph = oh + (size_t)r * KP2;
    ushort* pl = ol + (size_t)r * KP2;
    if (r >= M2) {
        for (int e = t; e < KP2; e += 256) { ph[e] = 0; pl[e] = 0; }
        return;
    }
    const int b = r / KT, tt = r - b * KT;
    const int jmax = (tt < JT - 1) ? tt : (JT - 1);
    const float* base = xconv + (size_t)r * EE;
    for (int e = t; e < KP2; e += 256) {
        float y = 0.f;
        if (e < EE) {
            const float* bp = base + e;
            for (int j = 0; j <= jmax; j++) y += ckT[j * EE + e] * bp[-(ptrdiff_t)j * EE];
        }
        ushort h = f2bf(y);
        ph[e] = h;
        pl[e] = f2bf(y - bf2f(h));
    }
}

// ---------------- out = x (copy), then scatter-add x_proc rows ----------------
__global__ void copy4_kernel(const float4* __restrict__ src, float4* __restrict__ dst, int n4) {
    int i = blockIdx.x * blockDim.x + threadIdx.x;
    int stride = gridDim.x * blockDim.x;
    for (; i < n4; i += stride) dst[i] = src[i];
}

__global__ __launch_bounds__(256) void scatter_kernel(const float* __restrict__ xproc,
                                                      const int* __restrict__ idx,
                                                      float* __restrict__ out) {
    int t = blockIdx.x, b = blockIdx.y;
    int row = idx[b * KT + t];
    const float* src = xproc + ((size_t)(b * KT + t)) * CC;
    float* dst = out + ((size_t)(b * LL + row)) * CC;
    for (int d = threadIdx.x; d < CC; d += 256) dst[d] += src[d];
}

extern "C" void kernel_launch(void* const* d_in, const int* in_sizes, int n_in,
                              void* d_out, int out_size, void* d_ws, size_t ws_size,
                              hipStream_t stream) {
    const float* x      = (const float*)d_in[0];
    const float* norm_w = (const float*)d_in[1];
    const float* w_in   = (const float*)d_in[2];
    const float* b_in   = (const float*)d_in[3];
    const float* w_out  = (const float*)d_in[4];
    const float* b_out  = (const float*)d_in[5];
    const float* Amat   = (const float*)d_in[6];
    const float* Bp     = (const float*)d_in[7];
    const float* Cp     = (const float*)d_in[8];
    const float* conv_w = (const float*)d_in[9];
    float* out = (float*)d_out;

    char* wsb = (char*)d_ws;
    size_t off = 0;
    auto take = [&](size_t bytes) {
        void* p = wsb + off;
        off += (bytes + 255) & ~(size_t)255;
        return p;
    };
    float*  xproj = (float*)take((size_t)M1 * EE * 4);        // 144.7 MB
    float*  winp  = (float*)take((size_t)EE * CC * 4);        // 2.44 MB
    float*  winpT = (float*)take((size_t)EE * CC * 4);        // 2.44 MB
    ushort* wh    = (ushort*)take((size_t)1152 * KP * 2);     // 1.33 MB
    ushort* wl    = (ushort*)take((size_t)1152 * KP * 2);
    ushort* w2h   = (ushort*)take((size_t)NP2 * KP2 * 2);     // 1.43 MB
    ushort* w2l   = (ushort*)take((size_t)NP2 * KP2 * 2);
    float*  inv   = (float*)take((size_t)M1 * 4);
    float*  simv  = (float*)take((size_t)M1 * 4);
    int*    idxb  = (int*)take((size_t)BB * KT * 4);
    double* gbuf  = (double*)take((size_t)BB * CC * 8);
    double* xcn   = (double*)take((size_t)BB * CC * 8);
    double* t1b   = (double*)take((size_t)BB * EE * 8);
    float*  ckT   = (float*)take((size_t)JT * EE * 4);        // 70 KB
    size_t ovl = off;
    ushort* xh    = (ushort*)take((size_t)CHUNK * KP * 2);    // 9.44 MB (dead after gemm1)
    ushort* xl    = (ushort*)take((size_t)CHUNK * KP * 2);
    off = ovl;  // overlay: later buffers reuse the xh/xl region
    float*  xconv = (float*)take((size_t)BB * KT * EE * 4);   // 14.45 MB
    ushort* o2h   = (ushort*)take((size_t)M2P * KP2 * 2);     // 7.46 MB
    ushort* o2l   = (ushort*)take((size_t)M2P * KP2 * 2);
    float*  xproc = (float*)take((size_t)BB * KT * CC * 4);   // 7.22 MB
    (void)ws_size;

    winp_kernel<<<(EE * CC + 255) / 256, 256, 0, stream>>>(w_in, norm_w, winp, winpT, EE * CC);
    convw_kernel<<<1152, 256, 0, stream>>>(winp, wh, wl);
    w2conv_kernel<<<NP2, 256, 0, stream>>>(w_out, w2h, w2l);
    ssmtaps_kernel<<<1, 256, 0, stream>>>(Amat, Bp, Cp, ckT);

    for (int c = 0; c < NCH; c++) {
        convx_kernel<<<CHUNK, 256, 0, stream>>>(x, c * CHUNK, xh, xl, inv);
        dim3 g1(9, CHUNK / 128);
        gemm_mfma<<<g1, 256, 0, stream>>>(xh, xl, wh, wl, inv, b_in, xproj,
                                          EE, M1, EE, KP, c * CHUNK);
    }

    center_kernel<<<BB, 256, 0, stream>>>(x, xcn);
    dim3 gg1(EE / 4, BB);
    gram1_kernel<<<gg1, 256, 0, stream>>>(winp, xcn, t1b);
    dim3 gg2(CC / 4, BB);
    gram2_kernel<<<gg2, 256, 0, stream>>>(winpT, t1b, gbuf);
    dotsim_kernel<<<M1, 256, 0, stream>>>(x, gbuf, xproj, inv, simv);
    topk_kernel<<<BB, 1024, 0, stream>>>(simv, idxb);

    dim3 g2(KT, BB);
    gatherconv_kernel<<<g2, 256, 0, stream>>>(xproj, idxb, conv_w, xconv);

    conv16_kernel<<<M2P, 256, 0, stream>>>(xconv, ckT, o2h, o2l);

    dim3 g3(NP2 / 128, M2P / 128);  // 5 x 26
    gemm_mfma<<<g3, 256, 0, stream>>>(o2h, o2l, w2h, w2l, nullptr, b_out, xproc,
                                      CC, M2, CC, KP2, 0);

    copy4_kernel<<<2048, 256, 0, stream>>>((const float4*)x, (float4*)out, out_size / 4);
    scatter_kernel<<<g2, 256, 0, stream>>>(xproc, idxb, out);
}

// Round 6
// 496.979 us; speedup vs baseline: 2.4634x; 1.2761x over previous
//
#include <hip/hip_runtime.h>
#include <hip/hip_bf16.h>

// Problem constants (fixed by reference)
#define BB 8
#define LL 4096
#define CC 552      // DIM
#define EE 1104     // EXP
#define KT 409      // top-k
#define M1 32768    // B*L
#define M2 3272     // B*KT
#define KP 576      // K padded (gemm over DIM)
#define KP2 1120    // K padded (gemm over EXP)
#define M2P 3328    // M2 padded to 26*128
#define JT 16       // SSM truncation taps (||A||^16 ~ 2e-13)
#define JC 19       // composed conv4 * ssm16 taps
#define NQT 5       // col tiles in gemmq (640/128)

typedef __attribute__((ext_vector_type(8))) short bf16x8;
typedef __attribute__((ext_vector_type(4))) float f32x4;

__device__ __forceinline__ ushort f2bf(float f) {
    unsigned u = __float_as_uint(f);
    return (ushort)((u + 0x7FFFu + ((u >> 16) & 1u)) >> 16);  // RNE
}
__device__ __forceinline__ float bf2f(ushort h) {
    return __uint_as_float(((unsigned)h) << 16);
}

__global__ void zero_kernel(float* __restrict__ p, int n) {
    int i = blockIdx.x * blockDim.x + threadIdx.x;
    if (i < n) p[i] = 0.f;
}

// ---------- W' = w_in * norm_w (fp32) + transposed copy ----------
__global__ void winp_kernel(const float* __restrict__ w_in, const float* __restrict__ norm_w,
                            float* __restrict__ winp, float* __restrict__ winpT, int n) {
    int i = blockIdx.x * blockDim.x + threadIdx.x;
    if (i < n) {
        int c = i % CC, e = i / CC;
        float v = w_in[i] * norm_w[c];
        winp[i] = v;
        winpT[(size_t)c * EE + e] = v;
    }
}

// ---------- convert x rows -> bf16 hi/lo [M1][KP] + fused 1/(rms+eps) ----------
__global__ __launch_bounds__(256) void convx_kernel(const float* __restrict__ x,
                                                    ushort* __restrict__ xh, ushort* __restrict__ xl,
                                                    float* __restrict__ inv) {
    __shared__ float red[4];
    const int r = blockIdx.x;
    const float* xr = x + (size_t)r * CC;
    ushort* oh = xh + (size_t)r * KP;
    ushort* ol = xl + (size_t)r * KP;
    const int t = threadIdx.x;
    float s = 0.f;
    if (t < 144) {
        float4 v = make_float4(0.f, 0.f, 0.f, 0.f);
        if (t < 138) v = reinterpret_cast<const float4*>(xr)[t];
        s = v.x * v.x + v.y * v.y + v.z * v.z + v.w * v.w;
        ushort4 h, l;
        h.x = f2bf(v.x); l.x = f2bf(v.x - bf2f(h.x));
        h.y = f2bf(v.y); l.y = f2bf(v.y - bf2f(h.y));
        h.z = f2bf(v.z); l.z = f2bf(v.z - bf2f(h.z));
        h.w = f2bf(v.w); l.w = f2bf(v.w - bf2f(h.w));
        reinterpret_cast<ushort4*>(oh)[t] = h;
        reinterpret_cast<ushort4*>(ol)[t] = l;
    }
#pragma unroll
    for (int o = 32; o > 0; o >>= 1) s += __shfl_down(s, o, 64);
    if ((t & 63) == 0) red[t >> 6] = s;
    __syncthreads();
    if (t == 0) {
        float tot = red[0] + red[1] + red[2] + red[3];
        inv[r] = 1.f / (sqrtf(tot / (float)CC) + 1e-6f);
    }
}

// ---------- convert [*][CC] fp32 rows -> bf16 hi/lo [grid][KP]; rows >= nvalid zeroed ----------
__global__ __launch_bounds__(256) void convw_kernel(const float* __restrict__ src, int nvalid,
                                                    ushort* __restrict__ wh, ushort* __restrict__ wl) {
    const int n = blockIdx.x, t = threadIdx.x;
    if (t >= 144) return;
    float4 v = make_float4(0.f, 0.f, 0.f, 0.f);
    if (n < nvalid && t < 138) v = reinterpret_cast<const float4*>(src + (size_t)n * CC)[t];
    ushort4 h, l;
    h.x = f2bf(v.x); l.x = f2bf(v.x - bf2f(h.x));
    h.y = f2bf(v.y); l.y = f2bf(v.y - bf2f(h.y));
    h.z = f2bf(v.z); l.z = f2bf(v.z - bf2f(h.z));
    h.w = f2bf(v.w); l.w = f2bf(v.w - bf2f(h.w));
    reinterpret_cast<ushort4*>(wh + (size_t)n * KP)[t] = h;
    reinterpret_cast<ushort4*>(wl + (size_t)n * KP)[t] = l;
}

// ---------- convert [*][EE] fp32 rows -> bf16 hi/lo [grid][KP2]; rows >= CC zeroed ----------
__global__ __launch_bounds__(256) void w2conv_kernel(const float* __restrict__ src,
                                                     ushort* __restrict__ wh, ushort* __restrict__ wl) {
    const int n = blockIdx.x, t = threadIdx.x;
    for (int i = t; i < KP2 / 4; i += 256) {
        float4 v = make_float4(0.f, 0.f, 0.f, 0.f);
        if (n < CC && i < EE / 4) v = reinterpret_cast<const float4*>(src + (size_t)n * EE)[i];
        ushort4 h, l;
        h.x = f2bf(v.x); l.x = f2bf(v.x - bf2f(h.x));
        h.y = f2bf(v.y); l.y = f2bf(v.y - bf2f(h.y));
        h.z = f2bf(v.z); l.z = f2bf(v.z - bf2f(h.z));
        h.w = f2bf(v.w); l.w = f2bf(v.w - bf2f(h.w));
        reinterpret_cast<ushort4*>(wh + (size_t)n * KP2)[i] = h;
        reinterpret_cast<ushort4*>(wl + (size_t)n * KP2)[i] = l;
    }
}

// ---------- unified split-bf16 MFMA GEMM: C = rowscale[m]*(A@B^T) + bias[n] ----------
__global__ __launch_bounds__(256) void gemm_mfma(
    const ushort* __restrict__ Ah, const ushort* __restrict__ Al,   // [Mp][Kp]
    const ushort* __restrict__ Bh, const ushort* __restrict__ Bl,   // [Np][Kp]
    const float* __restrict__ rowscale, const float* __restrict__ bias,
    float* __restrict__ C, int ldc, int M, int N, int Kp, int r0) {
    __shared__ ushort As_h[128][40];
    __shared__ ushort As_l[128][40];
    __shared__ ushort Bs_h[128][40];
    __shared__ ushort Bs_l[128][40];
    const int tid = threadIdx.x;
    const int col0 = blockIdx.x * 128;
    const int row0 = blockIdx.y * 128;
    const int wave = tid >> 6, lane = tid & 63;
    const int wr = (wave >> 1) * 64, wc = (wave & 1) * 64;
    const int sr = tid >> 2, sk = (tid & 3) * 8;
    const int lrow = lane & 15, kb = (lane >> 4) * 8;

    f32x4 acc[4][4];
    const f32x4 zero = {0.f, 0.f, 0.f, 0.f};
#pragma unroll
    for (int i = 0; i < 4; i++)
#pragma unroll
        for (int j = 0; j < 4; j++) acc[i][j] = zero;

    for (int k0 = 0; k0 < Kp; k0 += 32) {
        int4 vah0 = *reinterpret_cast<const int4*>(Ah + (size_t)(row0 + sr) * Kp + k0 + sk);
        int4 vah1 = *reinterpret_cast<const int4*>(Ah + (size_t)(row0 + sr + 64) * Kp + k0 + sk);
        int4 val0 = *reinterpret_cast<const int4*>(Al + (size_t)(row0 + sr) * Kp + k0 + sk);
        int4 val1 = *reinterpret_cast<const int4*>(Al + (size_t)(row0 + sr + 64) * Kp + k0 + sk);
        int4 vbh0 = *reinterpret_cast<const int4*>(Bh + (size_t)(col0 + sr) * Kp + k0 + sk);
        int4 vbh1 = *reinterpret_cast<const int4*>(Bh + (size_t)(col0 + sr + 64) * Kp + k0 + sk);
        int4 vbl0 = *reinterpret_cast<const int4*>(Bl + (size_t)(col0 + sr) * Kp + k0 + sk);
        int4 vbl1 = *reinterpret_cast<const int4*>(Bl + (size_t)(col0 + sr + 64) * Kp + k0 + sk);
        __syncthreads();
        *reinterpret_cast<int4*>(&As_h[sr][sk]) = vah0;
        *reinterpret_cast<int4*>(&As_h[sr + 64][sk]) = vah1;
        *reinterpret_cast<int4*>(&As_l[sr][sk]) = val0;
        *reinterpret_cast<int4*>(&As_l[sr + 64][sk]) = val1;
        *reinterpret_cast<int4*>(&Bs_h[sr][sk]) = vbh0;
        *reinterpret_cast<int4*>(&Bs_h[sr + 64][sk]) = vbh1;
        *reinterpret_cast<int4*>(&Bs_l[sr][sk]) = vbl0;
        *reinterpret_cast<int4*>(&Bs_l[sr + 64][sk]) = vbl1;
        __syncthreads();
        bf16x8 ah[4], al[4], bh[4], bl[4];
#pragma unroll
        for (int i = 0; i < 4; i++) {
            ah[i] = *reinterpret_cast<const bf16x8*>(&As_h[wr + i * 16 + lrow][kb]);
            al[i] = *reinterpret_cast<const bf16x8*>(&As_l[wr + i * 16 + lrow][kb]);
            bh[i] = *reinterpret_cast<const bf16x8*>(&Bs_h[wc + i * 16 + lrow][kb]);
            bl[i] = *reinterpret_cast<const bf16x8*>(&Bs_l[wc + i * 16 + lrow][kb]);
        }
#pragma unroll
        for (int i = 0; i < 4; i++)
#pragma unroll
            for (int j = 0; j < 4; j++) {
                acc[i][j] = __builtin_amdgcn_mfma_f32_16x16x32_bf16(ah[i], bh[j], acc[i][j], 0, 0, 0);
                acc[i][j] = __builtin_amdgcn_mfma_f32_16x16x32_bf16(ah[i], bl[j], acc[i][j], 0, 0, 0);
                acc[i][j] = __builtin_amdgcn_mfma_f32_16x16x32_bf16(al[i], bh[j], acc[i][j], 0, 0, 0);
            }
    }
    // epilogue: C/D layout col=lane&15, row=(lane>>4)*4+reg  [m89-verified]
#pragma unroll
    for (int i = 0; i < 4; i++) {
        const int gmb = r0 + row0 + wr + i * 16 + (lane >> 4) * 4;
#pragma unroll
        for (int reg = 0; reg < 4; reg++) {
            const int gm = gmb + reg;
            if (gm < M) {
                const float rs = rowscale ? rowscale[gm] : 1.f;
#pragma unroll
                for (int j = 0; j < 4; j++) {
                    const int gn = col0 + wc + j * 16 + lrow;
                    if (gn < N) C[(size_t)gm * ldc + gn] = acc[i][j][reg] * rs + (bias ? bias[gn] : 0.f);
                }
            }
        }
    }
}

// ---------- gemmq: y = x@G (split-bf16) with fused q_m = sum_n y[m,n]*x[m,n]; y never stored ----------
__global__ __launch_bounds__(256) void gemm_mfma_q(
    const ushort* __restrict__ Ah, const ushort* __restrict__ Al,   // x hi/lo [M1][KP]
    const ushort* __restrict__ Bh, const ushort* __restrict__ Bl,   // G hi/lo [640][KP]
    const float* __restrict__ xsrc, float* __restrict__ qpart) {
    __shared__ ushort As_h[128][40];
    __shared__ ushort As_l[128][40];
    __shared__ ushort Bs_h[128][40];
    __shared__ ushort Bs_l[128][40];
    const int tid = threadIdx.x;
    const int col0 = blockIdx.x * 128;
    const int row0 = blockIdx.y * 128;
    const int wave = tid >> 6, lane = tid & 63;
    const int wr = (wave >> 1) * 64, wc = (wave & 1) * 64;
    const int sr = tid >> 2, sk = (tid & 3) * 8;
    const int lrow = lane & 15, kb = (lane >> 4) * 8;

    f32x4 acc[4][4];
    const f32x4 zero = {0.f, 0.f, 0.f, 0.f};
#pragma unroll
    for (int i = 0; i < 4; i++)
#pragma unroll
        for (int j = 0; j < 4; j++) acc[i][j] = zero;

    for (int k0 = 0; k0 < KP; k0 += 32) {
        int4 vah0 = *reinterpret_cast<const int4*>(Ah + (size_t)(row0 + sr) * KP + k0 + sk);
        int4 vah1 = *reinterpret_cast<const int4*>(Ah + (size_t)(row0 + sr + 64) * KP + k0 + sk);
        int4 val0 = *reinterpret_cast<const int4*>(Al + (size_t)(row0 + sr) * KP + k0 + sk);
        int4 val1 = *reinterpret_cast<const int4*>(Al + (size_t)(row0 + sr + 64) * KP + k0 + sk);
        int4 vbh0 = *reinterpret_cast<const int4*>(Bh + (size_t)(col0 + sr) * KP + k0 + sk);
        int4 vbh1 = *reinterpret_cast<const int4*>(Bh + (size_t)(col0 + sr + 64) * KP + k0 + sk);
        int4 vbl0 = *reinterpret_cast<const int4*>(Bl + (size_t)(col0 + sr) * KP + k0 + sk);
        int4 vbl1 = *reinterpret_cast<const int4*>(Bl + (size_t)(col0 + sr + 64) * KP + k0 + sk);
        __syncthreads();
        *reinterpret_cast<int4*>(&As_h[sr][sk]) = vah0;
        *reinterpret_cast<int4*>(&As_h[sr + 64][sk]) = vah1;
        *reinterpret_cast<int4*>(&As_l[sr][sk]) = val0;
        *reinterpret_cast<int4*>(&As_l[sr + 64][sk]) = val1;
        *reinterpret_cast<int4*>(&Bs_h[sr][sk]) = vbh0;
        *reinterpret_cast<int4*>(&Bs_h[sr + 64][sk]) = vbh1;
        *reinterpret_cast<int4*>(&Bs_l[sr][sk]) = vbl0;
        *reinterpret_cast<int4*>(&Bs_l[sr + 64][sk]) = vbl1;
        __syncthreads();
        bf16x8 ah[4], al[4], bh[4], bl[4];
#pragma unroll
        for (int i = 0; i < 4; i++) {
            ah[i] = *reinterpret_cast<const bf16x8*>(&As_h[wr + i * 16 + lrow][kb]);
            al[i] = *reinterpret_cast<const bf16x8*>(&As_l[wr + i * 16 + lrow][kb]);
            bh[i] = *reinterpret_cast<const bf16x8*>(&Bs_h[wc + i * 16 + lrow][kb]);
            bl[i] = *reinterpret_cast<const bf16x8*>(&Bs_l[wc + i * 16 + lrow][kb]);
        }
#pragma unroll
        for (int i = 0; i < 4; i++)
#pragma unroll
            for (int j = 0; j < 4; j++) {
                acc[i][j] = __builtin_amdgcn_mfma_f32_16x16x32_bf16(ah[i], bh[j], acc[i][j], 0, 0, 0);
                acc[i][j] = __builtin_amdgcn_mfma_f32_16x16x32_bf16(ah[i], bl[j], acc[i][j], 0, 0, 0);
                acc[i][j] = __builtin_amdgcn_mfma_f32_16x16x32_bf16(al[i], bh[j], acc[i][j], 0, 0, 0);
            }
    }
    float* qp = qpart + (size_t)blockIdx.x * M1;
#pragma unroll
    for (int i = 0; i < 4; i++) {
#pragma unroll
        for (int reg = 0; reg < 4; reg++) {
            const int gm = row0 + wr + i * 16 + (lane >> 4) * 4 + reg;
            float part = 0.f;
#pragma unroll
            for (int j = 0; j < 4; j++) {
                const int gn = col0 + wc + j * 16 + lrow;
                const float xv = (gn < CC) ? xsrc[(size_t)gm * CC + gn] : 0.f;
                part += acc[i][j][reg] * xv;
            }
#pragma unroll
            for (int o = 1; o < 16; o <<= 1) part += __shfl_xor(part, o, 64);
            if ((lane & 15) == 0) atomicAdd(&qp[gm], part);  // 2 commutative adds/cell: deterministic
        }
    }
}

// ---------- center row -> fp64 normalized (one block per batch) ----------
__global__ __launch_bounds__(256) void center_kernel(const float* __restrict__ x,
                                                     double* __restrict__ xcn) {
    __shared__ double red[4];
    const int b = blockIdx.x, tid = threadIdx.x;
    const float* xc = x + ((size_t)(b * LL + LL / 2)) * CC;
    double s = 0.0;
    for (int c = tid; c < CC; c += 256) { double v = xc[c]; s += v * v; }
#pragma unroll
    for (int o = 32; o > 0; o >>= 1) s += __shfl_down(s, o, 64);
    if ((tid & 63) == 0) red[tid >> 6] = s;
    __syncthreads();
    const double tot = red[0] + red[1] + red[2] + red[3];
    const double invc = 1.0 / (sqrt(tot / (double)CC) + 1e-6);
    for (int c = tid; c < CC; c += 256) xcn[(size_t)b * CC + c] = (double)xc[c] * invc;
}

// ---------- t1[b][e] = <W'_e, xcn_b>, one wave per (b,e) ----------
__global__ __launch_bounds__(256) void gram1_kernel(const float* __restrict__ winp,
                                                    const double* __restrict__ xcn,
                                                    double* __restrict__ t1) {
    const int b = blockIdx.y;
    const int wave = threadIdx.x >> 6, lane = threadIdx.x & 63;
    const int e = blockIdx.x * 4 + wave;
    const float* wr = winp + (size_t)e * CC;
    const double* xb = xcn + (size_t)b * CC;
    double s = 0.0;
    for (int c = lane; c < CC; c += 64) s += (double)wr[c] * xb[c];
#pragma unroll
    for (int o = 32; o > 0; o >>= 1) s += __shfl_down(s, o, 64);
    if (lane == 0) t1[(size_t)b * EE + e] = s;
}

// ---------- g[b][c] = <W'T_c, t1_b>, one wave per (b,c) ----------
__global__ __launch_bounds__(256) void gram2_kernel(const float* __restrict__ winpT,
                                                    const double* __restrict__ t1,
                                                    double* __restrict__ g) {
    const int b = blockIdx.y;
    const int wave = threadIdx.x >> 6, lane = threadIdx.x & 63;
    const int c = blockIdx.x * 4 + wave;
    if (c >= CC) return;
    const float* wr = winpT + (size_t)c * EE;
    const double* tb = t1 + (size_t)b * EE;
    double s = 0.0;
    for (int e = lane; e < EE; e += 64) s += (double)wr[e] * tb[e];
#pragma unroll
    for (int o = 32; o > 0; o >>= 1) s += __shfl_down(s, o, 64);
    if (lane == 0) g[(size_t)b * CC + c] = s;
}

// ---------- sim_r = <x_r, g_b> / sqrt(q_r)  (inv_r cancels exactly) ----------
__global__ __launch_bounds__(256) void dotsim_kernel(const float* __restrict__ x,
                                                     const double* __restrict__ g,
                                                     const float* __restrict__ qpart,
                                                     float* __restrict__ sim) {
    __shared__ double redd[4];
    const int r = blockIdx.x, tid = threadIdx.x;
    const int b = r >> 12;
    const float* xr = x + (size_t)r * CC;
    const double* gb = g + (size_t)b * CC;
    double d = 0.0;
    for (int c = tid; c < CC; c += 256) d += (double)xr[c] * gb[c];
#pragma unroll
    for (int o = 32; o > 0; o >>= 1) d += __shfl_down(d, o, 64);
    if ((tid & 63) == 0) redd[tid >> 6] = d;
    __syncthreads();
    if (tid == 0) {
        double dt = redd[0] + redd[1] + redd[2] + redd[3];
        double q = 0.0;
#pragma unroll
        for (int t5 = 0; t5 < NQT; t5++) q += (double)qpart[(size_t)t5 * M1 + r];
        sim[r] = (float)(dt / sqrt(fmax(q, 1e-30)));
    }
}

// ---------------- top-k via full bitonic sort of (value desc, idx asc) keys ----------------
__global__ __launch_bounds__(1024) void topk_kernel(const float* __restrict__ sim,
                                                    int* __restrict__ idx) {
    __shared__ unsigned long long keys[4096];
    const int b = blockIdx.x;
    for (int i = threadIdx.x; i < 4096; i += 1024) {
        unsigned u = __float_as_uint(sim[b * 4096 + i]);
        u = (u & 0x80000000u) ? ~u : (u | 0x80000000u);
        keys[i] = ((unsigned long long)(~u) << 32) | (unsigned)i;
    }
    __syncthreads();
    for (int size = 2; size <= 4096; size <<= 1) {
        for (int stride = size >> 1; stride > 0; stride >>= 1) {
#pragma unroll 1
            for (int t = threadIdx.x; t < 2048; t += 1024) {
                int low = t & (stride - 1);
                int pos = ((t - low) << 1) + low;
                bool up = ((pos & size) == 0);
                unsigned long long ka = keys[pos], kb = keys[pos + stride];
                if ((ka > kb) == up) { keys[pos] = kb; keys[pos + stride] = ka; }
            }
            __syncthreads();
        }
    }
    for (int t = threadIdx.x; t < KT; t += 1024) idx[b * KT + t] = (int)(keys[t] & 0xffffffffu);
}

// ---------- gather selected x rows (hi/lo) + inv; rows >= M2 zeroed ----------
__global__ __launch_bounds__(256) void gatherx_kernel(const ushort* __restrict__ xh,
                                                      const ushort* __restrict__ xl,
                                                      const float* __restrict__ inv,
                                                      const int* __restrict__ idx,
                                                      ushort* __restrict__ sh,
                                                      ushort* __restrict__ sl,
                                                      float* __restrict__ invsel) {
    const int r = blockIdx.x, t = threadIdx.x;
    if (r >= M2) {
        if (t < 144) {
            reinterpret_cast<ushort4*>(sh + (size_t)r * KP)[t] = make_ushort4(0, 0, 0, 0);
            reinterpret_cast<ushort4*>(sl + (size_t)r * KP)[t] = make_ushort4(0, 0, 0, 0);
        }
        return;
    }
    const int b = r / KT;
    const int src = b * LL + idx[r];
    if (t < 144) {
        reinterpret_cast<ushort4*>(sh + (size_t)r * KP)[t] =
            reinterpret_cast<const ushort4*>(xh + (size_t)src * KP)[t];
        reinterpret_cast<ushort4*>(sl + (size_t)r * KP)[t] =
            reinterpret_cast<const ushort4*>(xl + (size_t)src * KP)[t];
    }
    if (t == 0) invsel[r] = inv[src];
}

// ---------- composed taps: K19[m][e] = sum_i conv_w'[e][i] * (sigC[e].A^(m-i).sigB) ----------
__global__ __launch_bounds__(256) void taps19_kernel(const float* __restrict__ A,
                                                     const float* __restrict__ Bp,
                                                     const float* __restrict__ Cp,
                                                     const float* __restrict__ conv_w,
                                                     float* __restrict__ ck19) {
    __shared__ float Ash[256];
    __shared__ float vmat[JT][16];
    const int t = threadIdx.x;
    Ash[t] = A[t];
    __syncthreads();
    if (t < 16) vmat[0][t] = 1.f / (1.f + expf(-Bp[t]));
    __syncthreads();
    for (int j = 1; j < JT; j++) {
        float nv = 0.f;
        if (t < 16) {
#pragma unroll
            for (int s2 = 0; s2 < 16; s2++) nv += Ash[t * 16 + s2] * vmat[j - 1][s2];
        }
        __syncthreads();
        if (t < 16) vmat[j][t] = nv;
        __syncthreads();
    }
    for (int e = t; e < EE; e += 256) {
        float sc[16];
#pragma unroll
        for (int s = 0; s < 16; s++) sc[s] = 1.f / (1.f + expf(-Cp[e * 16 + s]));
        float ck[JT];
#pragma unroll
        for (int j = 0; j < JT; j++) {
            float kk = 0.f;
#pragma unroll
            for (int s = 0; s < 16; s++) kk += sc[s] * vmat[j][s];
            ck[j] = kk;
        }
        float w4[4];
#pragma unroll
        for (int i = 0; i < 4; i++) w4[i] = conv_w[e * 4 + 3 - i];
#pragma unroll
        for (int m = 0; m < JC; m++) {
            float kk = 0.f;
#pragma unroll
            for (int i = 0; i < 4; i++) {
                int jm = m - i;
                if (jm >= 0 && jm < JT) kk += w4[i] * ck[jm];
            }
            ck19[m * EE + e] = kk;
        }
    }
}

// ---------- 19-tap causal depthwise conv on selected rows -> bf16 hi/lo for GEMM2 ----------
__global__ __launch_bounds__(256) void conv19_kernel(const float* __restrict__ xps,
                                                     const float* __restrict__ ck19,
                                                     ushort* __restrict__ oh,
                                                     ushort* __restrict__ ol) {
    const int r = blockIdx.x, t = threadIdx.x;
    ushort* ph = oh + (size_t)r * KP2;
    ushort* pl = ol + (size_t)r * KP2;
    if (r >= M2) {
        for (int e = t; e < KP2; e += 256) { ph[e] = 0; pl[e] = 0; }
        return;
    }
    const int b = r / KT, tt = r - b * KT;
    const int jmax = (tt < JC - 1) ? tt : (JC - 1);
    const float* base = xps + (size_t)r * EE;
    for (int e = t; e < KP2; e += 256) {
        float y = 0.f;
        if (e < EE) {
            const float* bp = base + e;
            for (int j = 0; j <= jmax; j++) y += ck19[j * EE + e] * bp[-(ptrdiff_t)j * EE];
        }
        ushort h = f2bf(y);
        ph[e] = h;
        pl[e] = f2bf(y - bf2f(h));
    }
}

// ---------------- out = x (copy), then scatter-add x_proc rows ----------------
__global__ void copy4_kernel(const float4* __restrict__ src, float4* __restrict__ dst, int n4) {
    int i = blockIdx.x * blockDim.x + threadIdx.x;
    int stride = gridDim.x * blockDim.x;
    for (; i < n4; i += stride) dst[i] = src[i];
}

__global__ __launch_bounds__(256) void scatter_kernel(const float* __restrict__ xproc,
                                                      const int* __restrict__ idx,
                                                      float* __restrict__ out) {
    int t = blockIdx.x, b = blockIdx.y;
    int row = idx[b * KT + t];
    const float* src = xproc + ((size_t)(b * KT + t)) * CC;
    float* dst = out + ((size_t)(b * LL + row)) * CC;
    for (int d = threadIdx.x; d < CC; d += 256) dst[d] += src[d];
}

extern "C" void kernel_launch(void* const* d_in, const int* in_sizes, int n_in,
                              void* d_out, int out_size, void* d_ws, size_t ws_size,
                              hipStream_t stream) {
    const float* x      = (const float*)d_in[0];
    const float* norm_w = (const float*)d_in[1];
    const float* w_in   = (const float*)d_in[2];
    const float* b_in   = (const float*)d_in[3];
    const float* w_out  = (const float*)d_in[4];
    const float* b_out  = (const float*)d_in[5];
    const float* Amat   = (const float*)d_in[6];
    const float* Bp     = (const float*)d_in[7];
    const float* Cp     = (const float*)d_in[8];
    const float* conv_w = (const float*)d_in[9];
    float* out = (float*)d_out;

    char* wsb = (char*)d_ws;
    size_t off = 0;
    auto take = [&](size_t bytes) {
        void* p = wsb + off;
        off += (bytes + 255) & ~(size_t)255;
        return p;
    };
    ushort* xh    = (ushort*)take((size_t)M1 * KP * 2);       // 37.7 MB
    ushort* xl    = (ushort*)take((size_t)M1 * KP * 2);       // 37.7 MB
    float*  winp  = (float*)take((size_t)EE * CC * 4);
    float*  winpT = (float*)take((size_t)EE * CC * 4);
    ushort* wh    = (ushort*)take((size_t)1152 * KP * 2);
    ushort* wl    = (ushort*)take((size_t)1152 * KP * 2);
    ushort* w2h   = (ushort*)take((size_t)640 * KP2 * 2);
    ushort* w2l   = (ushort*)take((size_t)640 * KP2 * 2);
    ushort* wth   = (ushort*)take((size_t)640 * KP2 * 2);
    ushort* wtl   = (ushort*)take((size_t)640 * KP2 * 2);
    float*  G     = (float*)take((size_t)640 * CC * 4);
    ushort* Gh    = (ushort*)take((size_t)640 * KP * 2);
    ushort* Gl    = (ushort*)take((size_t)640 * KP * 2);
    float*  inv   = (float*)take((size_t)M1 * 4);
    float*  qpart = (float*)take((size_t)NQT * M1 * 4);
    float*  simv  = (float*)take((size_t)M1 * 4);
    int*    idxb  = (int*)take((size_t)BB * KT * 4);
    double* gbuf  = (double*)take((size_t)BB * CC * 8);
    double* xcn   = (double*)take((size_t)BB * CC * 8);
    double* t1b   = (double*)take((size_t)BB * EE * 8);
    float*  ck19  = (float*)take((size_t)JC * EE * 4);
    ushort* sh    = (ushort*)take((size_t)M2P * KP * 2);
    ushort* sl    = (ushort*)take((size_t)M2P * KP * 2);
    float*  invsel= (float*)take((size_t)M2P * 4);
    float*  xps   = (float*)take((size_t)M2P * EE * 4);
    ushort* o2h   = (ushort*)take((size_t)M2P * KP2 * 2);
    ushort* o2l   = (ushort*)take((size_t)M2P * KP2 * 2);
    float*  xproc = (float*)take((size_t)M2P * CC * 4);
    (void)ws_size;

    // --- prep ---
    zero_kernel<<<(NQT * M1 + 255) / 256, 256, 0, stream>>>(qpart, NQT * M1);
    winp_kernel<<<(EE * CC + 255) / 256, 256, 0, stream>>>(w_in, norm_w, winp, winpT, EE * CC);
    convw_kernel<<<1152, 256, 0, stream>>>(winp, EE, wh, wl);
    w2conv_kernel<<<640, 256, 0, stream>>>(w_out, w2h, w2l);
    w2conv_kernel<<<640, 256, 0, stream>>>(winpT, wth, wtl);
    taps19_kernel<<<1, 256, 0, stream>>>(Amat, Bp, Cp, conv_w, ck19);
    convx_kernel<<<M1, 256, 0, stream>>>(x, xh, xl, inv);

    // --- G = W'^T W' (split-bf16), converted for gemmq B-operand ---
    dim3 gG(5, 5);
    gemm_mfma<<<gG, 256, 0, stream>>>(wth, wtl, wth, wtl, nullptr, nullptr, G,
                                      CC, CC, CC, KP2, 0);
    convw_kernel<<<640, 256, 0, stream>>>(G, CC, Gh, Gl);

    // --- q_r = x_r^T G x_r (fused; y never materialized) ---
    dim3 gq(NQT, M1 / 128);
    gemm_mfma_q<<<gq, 256, 0, stream>>>(xh, xl, Gh, Gl, x, qpart);

    // --- sim + topk ---
    center_kernel<<<BB, 256, 0, stream>>>(x, xcn);
    dim3 gg1(EE / 4, BB);
    gram1_kernel<<<gg1, 256, 0, stream>>>(winp, xcn, t1b);
    dim3 gg2(CC / 4, BB);
    gram2_kernel<<<gg2, 256, 0, stream>>>(winpT, t1b, gbuf);
    dotsim_kernel<<<M1, 256, 0, stream>>>(x, gbuf, qpart, simv);
    topk_kernel<<<BB, 1024, 0, stream>>>(simv, idxb);

    // --- selected rows only: xproj_sel = inv*(x_sel@W'^T) + b_in ---
    gatherx_kernel<<<M2P, 256, 0, stream>>>(xh, xl, inv, idxb, sh, sl, invsel);
    dim3 g1(9, M2P / 128);
    gemm_mfma<<<g1, 256, 0, stream>>>(sh, sl, wh, wl, invsel, b_in, xps,
                                      EE, M2, EE, KP, 0);

    // --- conv4 ∘ ssm16 = single 19-tap depthwise causal conv ---
    conv19_kernel<<<M2P, 256, 0, stream>>>(xps, ck19, o2h, o2l);

    // --- gemm2 + output assembly ---
    dim3 g3(5, M2P / 128);
    gemm_mfma<<<g3, 256, 0, stream>>>(o2h, o2l, w2h, w2l, nullptr, b_out, xproc,
                                      CC, M2, CC, KP2, 0);

    copy4_kernel<<<2048, 256, 0, stream>>>((const float4*)x, (float4*)out, out_size / 4);
    dim3 g2(KT, BB);
    scatter_kernel<<<g2, 256, 0, stream>>>(xproc, idxb, out);
}

// Round 7
// 471.695 us; speedup vs baseline: 2.5954x; 1.0536x over previous
//
#include <hip/hip_runtime.h>
#include <hip/hip_bf16.h>

// Problem constants (fixed by reference)
#define BB 8
#define LL 4096
#define CC 552      // DIM
#define EE 1104     // EXP
#define KT 409      // top-k
#define M1 32768    // B*L
#define M2 3272     // B*KT
#define KP 576      // K padded (gemm over DIM)
#define KP2 1120    // K padded (gemm over EXP)
#define M2P 3328    // M2 padded to 26*128
#define JT 16       // SSM truncation taps (||A||^16 ~ 2e-13)
#define JC 19       // composed conv4 * ssm16 taps
#define NQT 5       // col tiles in gemmq (640/128)

typedef __attribute__((ext_vector_type(8))) short bf16x8;
typedef __attribute__((ext_vector_type(4))) float f32x4;

__device__ __forceinline__ ushort f2bf(float f) {
    unsigned u = __float_as_uint(f);
    return (ushort)((u + 0x7FFFu + ((u >> 16) & 1u)) >> 16);  // RNE
}
__device__ __forceinline__ float bf2f(ushort h) {
    return __uint_as_float(((unsigned)h) << 16);
}

__global__ void zero_kernel(float* __restrict__ p, int n) {
    int i = blockIdx.x * blockDim.x + threadIdx.x;
    if (i < n) p[i] = 0.f;
}

// ---------- W' = w_in * norm_w (fp32) + transposed copy ----------
__global__ void winp_kernel(const float* __restrict__ w_in, const float* __restrict__ norm_w,
                            float* __restrict__ winp, float* __restrict__ winpT, int n) {
    int i = blockIdx.x * blockDim.x + threadIdx.x;
    if (i < n) {
        int c = i % CC, e = i / CC;
        float v = w_in[i] * norm_w[c];
        winp[i] = v;
        winpT[(size_t)c * EE + e] = v;
    }
}

// ---------- convert x rows -> bf16 hi/lo [M1][KP] + fused 1/(rms+eps) ----------
__global__ __launch_bounds__(256) void convx_kernel(const float* __restrict__ x,
                                                    ushort* __restrict__ xh, ushort* __restrict__ xl,
                                                    float* __restrict__ inv) {
    __shared__ float red[4];
    const int r = blockIdx.x;
    const float* xr = x + (size_t)r * CC;
    ushort* oh = xh + (size_t)r * KP;
    ushort* ol = xl + (size_t)r * KP;
    const int t = threadIdx.x;
    float s = 0.f;
    if (t < 144) {
        float4 v = make_float4(0.f, 0.f, 0.f, 0.f);
        if (t < 138) v = reinterpret_cast<const float4*>(xr)[t];
        s = v.x * v.x + v.y * v.y + v.z * v.z + v.w * v.w;
        ushort4 h, l;
        h.x = f2bf(v.x); l.x = f2bf(v.x - bf2f(h.x));
        h.y = f2bf(v.y); l.y = f2bf(v.y - bf2f(h.y));
        h.z = f2bf(v.z); l.z = f2bf(v.z - bf2f(h.z));
        h.w = f2bf(v.w); l.w = f2bf(v.w - bf2f(h.w));
        reinterpret_cast<ushort4*>(oh)[t] = h;
        reinterpret_cast<ushort4*>(ol)[t] = l;
    }
#pragma unroll
    for (int o = 32; o > 0; o >>= 1) s += __shfl_down(s, o, 64);
    if ((t & 63) == 0) red[t >> 6] = s;
    __syncthreads();
    if (t == 0) {
        float tot = red[0] + red[1] + red[2] + red[3];
        inv[r] = 1.f / (sqrtf(tot / (float)CC) + 1e-6f);
    }
}

// ---------- convert [*][CC] fp32 rows -> bf16 hi/lo [grid][KP]; rows >= nvalid zeroed ----------
__global__ __launch_bounds__(256) void convw_kernel(const float* __restrict__ src, int nvalid,
                                                    ushort* __restrict__ wh, ushort* __restrict__ wl) {
    const int n = blockIdx.x, t = threadIdx.x;
    if (t >= 144) return;
    float4 v = make_float4(0.f, 0.f, 0.f, 0.f);
    if (n < nvalid && t < 138) v = reinterpret_cast<const float4*>(src + (size_t)n * CC)[t];
    ushort4 h, l;
    h.x = f2bf(v.x); l.x = f2bf(v.x - bf2f(h.x));
    h.y = f2bf(v.y); l.y = f2bf(v.y - bf2f(h.y));
    h.z = f2bf(v.z); l.z = f2bf(v.z - bf2f(h.z));
    h.w = f2bf(v.w); l.w = f2bf(v.w - bf2f(h.w));
    reinterpret_cast<ushort4*>(wh + (size_t)n * KP)[t] = h;
    reinterpret_cast<ushort4*>(wl + (size_t)n * KP)[t] = l;
}

// ---------- triangular-masked conversion of G: Ghat[n][k] = G[n][k]*(n>k?2:n==k?1:0) ----------
__global__ __launch_bounds__(256) void convG_kernel(const float* __restrict__ G,
                                                    ushort* __restrict__ gh, ushort* __restrict__ gl) {
    const int n = blockIdx.x, t = threadIdx.x;
    if (t >= 144) return;
    float4 v = make_float4(0.f, 0.f, 0.f, 0.f);
    if (n < CC && t < 138) {
        v = reinterpret_cast<const float4*>(G + (size_t)n * CC)[t];
        const int k0 = t * 4;
        float m0 = (n > k0 + 0) ? 2.f : (n == k0 + 0) ? 1.f : 0.f;
        float m1 = (n > k0 + 1) ? 2.f : (n == k0 + 1) ? 1.f : 0.f;
        float m2 = (n > k0 + 2) ? 2.f : (n == k0 + 2) ? 1.f : 0.f;
        float m3 = (n > k0 + 3) ? 2.f : (n == k0 + 3) ? 1.f : 0.f;
        v = make_float4(v.x * m0, v.y * m1, v.z * m2, v.w * m3);
    }
    ushort4 h, l;
    h.x = f2bf(v.x); l.x = f2bf(v.x - bf2f(h.x));
    h.y = f2bf(v.y); l.y = f2bf(v.y - bf2f(h.y));
    h.z = f2bf(v.z); l.z = f2bf(v.z - bf2f(h.z));
    h.w = f2bf(v.w); l.w = f2bf(v.w - bf2f(h.w));
    reinterpret_cast<ushort4*>(gh + (size_t)n * KP)[t] = h;
    reinterpret_cast<ushort4*>(gl + (size_t)n * KP)[t] = l;
}

// ---------- convert [*][EE] fp32 rows -> bf16 hi/lo [grid][KP2]; rows >= CC zeroed ----------
__global__ __launch_bounds__(256) void w2conv_kernel(const float* __restrict__ src,
                                                     ushort* __restrict__ wh, ushort* __restrict__ wl) {
    const int n = blockIdx.x, t = threadIdx.x;
    for (int i = t; i < KP2 / 4; i += 256) {
        float4 v = make_float4(0.f, 0.f, 0.f, 0.f);
        if (n < CC && i < EE / 4) v = reinterpret_cast<const float4*>(src + (size_t)n * EE)[i];
        ushort4 h, l;
        h.x = f2bf(v.x); l.x = f2bf(v.x - bf2f(h.x));
        h.y = f2bf(v.y); l.y = f2bf(v.y - bf2f(h.y));
        h.z = f2bf(v.z); l.z = f2bf(v.z - bf2f(h.z));
        h.w = f2bf(v.w); l.w = f2bf(v.w - bf2f(h.w));
        reinterpret_cast<ushort4*>(wh + (size_t)n * KP2)[i] = h;
        reinterpret_cast<ushort4*>(wl + (size_t)n * KP2)[i] = l;
    }
}

// ---------- unified split-bf16 MFMA GEMM: C = rowscale[m]*(A@B^T) + bias[n] ----------
__global__ __launch_bounds__(256) void gemm_mfma(
    const ushort* __restrict__ Ah, const ushort* __restrict__ Al,   // [Mp][Kp]
    const ushort* __restrict__ Bh, const ushort* __restrict__ Bl,   // [Np][Kp]
    const float* __restrict__ rowscale, const float* __restrict__ bias,
    float* __restrict__ C, int ldc, int M, int N, int Kp, int r0) {
    __shared__ ushort As_h[128][40];
    __shared__ ushort As_l[128][40];
    __shared__ ushort Bs_h[128][40];
    __shared__ ushort Bs_l[128][40];
    const int tid = threadIdx.x;
    const int col0 = blockIdx.x * 128;
    const int row0 = blockIdx.y * 128;
    const int wave = tid >> 6, lane = tid & 63;
    const int wr = (wave >> 1) * 64, wc = (wave & 1) * 64;
    const int sr = tid >> 2, sk = (tid & 3) * 8;
    const int lrow = lane & 15, kb = (lane >> 4) * 8;

    f32x4 acc[4][4];
    const f32x4 zero = {0.f, 0.f, 0.f, 0.f};
#pragma unroll
    for (int i = 0; i < 4; i++)
#pragma unroll
        for (int j = 0; j < 4; j++) acc[i][j] = zero;

    for (int k0 = 0; k0 < Kp; k0 += 32) {
        int4 vah0 = *reinterpret_cast<const int4*>(Ah + (size_t)(row0 + sr) * Kp + k0 + sk);
        int4 vah1 = *reinterpret_cast<const int4*>(Ah + (size_t)(row0 + sr + 64) * Kp + k0 + sk);
        int4 val0 = *reinterpret_cast<const int4*>(Al + (size_t)(row0 + sr) * Kp + k0 + sk);
        int4 val1 = *reinterpret_cast<const int4*>(Al + (size_t)(row0 + sr + 64) * Kp + k0 + sk);
        int4 vbh0 = *reinterpret_cast<const int4*>(Bh + (size_t)(col0 + sr) * Kp + k0 + sk);
        int4 vbh1 = *reinterpret_cast<const int4*>(Bh + (size_t)(col0 + sr + 64) * Kp + k0 + sk);
        int4 vbl0 = *reinterpret_cast<const int4*>(Bl + (size_t)(col0 + sr) * Kp + k0 + sk);
        int4 vbl1 = *reinterpret_cast<const int4*>(Bl + (size_t)(col0 + sr + 64) * Kp + k0 + sk);
        __syncthreads();
        *reinterpret_cast<int4*>(&As_h[sr][sk]) = vah0;
        *reinterpret_cast<int4*>(&As_h[sr + 64][sk]) = vah1;
        *reinterpret_cast<int4*>(&As_l[sr][sk]) = val0;
        *reinterpret_cast<int4*>(&As_l[sr + 64][sk]) = val1;
        *reinterpret_cast<int4*>(&Bs_h[sr][sk]) = vbh0;
        *reinterpret_cast<int4*>(&Bs_h[sr + 64][sk]) = vbh1;
        *reinterpret_cast<int4*>(&Bs_l[sr][sk]) = vbl0;
        *reinterpret_cast<int4*>(&Bs_l[sr + 64][sk]) = vbl1;
        __syncthreads();
        bf16x8 ah[4], al[4], bh[4], bl[4];
#pragma unroll
        for (int i = 0; i < 4; i++) {
            ah[i] = *reinterpret_cast<const bf16x8*>(&As_h[wr + i * 16 + lrow][kb]);
            al[i] = *reinterpret_cast<const bf16x8*>(&As_l[wr + i * 16 + lrow][kb]);
            bh[i] = *reinterpret_cast<const bf16x8*>(&Bs_h[wc + i * 16 + lrow][kb]);
            bl[i] = *reinterpret_cast<const bf16x8*>(&Bs_l[wc + i * 16 + lrow][kb]);
        }
#pragma unroll
        for (int i = 0; i < 4; i++)
#pragma unroll
            for (int j = 0; j < 4; j++) {
                acc[i][j] = __builtin_amdgcn_mfma_f32_16x16x32_bf16(ah[i], bh[j], acc[i][j], 0, 0, 0);
                acc[i][j] = __builtin_amdgcn_mfma_f32_16x16x32_bf16(ah[i], bl[j], acc[i][j], 0, 0, 0);
                acc[i][j] = __builtin_amdgcn_mfma_f32_16x16x32_bf16(al[i], bh[j], acc[i][j], 0, 0, 0);
            }
    }
    // epilogue: C/D layout col=lane&15, row=(lane>>4)*4+reg  [m89-verified]
#pragma unroll
    for (int i = 0; i < 4; i++) {
        const int gmb = r0 + row0 + wr + i * 16 + (lane >> 4) * 4;
#pragma unroll
        for (int reg = 0; reg < 4; reg++) {
            const int gm = gmb + reg;
            if (gm < M) {
                const float rs = rowscale ? rowscale[gm] : 1.f;
#pragma unroll
                for (int j = 0; j < 4; j++) {
                    const int gn = col0 + wc + j * 16 + lrow;
                    if (gn < N) C[(size_t)gm * ldc + gn] = acc[i][j][reg] * rs + (bias ? bias[gn] : 0.f);
                }
            }
        }
    }
}

// ---------- gemmq: y = x@Ghat with fused q_m = sum_n y[m,n]*x[m,n]; y never stored ----------
// Ghat is triangular-masked (2L+D): k-tiles above the diagonal are zero -> K-loop ends at col0+128.
__global__ __launch_bounds__(256) void gemm_mfma_q(
    const ushort* __restrict__ Ah, const ushort* __restrict__ Al,   // x hi/lo [M1][KP]
    const ushort* __restrict__ Bh, const ushort* __restrict__ Bl,   // Ghat hi/lo [640][KP]
    const float* __restrict__ xsrc, float* __restrict__ qpart) {
    __shared__ ushort As_h[128][40];
    __shared__ ushort As_l[128][40];
    __shared__ ushort Bs_h[128][40];
    __shared__ ushort Bs_l[128][40];
    const int tid = threadIdx.x;
    const int col0 = blockIdx.x * 128;
    const int row0 = blockIdx.y * 128;
    const int kend = (KP < col0 + 128) ? KP : (col0 + 128);   // triangular cut
    const int wave = tid >> 6, lane = tid & 63;
    const int wr = (wave >> 1) * 64, wc = (wave & 1) * 64;
    const int sr = tid >> 2, sk = (tid & 3) * 8;
    const int lrow = lane & 15, kb = (lane >> 4) * 8;

    f32x4 acc[4][4];
    const f32x4 zero = {0.f, 0.f, 0.f, 0.f};
#pragma unroll
    for (int i = 0; i < 4; i++)
#pragma unroll
        for (int j = 0; j < 4; j++) acc[i][j] = zero;

    for (int k0 = 0; k0 < kend; k0 += 32) {
        int4 vah0 = *reinterpret_cast<const int4*>(Ah + (size_t)(row0 + sr) * KP + k0 + sk);
        int4 vah1 = *reinterpret_cast<const int4*>(Ah + (size_t)(row0 + sr + 64) * KP + k0 + sk);
        int4 val0 = *reinterpret_cast<const int4*>(Al + (size_t)(row0 + sr) * KP + k0 + sk);
        int4 val1 = *reinterpret_cast<const int4*>(Al + (size_t)(row0 + sr + 64) * KP + k0 + sk);
        int4 vbh0 = *reinterpret_cast<const int4*>(Bh + (size_t)(col0 + sr) * KP + k0 + sk);
        int4 vbh1 = *reinterpret_cast<const int4*>(Bh + (size_t)(col0 + sr + 64) * KP + k0 + sk);
        int4 vbl0 = *reinterpret_cast<const int4*>(Bl + (size_t)(col0 + sr) * KP + k0 + sk);
        int4 vbl1 = *reinterpret_cast<const int4*>(Bl + (size_t)(col0 + sr + 64) * KP + k0 + sk);
        __syncthreads();
        *reinterpret_cast<int4*>(&As_h[sr][sk]) = vah0;
        *reinterpret_cast<int4*>(&As_h[sr + 64][sk]) = vah1;
        *reinterpret_cast<int4*>(&As_l[sr][sk]) = val0;
        *reinterpret_cast<int4*>(&As_l[sr + 64][sk]) = val1;
        *reinterpret_cast<int4*>(&Bs_h[sr][sk]) = vbh0;
        *reinterpret_cast<int4*>(&Bs_h[sr + 64][sk]) = vbh1;
        *reinterpret_cast<int4*>(&Bs_l[sr][sk]) = vbl0;
        *reinterpret_cast<int4*>(&Bs_l[sr + 64][sk]) = vbl1;
        __syncthreads();
        bf16x8 ah[4], al[4], bh[4], bl[4];
#pragma unroll
        for (int i = 0; i < 4; i++) {
            ah[i] = *reinterpret_cast<const bf16x8*>(&As_h[wr + i * 16 + lrow][kb]);
            al[i] = *reinterpret_cast<const bf16x8*>(&As_l[wr + i * 16 + lrow][kb]);
            bh[i] = *reinterpret_cast<const bf16x8*>(&Bs_h[wc + i * 16 + lrow][kb]);
            bl[i] = *reinterpret_cast<const bf16x8*>(&Bs_l[wc + i * 16 + lrow][kb]);
        }
#pragma unroll
        for (int i = 0; i < 4; i++)
#pragma unroll
            for (int j = 0; j < 4; j++) {
                acc[i][j] = __builtin_amdgcn_mfma_f32_16x16x32_bf16(ah[i], bh[j], acc[i][j], 0, 0, 0);
                acc[i][j] = __builtin_amdgcn_mfma_f32_16x16x32_bf16(ah[i], bl[j], acc[i][j], 0, 0, 0);
                acc[i][j] = __builtin_amdgcn_mfma_f32_16x16x32_bf16(al[i], bh[j], acc[i][j], 0, 0, 0);
            }
    }
    float* qp = qpart + (size_t)blockIdx.x * M1;
#pragma unroll
    for (int i = 0; i < 4; i++) {
#pragma unroll
        for (int reg = 0; reg < 4; reg++) {
            const int gm = row0 + wr + i * 16 + (lane >> 4) * 4 + reg;
            float part = 0.f;
#pragma unroll
            for (int j = 0; j < 4; j++) {
                const int gn = col0 + wc + j * 16 + lrow;
                const float xv = (gn < CC) ? xsrc[(size_t)gm * CC + gn] : 0.f;
                part += acc[i][j][reg] * xv;
            }
#pragma unroll
            for (int o = 1; o < 16; o <<= 1) part += __shfl_xor(part, o, 64);
            if ((lane & 15) == 0) atomicAdd(&qp[gm], part);  // 2 commutative adds/cell: deterministic
        }
    }
}

// ---------- center row -> fp64 normalized (one block per batch) ----------
__global__ __launch_bounds__(256) void center_kernel(const float* __restrict__ x,
                                                     double* __restrict__ xcn) {
    __shared__ double red[4];
    const int b = blockIdx.x, tid = threadIdx.x;
    const float* xc = x + ((size_t)(b * LL + LL / 2)) * CC;
    double s = 0.0;
    for (int c = tid; c < CC; c += 256) { double v = xc[c]; s += v * v; }
#pragma unroll
    for (int o = 32; o > 0; o >>= 1) s += __shfl_down(s, o, 64);
    if ((tid & 63) == 0) red[tid >> 6] = s;
    __syncthreads();
    const double tot = red[0] + red[1] + red[2] + red[3];
    const double invc = 1.0 / (sqrt(tot / (double)CC) + 1e-6);
    for (int c = tid; c < CC; c += 256) xcn[(size_t)b * CC + c] = (double)xc[c] * invc;
}

// ---------- t1[b][e] = <W'_e, xcn_b>, one wave per (b,e) ----------
__global__ __launch_bounds__(256) void gram1_kernel(const float* __restrict__ winp,
                                                    const double* __restrict__ xcn,
                                                    double* __restrict__ t1) {
    const int b = blockIdx.y;
    const int wave = threadIdx.x >> 6, lane = threadIdx.x & 63;
    const int e = blockIdx.x * 4 + wave;
    const float* wr = winp + (size_t)e * CC;
    const double* xb = xcn + (size_t)b * CC;
    double s = 0.0;
    for (int c = lane; c < CC; c += 64) s += (double)wr[c] * xb[c];
#pragma unroll
    for (int o = 32; o > 0; o >>= 1) s += __shfl_down(s, o, 64);
    if (lane == 0) t1[(size_t)b * EE + e] = s;
}

// ---------- g[b][c] = <W'T_c, t1_b>, one wave per (b,c) ----------
__global__ __launch_bounds__(256) void gram2_kernel(const float* __restrict__ winpT,
                                                    const double* __restrict__ t1,
                                                    double* __restrict__ g) {
    const int b = blockIdx.y;
    const int wave = threadIdx.x >> 6, lane = threadIdx.x & 63;
    const int c = blockIdx.x * 4 + wave;
    if (c >= CC) return;
    const float* wr = winpT + (size_t)c * EE;
    const double* tb = t1 + (size_t)b * EE;
    double s = 0.0;
    for (int e = lane; e < EE; e += 64) s += (double)wr[e] * tb[e];
#pragma unroll
    for (int o = 32; o > 0; o >>= 1) s += __shfl_down(s, o, 64);
    if (lane == 0) g[(size_t)b * CC + c] = s;
}

// ---------- sim_r = <x_r, g_b> / sqrt(q_r)  (inv_r cancels exactly) ----------
__global__ __launch_bounds__(256) void dotsim_kernel(const float* __restrict__ x,
                                                     const double* __restrict__ g,
                                                     const float* __restrict__ qpart,
                                                     float* __restrict__ sim) {
    __shared__ double redd[4];
    const int r = blockIdx.x, tid = threadIdx.x;
    const int b = r >> 12;
    const float* xr = x + (size_t)r * CC;
    const double* gb = g + (size_t)b * CC;
    double d = 0.0;
    for (int i = tid; i < 138; i += 256) {
        float4 xv = reinterpret_cast<const float4*>(xr)[i];
        const double* gp = gb + i * 4;
        d += (double)xv.x * gp[0] + (double)xv.y * gp[1] + (double)xv.z * gp[2] + (double)xv.w * gp[3];
    }
#pragma unroll
    for (int o = 32; o > 0; o >>= 1) d += __shfl_down(d, o, 64);
    if ((tid & 63) == 0) redd[tid >> 6] = d;
    __syncthreads();
    if (tid == 0) {
        double dt = redd[0] + redd[1] + redd[2] + redd[3];
        double q = 0.0;
#pragma unroll
        for (int t5 = 0; t5 < NQT; t5++) q += (double)qpart[(size_t)t5 * M1 + r];
        sim[r] = (float)(dt / sqrt(fmax(q, 1e-30)));
    }
}

// ---------------- top-k via full bitonic sort of (value desc, idx asc) keys ----------------
__global__ __launch_bounds__(1024) void topk_kernel(const float* __restrict__ sim,
                                                    int* __restrict__ idx) {
    __shared__ unsigned long long keys[4096];
    const int b = blockIdx.x;
    for (int i = threadIdx.x; i < 4096; i += 1024) {
        unsigned u = __float_as_uint(sim[b * 4096 + i]);
        u = (u & 0x80000000u) ? ~u : (u | 0x80000000u);
        keys[i] = ((unsigned long long)(~u) << 32) | (unsigned)i;
    }
    __syncthreads();
    for (int size = 2; size <= 4096; size <<= 1) {
        for (int stride = size >> 1; stride > 0; stride >>= 1) {
#pragma unroll 1
            for (int t = threadIdx.x; t < 2048; t += 1024) {
                int low = t & (stride - 1);
                int pos = ((t - low) << 1) + low;
                bool up = ((pos & size) == 0);
                unsigned long long ka = keys[pos], kb = keys[pos + stride];
                if ((ka > kb) == up) { keys[pos] = kb; keys[pos + stride] = ka; }
            }
            __syncthreads();
        }
    }
    for (int t = threadIdx.x; t < KT; t += 1024) idx[b * KT + t] = (int)(keys[t] & 0xffffffffu);
}

// ---------- gather selected x rows (hi/lo) + inv; rows >= M2 zeroed ----------
__global__ __launch_bounds__(256) void gatherx_kernel(const ushort* __restrict__ xh,
                                                      const ushort* __restrict__ xl,
                                                      const float* __restrict__ inv,
                                                      const int* __restrict__ idx,
                                                      ushort* __restrict__ sh,
                                                      ushort* __restrict__ sl,
                                                      float* __restrict__ invsel) {
    const int r = blockIdx.x, t = threadIdx.x;
    if (r >= M2) {
        if (t < 144) {
            reinterpret_cast<ushort4*>(sh + (size_t)r * KP)[t] = make_ushort4(0, 0, 0, 0);
            reinterpret_cast<ushort4*>(sl + (size_t)r * KP)[t] = make_ushort4(0, 0, 0, 0);
        }
        return;
    }
    const int b = r / KT;
    const int src = b * LL + idx[r];
    if (t < 144) {
        reinterpret_cast<ushort4*>(sh + (size_t)r * KP)[t] =
            reinterpret_cast<const ushort4*>(xh + (size_t)src * KP)[t];
        reinterpret_cast<ushort4*>(sl + (size_t)r * KP)[t] =
            reinterpret_cast<const ushort4*>(xl + (size_t)src * KP)[t];
    }
    if (t == 0) invsel[r] = inv[src];
}

// ---------- composed taps: K19[m][e] = sum_i conv_w'[e][i] * (sigC[e].A^(m-i).sigB) ----------
__global__ __launch_bounds__(256) void taps19_kernel(const float* __restrict__ A,
                                                     const float* __restrict__ Bp,
                                                     const float* __restrict__ Cp,
                                                     const float* __restrict__ conv_w,
                                                     float* __restrict__ ck19) {
    __shared__ float Ash[256];
    __shared__ float vmat[JT][16];
    const int t = threadIdx.x;
    Ash[t] = A[t];
    __syncthreads();
    if (t < 16) vmat[0][t] = 1.f / (1.f + expf(-Bp[t]));
    __syncthreads();
    for (int j = 1; j < JT; j++) {
        float nv = 0.f;
        if (t < 16) {
#pragma unroll
            for (int s2 = 0; s2 < 16; s2++) nv += Ash[t * 16 + s2] * vmat[j - 1][s2];
        }
        __syncthreads();
        if (t < 16) vmat[j][t] = nv;
        __syncthreads();
    }
    for (int e = t; e < EE; e += 256) {
        float sc[16];
#pragma unroll
        for (int s = 0; s < 16; s++) sc[s] = 1.f / (1.f + expf(-Cp[e * 16 + s]));
        float ck[JT];
#pragma unroll
        for (int j = 0; j < JT; j++) {
            float kk = 0.f;
#pragma unroll
            for (int s = 0; s < 16; s++) kk += sc[s] * vmat[j][s];
            ck[j] = kk;
        }
        float w4[4];
#pragma unroll
        for (int i = 0; i < 4; i++) w4[i] = conv_w[e * 4 + 3 - i];
#pragma unroll
        for (int m = 0; m < JC; m++) {
            float kk = 0.f;
#pragma unroll
            for (int i = 0; i < 4; i++) {
                int jm = m - i;
                if (jm >= 0 && jm < JT) kk += w4[i] * ck[jm];
            }
            ck19[m * EE + e] = kk;
        }
    }
}

// ---------- 19-tap causal depthwise conv on selected rows -> bf16 hi/lo for GEMM2 ----------
__global__ __launch_bounds__(256) void conv19_kernel(const float* __restrict__ xps,
                                                     const float* __restrict__ ck19,
                                                     ushort* __restrict__ oh,
                                                     ushort* __restrict__ ol) {
    const int r = blockIdx.x, t = threadIdx.x;
    ushort* ph = oh + (size_t)r * KP2;
    ushort* pl = ol + (size_t)r * KP2;
    if (r >= M2) {
        for (int e = t; e < KP2; e += 256) { ph[e] = 0; pl[e] = 0; }
        return;
    }
    const int b = r / KT, tt = r - b * KT;
    const int jmax = (tt < JC - 1) ? tt : (JC - 1);
    const float* base = xps + (size_t)r * EE;
    for (int e = t; e < KP2; e += 256) {
        float y = 0.f;
        if (e < EE) {
            const float* bp = base + e;
            for (int j = 0; j <= jmax; j++) y += ck19[j * EE + e] * bp[-(ptrdiff_t)j * EE];
        }
        ushort h = f2bf(y);
        ph[e] = h;
        pl[e] = f2bf(y - bf2f(h));
    }
}

// ---------------- out = x (copy), then scatter-add x_proc rows ----------------
__global__ void copy4_kernel(const float4* __restrict__ src, float4* __restrict__ dst, int n4) {
    int i = blockIdx.x * blockDim.x + threadIdx.x;
    int stride = gridDim.x * blockDim.x;
    for (; i < n4; i += stride) dst[i] = src[i];
}

__global__ __launch_bounds__(256) void scatter_kernel(const float* __restrict__ xproc,
                                                      const int* __restrict__ idx,
                                                      float* __restrict__ out) {
    int t = blockIdx.x, b = blockIdx.y;
    int row = idx[b * KT + t];
    const float* src = xproc + ((size_t)(b * KT + t)) * CC;
    float* dst = out + ((size_t)(b * LL + row)) * CC;
    for (int d = threadIdx.x; d < CC; d += 256) dst[d] += src[d];
}

extern "C" void kernel_launch(void* const* d_in, const int* in_sizes, int n_in,
                              void* d_out, int out_size, void* d_ws, size_t ws_size,
                              hipStream_t stream) {
    const float* x      = (const float*)d_in[0];
    const float* norm_w = (const float*)d_in[1];
    const float* w_in   = (const float*)d_in[2];
    const float* b_in   = (const float*)d_in[3];
    const float* w_out  = (const float*)d_in[4];
    const float* b_out  = (const float*)d_in[5];
    const float* Amat   = (const float*)d_in[6];
    const float* Bp     = (const float*)d_in[7];
    const float* Cp     = (const float*)d_in[8];
    const float* conv_w = (const float*)d_in[9];
    float* out = (float*)d_out;

    char* wsb = (char*)d_ws;
    size_t off = 0;
    auto take = [&](size_t bytes) {
        void* p = wsb + off;
        off += (bytes + 255) & ~(size_t)255;
        return p;
    };
    ushort* xh    = (ushort*)take((size_t)M1 * KP * 2);       // 37.7 MB
    ushort* xl    = (ushort*)take((size_t)M1 * KP * 2);       // 37.7 MB
    float*  winp  = (float*)take((size_t)EE * CC * 4);
    float*  winpT = (float*)take((size_t)EE * CC * 4);
    ushort* wh    = (ushort*)take((size_t)1152 * KP * 2);
    ushort* wl    = (ushort*)take((size_t)1152 * KP * 2);
    ushort* w2h   = (ushort*)take((size_t)640 * KP2 * 2);
    ushort* w2l   = (ushort*)take((size_t)640 * KP2 * 2);
    ushort* wth   = (ushort*)take((size_t)640 * KP2 * 2);
    ushort* wtl   = (ushort*)take((size_t)640 * KP2 * 2);
    float*  G     = (float*)take((size_t)640 * CC * 4);
    ushort* Gh    = (ushort*)take((size_t)640 * KP * 2);
    ushort* Gl    = (ushort*)take((size_t)640 * KP * 2);
    float*  inv   = (float*)take((size_t)M1 * 4);
    float*  qpart = (float*)take((size_t)NQT * M1 * 4);
    float*  simv  = (float*)take((size_t)M1 * 4);
    int*    idxb  = (int*)take((size_t)BB * KT * 4);
    double* gbuf  = (double*)take((size_t)BB * CC * 8);
    double* xcn   = (double*)take((size_t)BB * CC * 8);
    double* t1b   = (double*)take((size_t)BB * EE * 8);
    float*  ck19  = (float*)take((size_t)JC * EE * 4);
    ushort* sh    = (ushort*)take((size_t)M2P * KP * 2);
    ushort* sl    = (ushort*)take((size_t)M2P * KP * 2);
    float*  invsel= (float*)take((size_t)M2P * 4);
    float*  xps   = (float*)take((size_t)M2P * EE * 4);
    ushort* o2h   = (ushort*)take((size_t)M2P * KP2 * 2);
    ushort* o2l   = (ushort*)take((size_t)M2P * KP2 * 2);
    float*  xproc = (float*)take((size_t)M2P * CC * 4);
    (void)ws_size;

    // --- prep ---
    zero_kernel<<<(NQT * M1 + 255) / 256, 256, 0, stream>>>(qpart, NQT * M1);
    winp_kernel<<<(EE * CC + 255) / 256, 256, 0, stream>>>(w_in, norm_w, winp, winpT, EE * CC);
    convw_kernel<<<1152, 256, 0, stream>>>(winp, EE, wh, wl);
    w2conv_kernel<<<640, 256, 0, stream>>>(w_out, w2h, w2l);
    w2conv_kernel<<<640, 256, 0, stream>>>(winpT, wth, wtl);
    taps19_kernel<<<1, 256, 0, stream>>>(Amat, Bp, Cp, conv_w, ck19);
    convx_kernel<<<M1, 256, 0, stream>>>(x, xh, xl, inv);

    // --- G = W'^T W' (split-bf16), triangular-masked (2L+D) for gemmq ---
    dim3 gG(5, 5);
    gemm_mfma<<<gG, 256, 0, stream>>>(wth, wtl, wth, wtl, nullptr, nullptr, G,
                                      CC, CC, CC, KP2, 0);
    convG_kernel<<<640, 256, 0, stream>>>(G, Gh, Gl);

    // --- q_r = x_r^T G x_r via masked Ghat (y never materialized) ---
    dim3 gq(NQT, M1 / 128);
    gemm_mfma_q<<<gq, 256, 0, stream>>>(xh, xl, Gh, Gl, x, qpart);

    // --- sim + topk ---
    center_kernel<<<BB, 256, 0, stream>>>(x, xcn);
    dim3 gg1(EE / 4, BB);
    gram1_kernel<<<gg1, 256, 0, stream>>>(winp, xcn, t1b);
    dim3 gg2(CC / 4, BB);
    gram2_kernel<<<gg2, 256, 0, stream>>>(winpT, t1b, gbuf);
    dotsim_kernel<<<M1, 256, 0, stream>>>(x, gbuf, qpart, simv);
    topk_kernel<<<BB, 1024, 0, stream>>>(simv, idxb);

    // --- selected rows only: xproj_sel = inv*(x_sel@W'^T) + b_in ---
    gatherx_kernel<<<M2P, 256, 0, stream>>>(xh, xl, inv, idxb, sh, sl, invsel);
    dim3 g1(9, M2P / 128);
    gemm_mfma<<<g1, 256, 0, stream>>>(sh, sl, wh, wl, invsel, b_in, xps,
                                      EE, M2, EE, KP, 0);

    // --- conv4 ∘ ssm16 = single 19-tap depthwise causal conv ---
    conv19_kernel<<<M2P, 256, 0, stream>>>(xps, ck19, o2h, o2l);

    // --- gemm2 + output assembly ---
    dim3 g3(5, M2P / 128);
    gemm_mfma<<<g3, 256, 0, stream>>>(o2h, o2l, w2h, w2l, nullptr, b_out, xproc,
                                      CC, M2, CC, KP2, 0);

    copy4_kernel<<<2048, 256, 0, stream>>>((const float4*)x, (float4*)out, out_size / 4);
    dim3 g2(KT, BB);
    scatter_kernel<<<g2, 256, 0, stream>>>(xproc, idxb, out);
}

// Round 8
// 464.174 us; speedup vs baseline: 2.6375x; 1.0162x over previous
//
#include <hip/hip_runtime.h>
#include <hip/hip_bf16.h>

// Problem constants (fixed by reference)
#define BB 8
#define LL 4096
#define CC 552      // DIM
#define EE 1104     // EXP
#define KT 409      // top-k
#define M1 32768    // B*L
#define M2 3272     // B*KT
#define KP 576      // K padded (gemm over DIM)
#define KP2 1120    // K padded (gemm over EXP)
#define M2P 3328    // M2 padded to 26*128
#define JT 16       // SSM truncation taps (||A||^16 ~ 2e-13)
#define JC 19       // composed conv4 * ssm16 taps
#define NQT 5       // col tiles in gemmq (640/128)

typedef __attribute__((ext_vector_type(8))) short bf16x8;
typedef __attribute__((ext_vector_type(4))) float f32x4;

__device__ __forceinline__ ushort f2bf(float f) {
    unsigned u = __float_as_uint(f);
    return (ushort)((u + 0x7FFFu + ((u >> 16) & 1u)) >> 16);  // RNE
}
__device__ __forceinline__ float bf2f(ushort h) {
    return __uint_as_float(((unsigned)h) << 16);
}

// async global->LDS, 16B per lane; LDS dest = wave-uniform base + lane*16 [m97/m03]
__device__ __forceinline__ void gl_lds16(const ushort* g, ushort* l) {
    __builtin_amdgcn_global_load_lds(
        (const __attribute__((address_space(1))) void*)g,
        (__attribute__((address_space(3))) void*)l, 16, 0, 0);
}

__global__ void zero_kernel(float* __restrict__ p, int n) {
    int i = blockIdx.x * blockDim.x + threadIdx.x;
    if (i < n) p[i] = 0.f;
}

// ---------- W' = w_in * norm_w (fp32) + transposed copy ----------
__global__ void winp_kernel(const float* __restrict__ w_in, const float* __restrict__ norm_w,
                            float* __restrict__ winp, float* __restrict__ winpT, int n) {
    int i = blockIdx.x * blockDim.x + threadIdx.x;
    if (i < n) {
        int c = i % CC, e = i / CC;
        float v = w_in[i] * norm_w[c];
        winp[i] = v;
        winpT[(size_t)c * EE + e] = v;
    }
}

// ---------- convert x rows -> bf16 hi/lo [M1][KP] + fused 1/(rms+eps) ----------
__global__ __launch_bounds__(256) void convx_kernel(const float* __restrict__ x,
                                                    ushort* __restrict__ xh, ushort* __restrict__ xl,
                                                    float* __restrict__ inv) {
    __shared__ float red[4];
    const int r = blockIdx.x;
    const float* xr = x + (size_t)r * CC;
    ushort* oh = xh + (size_t)r * KP;
    ushort* ol = xl + (size_t)r * KP;
    const int t = threadIdx.x;
    float s = 0.f;
    if (t < 144) {
        float4 v = make_float4(0.f, 0.f, 0.f, 0.f);
        if (t < 138) v = reinterpret_cast<const float4*>(xr)[t];
        s = v.x * v.x + v.y * v.y + v.z * v.z + v.w * v.w;
        ushort4 h, l;
        h.x = f2bf(v.x); l.x = f2bf(v.x - bf2f(h.x));
        h.y = f2bf(v.y); l.y = f2bf(v.y - bf2f(h.y));
        h.z = f2bf(v.z); l.z = f2bf(v.z - bf2f(h.z));
        h.w = f2bf(v.w); l.w = f2bf(v.w - bf2f(h.w));
        reinterpret_cast<ushort4*>(oh)[t] = h;
        reinterpret_cast<ushort4*>(ol)[t] = l;
    }
#pragma unroll
    for (int o = 32; o > 0; o >>= 1) s += __shfl_down(s, o, 64);
    if ((t & 63) == 0) red[t >> 6] = s;
    __syncthreads();
    if (t == 0) {
        float tot = red[0] + red[1] + red[2] + red[3];
        inv[r] = 1.f / (sqrtf(tot / (float)CC) + 1e-6f);
    }
}

// ---------- convert [*][CC] fp32 rows -> bf16 hi/lo [grid][KP]; rows >= nvalid zeroed ----------
__global__ __launch_bounds__(256) void convw_kernel(const float* __restrict__ src, int nvalid,
                                                    ushort* __restrict__ wh, ushort* __restrict__ wl) {
    const int n = blockIdx.x, t = threadIdx.x;
    if (t >= 144) return;
    float4 v = make_float4(0.f, 0.f, 0.f, 0.f);
    if (n < nvalid && t < 138) v = reinterpret_cast<const float4*>(src + (size_t)n * CC)[t];
    ushort4 h, l;
    h.x = f2bf(v.x); l.x = f2bf(v.x - bf2f(h.x));
    h.y = f2bf(v.y); l.y = f2bf(v.y - bf2f(h.y));
    h.z = f2bf(v.z); l.z = f2bf(v.z - bf2f(h.z));
    h.w = f2bf(v.w); l.w = f2bf(v.w - bf2f(h.w));
    reinterpret_cast<ushort4*>(wh + (size_t)n * KP)[t] = h;
    reinterpret_cast<ushort4*>(wl + (size_t)n * KP)[t] = l;
}

// ---------- triangular-masked conversion of G: Ghat[n][k] = G[n][k]*(n>k?2:n==k?1:0) ----------
__global__ __launch_bounds__(256) void convG_kernel(const float* __restrict__ G,
                                                    ushort* __restrict__ gh, ushort* __restrict__ gl) {
    const int n = blockIdx.x, t = threadIdx.x;
    if (t >= 144) return;
    float4 v = make_float4(0.f, 0.f, 0.f, 0.f);
    if (n < CC && t < 138) {
        v = reinterpret_cast<const float4*>(G + (size_t)n * CC)[t];
        const int k0 = t * 4;
        float m0 = (n > k0 + 0) ? 2.f : (n == k0 + 0) ? 1.f : 0.f;
        float m1 = (n > k0 + 1) ? 2.f : (n == k0 + 1) ? 1.f : 0.f;
        float m2 = (n > k0 + 2) ? 2.f : (n == k0 + 2) ? 1.f : 0.f;
        float m3 = (n > k0 + 3) ? 2.f : (n == k0 + 3) ? 1.f : 0.f;
        v = make_float4(v.x * m0, v.y * m1, v.z * m2, v.w * m3);
    }
    ushort4 h, l;
    h.x = f2bf(v.x); l.x = f2bf(v.x - bf2f(h.x));
    h.y = f2bf(v.y); l.y = f2bf(v.y - bf2f(h.y));
    h.z = f2bf(v.z); l.z = f2bf(v.z - bf2f(h.z));
    h.w = f2bf(v.w); l.w = f2bf(v.w - bf2f(h.w));
    reinterpret_cast<ushort4*>(gh + (size_t)n * KP)[t] = h;
    reinterpret_cast<ushort4*>(gl + (size_t)n * KP)[t] = l;
}

// ---------- convert [*][EE] fp32 rows -> bf16 hi/lo [grid][KP2]; rows >= CC zeroed ----------
__global__ __launch_bounds__(256) void w2conv_kernel(const float* __restrict__ src,
                                                     ushort* __restrict__ wh, ushort* __restrict__ wl) {
    const int n = blockIdx.x, t = threadIdx.x;
    for (int i = t; i < KP2 / 4; i += 256) {
        float4 v = make_float4(0.f, 0.f, 0.f, 0.f);
        if (n < CC && i < EE / 4) v = reinterpret_cast<const float4*>(src + (size_t)n * EE)[i];
        ushort4 h, l;
        h.x = f2bf(v.x); l.x = f2bf(v.x - bf2f(h.x));
        h.y = f2bf(v.y); l.y = f2bf(v.y - bf2f(h.y));
        h.z = f2bf(v.z); l.z = f2bf(v.z - bf2f(h.z));
        h.w = f2bf(v.w); l.w = f2bf(v.w - bf2f(h.w));
        reinterpret_cast<ushort4*>(wh + (size_t)n * KP2)[i] = h;
        reinterpret_cast<ushort4*>(wl + (size_t)n * KP2)[i] = l;
    }
}

// ---------- unified split-bf16 MFMA GEMM with global_load_lds staging ----------
// C = rowscale[m]*(A@B^T) + bias[n]; operands pre-padded (128-row / 32-K multiples).
__global__ __launch_bounds__(256) void gemm_mfma(
    const ushort* __restrict__ Ah, const ushort* __restrict__ Al,   // [Mp][Kp]
    const ushort* __restrict__ Bh, const ushort* __restrict__ Bl,   // [Np][Kp]
    const float* __restrict__ rowscale, const float* __restrict__ bias,
    float* __restrict__ C, int ldc, int M, int N, int Kp, int r0) {
    __shared__ ushort As_h[128][32];
    __shared__ ushort As_l[128][32];
    __shared__ ushort Bs_h[128][32];
    __shared__ ushort Bs_l[128][32];
    const int tid = threadIdx.x;
    const int col0 = blockIdx.x * 128;
    const int row0 = blockIdx.y * 128;
    const int wave = tid >> 6, lane = tid & 63;
    const int wr = (wave >> 1) * 64, wc = (wave & 1) * 64;
    const int lrow = lane & 15, kb = (lane >> 4) * 8;

    // staging: wave w covers rows [w*32, w*32+32) of each tile; lane -> (row=l>>2, 16B chunk=l&3)
    const int s0 = wave * 32 + (lane >> 2);
    const int skh = (lane & 3) * 8;
    const ushort* gAh0 = Ah + (size_t)(row0 + s0) * Kp + skh;
    const ushort* gAl0 = Al + (size_t)(row0 + s0) * Kp + skh;
    const ushort* gBh0 = Bh + (size_t)(col0 + s0) * Kp + skh;
    const ushort* gBl0 = Bl + (size_t)(col0 + s0) * Kp + skh;
    const size_t rstep = (size_t)16 * Kp;
    ushort* lAh0 = &As_h[wave * 32][0];      ushort* lAh1 = &As_h[wave * 32 + 16][0];
    ushort* lAl0 = &As_l[wave * 32][0];      ushort* lAl1 = &As_l[wave * 32 + 16][0];
    ushort* lBh0 = &Bs_h[wave * 32][0];      ushort* lBh1 = &Bs_h[wave * 32 + 16][0];
    ushort* lBl0 = &Bs_l[wave * 32][0];      ushort* lBl1 = &Bs_l[wave * 32 + 16][0];

    f32x4 acc[4][4];
    const f32x4 zero = {0.f, 0.f, 0.f, 0.f};
#pragma unroll
    for (int i = 0; i < 4; i++)
#pragma unroll
        for (int j = 0; j < 4; j++) acc[i][j] = zero;

    for (int k0 = 0; k0 < Kp; k0 += 32) {
        __syncthreads();  // all waves done reading previous tile
        gl_lds16(gAh0 + k0, lAh0); gl_lds16(gAh0 + rstep + k0, lAh1);
        gl_lds16(gAl0 + k0, lAl0); gl_lds16(gAl0 + rstep + k0, lAl1);
        gl_lds16(gBh0 + k0, lBh0); gl_lds16(gBh0 + rstep + k0, lBh1);
        gl_lds16(gBl0 + k0, lBl0); gl_lds16(gBl0 + rstep + k0, lBl1);
        __syncthreads();  // vmcnt drained before barrier -> LDS tile ready
        bf16x8 ah[4], al[4], bh[4], bl[4];
#pragma unroll
        for (int i = 0; i < 4; i++) {
            ah[i] = *reinterpret_cast<const bf16x8*>(&As_h[wr + i * 16 + lrow][kb]);
            al[i] = *reinterpret_cast<const bf16x8*>(&As_l[wr + i * 16 + lrow][kb]);
            bh[i] = *reinterpret_cast<const bf16x8*>(&Bs_h[wc + i * 16 + lrow][kb]);
            bl[i] = *reinterpret_cast<const bf16x8*>(&Bs_l[wc + i * 16 + lrow][kb]);
        }
#pragma unroll
        for (int i = 0; i < 4; i++)
#pragma unroll
            for (int j = 0; j < 4; j++) {
                acc[i][j] = __builtin_amdgcn_mfma_f32_16x16x32_bf16(ah[i], bh[j], acc[i][j], 0, 0, 0);
                acc[i][j] = __builtin_amdgcn_mfma_f32_16x16x32_bf16(ah[i], bl[j], acc[i][j], 0, 0, 0);
                acc[i][j] = __builtin_amdgcn_mfma_f32_16x16x32_bf16(al[i], bh[j], acc[i][j], 0, 0, 0);
            }
    }
    // epilogue: C/D layout col=lane&15, row=(lane>>4)*4+reg  [m89-verified]
#pragma unroll
    for (int i = 0; i < 4; i++) {
        const int gmb = r0 + row0 + wr + i * 16 + (lane >> 4) * 4;
#pragma unroll
        for (int reg = 0; reg < 4; reg++) {
            const int gm = gmb + reg;
            if (gm < M) {
                const float rs = rowscale ? rowscale[gm] : 1.f;
#pragma unroll
                for (int j = 0; j < 4; j++) {
                    const int gn = col0 + wc + j * 16 + lrow;
                    if (gn < N) C[(size_t)gm * ldc + gn] = acc[i][j][reg] * rs + (bias ? bias[gn] : 0.f);
                }
            }
        }
    }
}

// ---------- gemmq: y = x@Ghat with fused q_m = sum_n y[m,n]*x[m,n]; y never stored ----------
// Ghat triangular-masked (2L+D): K-loop ends at col0+128.
__global__ __launch_bounds__(256) void gemm_mfma_q(
    const ushort* __restrict__ Ah, const ushort* __restrict__ Al,   // x hi/lo [M1][KP]
    const ushort* __restrict__ Bh, const ushort* __restrict__ Bl,   // Ghat hi/lo [640][KP]
    const float* __restrict__ xsrc, float* __restrict__ qpart) {
    __shared__ ushort As_h[128][32];
    __shared__ ushort As_l[128][32];
    __shared__ ushort Bs_h[128][32];
    __shared__ ushort Bs_l[128][32];
    const int tid = threadIdx.x;
    const int col0 = blockIdx.x * 128;
    const int row0 = blockIdx.y * 128;
    const int kend = (KP < col0 + 128) ? KP : (col0 + 128);   // triangular cut
    const int wave = tid >> 6, lane = tid & 63;
    const int wr = (wave >> 1) * 64, wc = (wave & 1) * 64;
    const int lrow = lane & 15, kb = (lane >> 4) * 8;

    const int s0 = wave * 32 + (lane >> 2);
    const int skh = (lane & 3) * 8;
    const ushort* gAh0 = Ah + (size_t)(row0 + s0) * KP + skh;
    const ushort* gAl0 = Al + (size_t)(row0 + s0) * KP + skh;
    const ushort* gBh0 = Bh + (size_t)(col0 + s0) * KP + skh;
    const ushort* gBl0 = Bl + (size_t)(col0 + s0) * KP + skh;
    const size_t rstep = (size_t)16 * KP;
    ushort* lAh0 = &As_h[wave * 32][0];      ushort* lAh1 = &As_h[wave * 32 + 16][0];
    ushort* lAl0 = &As_l[wave * 32][0];      ushort* lAl1 = &As_l[wave * 32 + 16][0];
    ushort* lBh0 = &Bs_h[wave * 32][0];      ushort* lBh1 = &Bs_h[wave * 32 + 16][0];
    ushort* lBl0 = &Bs_l[wave * 32][0];      ushort* lBl1 = &Bs_l[wave * 32 + 16][0];

    f32x4 acc[4][4];
    const f32x4 zero = {0.f, 0.f, 0.f, 0.f};
#pragma unroll
    for (int i = 0; i < 4; i++)
#pragma unroll
        for (int j = 0; j < 4; j++) acc[i][j] = zero;

    for (int k0 = 0; k0 < kend; k0 += 32) {
        __syncthreads();
        gl_lds16(gAh0 + k0, lAh0); gl_lds16(gAh0 + rstep + k0, lAh1);
        gl_lds16(gAl0 + k0, lAl0); gl_lds16(gAl0 + rstep + k0, lAl1);
        gl_lds16(gBh0 + k0, lBh0); gl_lds16(gBh0 + rstep + k0, lBh1);
        gl_lds16(gBl0 + k0, lBl0); gl_lds16(gBl0 + rstep + k0, lBl1);
        __syncthreads();
        bf16x8 ah[4], al[4], bh[4], bl[4];
#pragma unroll
        for (int i = 0; i < 4; i++) {
            ah[i] = *reinterpret_cast<const bf16x8*>(&As_h[wr + i * 16 + lrow][kb]);
            al[i] = *reinterpret_cast<const bf16x8*>(&As_l[wr + i * 16 + lrow][kb]);
            bh[i] = *reinterpret_cast<const bf16x8*>(&Bs_h[wc + i * 16 + lrow][kb]);
            bl[i] = *reinterpret_cast<const bf16x8*>(&Bs_l[wc + i * 16 + lrow][kb]);
        }
#pragma unroll
        for (int i = 0; i < 4; i++)
#pragma unroll
            for (int j = 0; j < 4; j++) {
                acc[i][j] = __builtin_amdgcn_mfma_f32_16x16x32_bf16(ah[i], bh[j], acc[i][j], 0, 0, 0);
                acc[i][j] = __builtin_amdgcn_mfma_f32_16x16x32_bf16(ah[i], bl[j], acc[i][j], 0, 0, 0);
                acc[i][j] = __builtin_amdgcn_mfma_f32_16x16x32_bf16(al[i], bh[j], acc[i][j], 0, 0, 0);
            }
    }
    float* qp = qpart + (size_t)blockIdx.x * M1;
#pragma unroll
    for (int i = 0; i < 4; i++) {
#pragma unroll
        for (int reg = 0; reg < 4; reg++) {
            const int gm = row0 + wr + i * 16 + (lane >> 4) * 4 + reg;
            float part = 0.f;
#pragma unroll
            for (int j = 0; j < 4; j++) {
                const int gn = col0 + wc + j * 16 + lrow;
                const float xv = (gn < CC) ? xsrc[(size_t)gm * CC + gn] : 0.f;
                part += acc[i][j][reg] * xv;
            }
#pragma unroll
            for (int o = 1; o < 16; o <<= 1) part += __shfl_xor(part, o, 64);
            if ((lane & 15) == 0) atomicAdd(&qp[gm], part);  // 2 commutative adds/cell: deterministic
        }
    }
}

// ---------- center row -> fp64 normalized (one block per batch) ----------
__global__ __launch_bounds__(256) void center_kernel(const float* __restrict__ x,
                                                     double* __restrict__ xcn) {
    __shared__ double red[4];
    const int b = blockIdx.x, tid = threadIdx.x;
    const float* xc = x + ((size_t)(b * LL + LL / 2)) * CC;
    double s = 0.0;
    for (int c = tid; c < CC; c += 256) { double v = xc[c]; s += v * v; }
#pragma unroll
    for (int o = 32; o > 0; o >>= 1) s += __shfl_down(s, o, 64);
    if ((tid & 63) == 0) red[tid >> 6] = s;
    __syncthreads();
    const double tot = red[0] + red[1] + red[2] + red[3];
    const double invc = 1.0 / (sqrt(tot / (double)CC) + 1e-6);
    for (int c = tid; c < CC; c += 256) xcn[(size_t)b * CC + c] = (double)xc[c] * invc;
}

// ---------- t1[b][e] = <W'_e, xcn_b>, one wave per (b,e) ----------
__global__ __launch_bounds__(256) void gram1_kernel(const float* __restrict__ winp,
                                                    const double* __restrict__ xcn,
                                                    double* __restrict__ t1) {
    const int b = blockIdx.y;
    const int wave = threadIdx.x >> 6, lane = threadIdx.x & 63;
    const int e = blockIdx.x * 4 + wave;
    const float* wr = winp + (size_t)e * CC;
    const double* xb = xcn + (size_t)b * CC;
    double s = 0.0;
    for (int c = lane; c < CC; c += 64) s += (double)wr[c] * xb[c];
#pragma unroll
    for (int o = 32; o > 0; o >>= 1) s += __shfl_down(s, o, 64);
    if (lane == 0) t1[(size_t)b * EE + e] = s;
}

// ---------- g[b][c] = <W'T_c, t1_b>, one wave per (b,c) ----------
__global__ __launch_bounds__(256) void gram2_kernel(const float* __restrict__ winpT,
                                                    const double* __restrict__ t1,
                                                    double* __restrict__ g) {
    const int b = blockIdx.y;
    const int wave = threadIdx.x >> 6, lane = threadIdx.x & 63;
    const int c = blockIdx.x * 4 + wave;
    if (c >= CC) return;
    const float* wr = winpT + (size_t)c * EE;
    const double* tb = t1 + (size_t)b * EE;
    double s = 0.0;
    for (int e = lane; e < EE; e += 64) s += (double)wr[e] * tb[e];
#pragma unroll
    for (int o = 32; o > 0; o >>= 1) s += __shfl_down(s, o, 64);
    if (lane == 0) g[(size_t)b * CC + c] = s;
}

// ---------- sim_r = <x_r, g_b> / sqrt(q_r)  (inv_r cancels exactly) ----------
__global__ __launch_bounds__(256) void dotsim_kernel(const float* __restrict__ x,
                                                     const double* __restrict__ g,
                                                     const float* __restrict__ qpart,
                                                     float* __restrict__ sim) {
    __shared__ double redd[4];
    const int r = blockIdx.x, tid = threadIdx.x;
    const int b = r >> 12;
    const float* xr = x + (size_t)r * CC;
    const double* gb = g + (size_t)b * CC;
    double d = 0.0;
    for (int i = tid; i < 138; i += 256) {
        float4 xv = reinterpret_cast<const float4*>(xr)[i];
        const double* gp = gb + i * 4;
        d += (double)xv.x * gp[0] + (double)xv.y * gp[1] + (double)xv.z * gp[2] + (double)xv.w * gp[3];
    }
#pragma unroll
    for (int o = 32; o > 0; o >>= 1) d += __shfl_down(d, o, 64);
    if ((tid & 63) == 0) redd[tid >> 6] = d;
    __syncthreads();
    if (tid == 0) {
        double dt = redd[0] + redd[1] + redd[2] + redd[3];
        double q = 0.0;
#pragma unroll
        for (int t5 = 0; t5 < NQT; t5++) q += (double)qpart[(size_t)t5 * M1 + r];
        sim[r] = (float)(dt / sqrt(fmax(q, 1e-30)));
    }
}

// ---------------- top-k via full bitonic sort of (value desc, idx asc) keys ----------------
__global__ __launch_bounds__(1024) void topk_kernel(const float* __restrict__ sim,
                                                    int* __restrict__ idx) {
    __shared__ unsigned long long keys[4096];
    const int b = blockIdx.x;
    for (int i = threadIdx.x; i < 4096; i += 1024) {
        unsigned u = __float_as_uint(sim[b * 4096 + i]);
        u = (u & 0x80000000u) ? ~u : (u | 0x80000000u);
        keys[i] = ((unsigned long long)(~u) << 32) | (unsigned)i;
    }
    __syncthreads();
    for (int size = 2; size <= 4096; size <<= 1) {
        for (int stride = size >> 1; stride > 0; stride >>= 1) {
#pragma unroll 1
            for (int t = threadIdx.x; t < 2048; t += 1024) {
                int low = t & (stride - 1);
                int pos = ((t - low) << 1) + low;
                bool up = ((pos & size) == 0);
                unsigned long long ka = keys[pos], kb = keys[pos + stride];
                if ((ka > kb) == up) { keys[pos] = kb; keys[pos + stride] = ka; }
            }
            __syncthreads();
        }
    }
    for (int t = threadIdx.x; t < KT; t += 1024) idx[b * KT + t] = (int)(keys[t] & 0xffffffffu);
}

// ---------- gather selected x rows (hi/lo) + inv; rows >= M2 zeroed ----------
__global__ __launch_bounds__(256) void gatherx_kernel(const ushort* __restrict__ xh,
                                                      const ushort* __restrict__ xl,
                                                      const float* __restrict__ inv,
                                                      const int* __restrict__ idx,
                                                      ushort* __restrict__ sh,
                                                      ushort* __restrict__ sl,
                                                      float* __restrict__ invsel) {
    const int r = blockIdx.x, t = threadIdx.x;
    if (r >= M2) {
        if (t < 144) {
            reinterpret_cast<ushort4*>(sh + (size_t)r * KP)[t] = make_ushort4(0, 0, 0, 0);
            reinterpret_cast<ushort4*>(sl + (size_t)r * KP)[t] = make_ushort4(0, 0, 0, 0);
        }
        return;
    }
    const int b = r / KT;
    const int src = b * LL + idx[r];
    if (t < 144) {
        reinterpret_cast<ushort4*>(sh + (size_t)r * KP)[t] =
            reinterpret_cast<const ushort4*>(xh + (size_t)src * KP)[t];
        reinterpret_cast<ushort4*>(sl + (size_t)r * KP)[t] =
            reinterpret_cast<const ushort4*>(xl + (size_t)src * KP)[t];
    }
    if (t == 0) invsel[r] = inv[src];
}

// ---------- composed taps: K19[m][e] = sum_i conv_w'[e][i] * (sigC[e].A^(m-i).sigB) ----------
__global__ __launch_bounds__(256) void taps19_kernel(const float* __restrict__ A,
                                                     const float* __restrict__ Bp,
                                                     const float* __restrict__ Cp,
                                                     const float* __restrict__ conv_w,
                                                     float* __restrict__ ck19) {
    __shared__ float Ash[256];
    __shared__ float vmat[JT][16];
    const int t = threadIdx.x;
    Ash[t] = A[t];
    __syncthreads();
    if (t < 16) vmat[0][t] = 1.f / (1.f + expf(-Bp[t]));
    __syncthreads();
    for (int j = 1; j < JT; j++) {
        float nv = 0.f;
        if (t < 16) {
#pragma unroll
            for (int s2 = 0; s2 < 16; s2++) nv += Ash[t * 16 + s2] * vmat[j - 1][s2];
        }
        __syncthreads();
        if (t < 16) vmat[j][t] = nv;
        __syncthreads();
    }
    for (int e = t; e < EE; e += 256) {
        float sc[16];
#pragma unroll
        for (int s = 0; s < 16; s++) sc[s] = 1.f / (1.f + expf(-Cp[e * 16 + s]));
        float ck[JT];
#pragma unroll
        for (int j = 0; j < JT; j++) {
            float kk = 0.f;
#pragma unroll
            for (int s = 0; s < 16; s++) kk += sc[s] * vmat[j][s];
            ck[j] = kk;
        }
        float w4[4];
#pragma unroll
        for (int i = 0; i < 4; i++) w4[i] = conv_w[e * 4 + 3 - i];
#pragma unroll
        for (int m = 0; m < JC; m++) {
            float kk = 0.f;
#pragma unroll
            for (int i = 0; i < 4; i++) {
                int jm = m - i;
                if (jm >= 0 && jm < JT) kk += w4[i] * ck[jm];
            }
            ck19[m * EE + e] = kk;
        }
    }
}

// ---------- 19-tap causal depthwise conv on selected rows -> bf16 hi/lo for GEMM2 ----------
__global__ __launch_bounds__(256) void conv19_kernel(const float* __restrict__ xps,
                                                     const float* __restrict__ ck19,
                                                     ushort* __restrict__ oh,
                                                     ushort* __restrict__ ol) {
    const int r = blockIdx.x, t = threadIdx.x;
    ushort* ph = oh + (size_t)r * KP2;
    ushort* pl = ol + (size_t)r * KP2;
    if (r >= M2) {
        for (int e = t; e < KP2; e += 256) { ph[e] = 0; pl[e] = 0; }
        return;
    }
    const int b = r / KT, tt = r - b * KT;
    const int jmax = (tt < JC - 1) ? tt : (JC - 1);
    const float* base = xps + (size_t)r * EE;
    for (int e = t; e < KP2; e += 256) {
        float y = 0.f;
        if (e < EE) {
            const float* bp = base + e;
            for (int j = 0; j <= jmax; j++) y += ck19[j * EE + e] * bp[-(ptrdiff_t)j * EE];
        }
        ushort h = f2bf(y);
        ph[e] = h;
        pl[e] = f2bf(y - bf2f(h));
    }
}

// ---------------- out = x (copy), then scatter-add x_proc rows ----------------
__global__ void copy4_kernel(const float4* __restrict__ src, float4* __restrict__ dst, int n4) {
    int i = blockIdx.x * blockDim.x + threadIdx.x;
    int stride = gridDim.x * blockDim.x;
    for (; i < n4; i += stride) dst[i] = src[i];
}

__global__ __launch_bounds__(256) void scatter_kernel(const float* __restrict__ xproc,
                                                      const int* __restrict__ idx,
                                                      float* __restrict__ out) {
    int t = blockIdx.x, b = blockIdx.y;
    int row = idx[b * KT + t];
    const float* src = xproc + ((size_t)(b * KT + t)) * CC;
    float* dst = out + ((size_t)(b * LL + row)) * CC;
    for (int d = threadIdx.x; d < CC; d += 256) dst[d] += src[d];
}

extern "C" void kernel_launch(void* const* d_in, const int* in_sizes, int n_in,
                              void* d_out, int out_size, void* d_ws, size_t ws_size,
                              hipStream_t stream) {
    const float* x      = (const float*)d_in[0];
    const float* norm_w = (const float*)d_in[1];
    const float* w_in   = (const float*)d_in[2];
    const float* b_in   = (const float*)d_in[3];
    const float* w_out  = (const float*)d_in[4];
    const float* b_out  = (const float*)d_in[5];
    const float* Amat   = (const float*)d_in[6];
    const float* Bp     = (const float*)d_in[7];
    const float* Cp     = (const float*)d_in[8];
    const float* conv_w = (const float*)d_in[9];
    float* out = (float*)d_out;

    char* wsb = (char*)d_ws;
    size_t off = 0;
    auto take = [&](size_t bytes) {
        void* p = wsb + off;
        off += (bytes + 255) & ~(size_t)255;
        return p;
    };
    ushort* xh    = (ushort*)take((size_t)M1 * KP * 2);       // 37.7 MB
    ushort* xl    = (ushort*)take((size_t)M1 * KP * 2);       // 37.7 MB
    float*  winp  = (float*)take((size_t)EE * CC * 4);
    float*  winpT = (float*)take((size_t)EE * CC * 4);
    ushort* wh    = (ushort*)take((size_t)1152 * KP * 2);
    ushort* wl    = (ushort*)take((size_t)1152 * KP * 2);
    ushort* w2h   = (ushort*)take((size_t)640 * KP2 * 2);
    ushort* w2l   = (ushort*)take((size_t)640 * KP2 * 2);
    ushort* wth   = (ushort*)take((size_t)640 * KP2 * 2);
    ushort* wtl   = (ushort*)take((size_t)640 * KP2 * 2);
    float*  G     = (float*)take((size_t)640 * CC * 4);
    ushort* Gh    = (ushort*)take((size_t)640 * KP * 2);
    ushort* Gl    = (ushort*)take((size_t)640 * KP * 2);
    float*  inv   = (float*)take((size_t)M1 * 4);
    float*  qpart = (float*)take((size_t)NQT * M1 * 4);
    float*  simv  = (float*)take((size_t)M1 * 4);
    int*    idxb  = (int*)take((size_t)BB * KT * 4);
    double* gbuf  = (double*)take((size_t)BB * CC * 8);
    double* xcn   = (double*)take((size_t)BB * CC * 8);
    double* t1b   = (double*)take((size_t)BB * EE * 8);
    float*  ck19  = (float*)take((size_t)JC * EE * 4);
    ushort* sh    = (ushort*)take((size_t)M2P * KP * 2);
    ushort* sl    = (ushort*)take((size_t)M2P * KP * 2);
    float*  invsel= (float*)take((size_t)M2P * 4);
    float*  xps   = (float*)take((size_t)M2P * EE * 4);
    ushort* o2h   = (ushort*)take((size_t)M2P * KP2 * 2);
    ushort* o2l   = (ushort*)take((size_t)M2P * KP2 * 2);
    float*  xproc = (float*)take((size_t)M2P * CC * 4);
    (void)ws_size;

    // --- prep ---
    zero_kernel<<<(NQT * M1 + 255) / 256, 256, 0, stream>>>(qpart, NQT * M1);
    winp_kernel<<<(EE * CC + 255) / 256, 256, 0, stream>>>(w_in, norm_w, winp, winpT, EE * CC);
    convw_kernel<<<1152, 256, 0, stream>>>(winp, EE, wh, wl);
    w2conv_kernel<<<640, 256, 0, stream>>>(w_out, w2h, w2l);
    w2conv_kernel<<<640, 256, 0, stream>>>(winpT, wth, wtl);
    taps19_kernel<<<1, 256, 0, stream>>>(Amat, Bp, Cp, conv_w, ck19);
    convx_kernel<<<M1, 256, 0, stream>>>(x, xh, xl, inv);

    // --- G = W'^T W' (split-bf16), triangular-masked (2L+D) for gemmq ---
    dim3 gG(5, 5);
    gemm_mfma<<<gG, 256, 0, stream>>>(wth, wtl, wth, wtl, nullptr, nullptr, G,
                                      CC, CC, CC, KP2, 0);
    convG_kernel<<<640, 256, 0, stream>>>(G, Gh, Gl);

    // --- q_r = x_r^T G x_r via masked Ghat (y never materialized) ---
    dim3 gq(NQT, M1 / 128);
    gemm_mfma_q<<<gq, 256, 0, stream>>>(xh, xl, Gh, Gl, x, qpart);

    // --- sim + topk ---
    center_kernel<<<BB, 256, 0, stream>>>(x, xcn);
    dim3 gg1(EE / 4, BB);
    gram1_kernel<<<gg1, 256, 0, stream>>>(winp, xcn, t1b);
    dim3 gg2(CC / 4, BB);
    gram2_kernel<<<gg2, 256, 0, stream>>>(winpT, t1b, gbuf);
    dotsim_kernel<<<M1, 256, 0, stream>>>(x, gbuf, qpart, simv);
    topk_kernel<<<BB, 1024, 0, stream>>>(simv, idxb);

    // --- selected rows only: xproj_sel = inv*(x_sel@W'^T) + b_in ---
    gatherx_kernel<<<M2P, 256, 0, stream>>>(xh, xl, inv, idxb, sh, sl, invsel);
    dim3 g1(9, M2P / 128);
    gemm_mfma<<<g1, 256, 0, stream>>>(sh, sl, wh, wl, invsel, b_in, xps,
                                      EE, M2, EE, KP, 0);

    // --- conv4 ∘ ssm16 = single 19-tap depthwise causal conv ---
    conv19_kernel<<<M2P, 256, 0, stream>>>(xps, ck19, o2h, o2l);

    // --- gemm2 + output assembly ---
    dim3 g3(5, M2P / 128);
    gemm_mfma<<<g3, 256, 0, stream>>>(o2h, o2l, w2h, w2l, nullptr, b_out, xproc,
                                      CC, M2, CC, KP2, 0);

    copy4_kernel<<<2048, 256, 0, stream>>>((const float4*)x, (float4*)out, out_size / 4);
    dim3 g2(KT, BB);
    scatter_kernel<<<g2, 256, 0, stream>>>(xproc, idxb, out);
}

// Round 9
// 455.480 us; speedup vs baseline: 2.6878x; 1.0191x over previous
//
#include <hip/hip_runtime.h>
#include <hip/hip_bf16.h>

// Problem constants (fixed by reference)
#define BB 8
#define LL 4096
#define CC 552      // DIM
#define EE 1104     // EXP
#define KT 409      // top-k
#define M1 32768    // B*L
#define M2 3272     // B*KT
#define KP 576      // K padded (gemm over DIM)
#define KP2 1120    // K padded (gemm over EXP)
#define M2P 3328    // M2 padded to 26*128
#define JT 16       // SSM truncation taps (||A||^16 ~ 2e-13)
#define JC 19       // composed conv4 * ssm16 taps
#define NQT 5       // col tiles in gemmq (640/128)

typedef __attribute__((ext_vector_type(8))) short bf16x8;
typedef __attribute__((ext_vector_type(4))) float f32x4;

__device__ __forceinline__ ushort f2bf(float f) {
    unsigned u = __float_as_uint(f);
    return (ushort)((u + 0x7FFFu + ((u >> 16) & 1u)) >> 16);  // RNE
}
__device__ __forceinline__ float bf2f(ushort h) {
    return __uint_as_float(((unsigned)h) << 16);
}

// async global->LDS, 16B per lane; LDS dest = wave-uniform base + lane*16 [m97/m03]
__device__ __forceinline__ void gl_lds16(const ushort* g, ushort* l) {
    __builtin_amdgcn_global_load_lds(
        (const __attribute__((address_space(1))) void*)g,
        (__attribute__((address_space(3))) void*)l, 16, 0, 0);
}

__global__ void zero_kernel(float* __restrict__ p, int n) {
    int i = blockIdx.x * blockDim.x + threadIdx.x;
    if (i < n) p[i] = 0.f;
}

__global__ void posinit_kernel(int* __restrict__ p, int n) {
    int i = blockIdx.x * blockDim.x + threadIdx.x;
    if (i < n) p[i] = -1;
}

// ---------- W' = w_in * norm_w (fp32) + transposed copy ----------
__global__ void winp_kernel(const float* __restrict__ w_in, const float* __restrict__ norm_w,
                            float* __restrict__ winp, float* __restrict__ winpT, int n) {
    int i = blockIdx.x * blockDim.x + threadIdx.x;
    if (i < n) {
        int c = i % CC, e = i / CC;
        float v = w_in[i] * norm_w[c];
        winp[i] = v;
        winpT[(size_t)c * EE + e] = v;
    }
}

// ---------- convx: wave-per-row; bf16 hi/lo + inv + fp64 dval = <x_r, g_b> ----------
__global__ __launch_bounds__(256) void convx_kernel(const float* __restrict__ x,
                                                    const double* __restrict__ gbuf,
                                                    ushort* __restrict__ xh, ushort* __restrict__ xl,
                                                    float* __restrict__ inv,
                                                    double* __restrict__ dval) {
    const int wave = threadIdx.x >> 6, lane = threadIdx.x & 63;
    const int r = blockIdx.x * 4 + wave;
    const int b = r >> 12;
    const float* xr = x + (size_t)r * CC;
    const double* gb = gbuf + (size_t)b * CC;
    ushort* oh = xh + (size_t)r * KP;
    ushort* ol = xl + (size_t)r * KP;
    float ss = 0.f;
    double d = 0.0;
#pragma unroll
    for (int k = 0; k < 3; k++) {
        const int c = lane + k * 64;
        if (c < 144) {
            float4 v = make_float4(0.f, 0.f, 0.f, 0.f);
            if (c < 138) {
                v = reinterpret_cast<const float4*>(xr)[c];
                ss += v.x * v.x + v.y * v.y + v.z * v.z + v.w * v.w;
                const double* gp = gb + c * 4;
                d += (double)v.x * gp[0] + (double)v.y * gp[1] +
                     (double)v.z * gp[2] + (double)v.w * gp[3];
            }
            ushort4 h, l;
            h.x = f2bf(v.x); l.x = f2bf(v.x - bf2f(h.x));
            h.y = f2bf(v.y); l.y = f2bf(v.y - bf2f(h.y));
            h.z = f2bf(v.z); l.z = f2bf(v.z - bf2f(h.z));
            h.w = f2bf(v.w); l.w = f2bf(v.w - bf2f(h.w));
            reinterpret_cast<ushort4*>(oh)[c] = h;
            reinterpret_cast<ushort4*>(ol)[c] = l;
        }
    }
#pragma unroll
    for (int o = 32; o > 0; o >>= 1) { ss += __shfl_down(ss, o, 64); d += __shfl_down(d, o, 64); }
    if (lane == 0) {
        inv[r] = 1.f / (sqrtf(ss / (float)CC) + 1e-6f);
        dval[r] = d;
    }
}

// ---------- convert [*][CC] fp32 rows -> bf16 hi/lo [grid][KP]; rows >= nvalid zeroed ----------
__global__ __launch_bounds__(256) void convw_kernel(const float* __restrict__ src, int nvalid,
                                                    ushort* __restrict__ wh, ushort* __restrict__ wl) {
    const int n = blockIdx.x, t = threadIdx.x;
    if (t >= 144) return;
    float4 v = make_float4(0.f, 0.f, 0.f, 0.f);
    if (n < nvalid && t < 138) v = reinterpret_cast<const float4*>(src + (size_t)n * CC)[t];
    ushort4 h, l;
    h.x = f2bf(v.x); l.x = f2bf(v.x - bf2f(h.x));
    h.y = f2bf(v.y); l.y = f2bf(v.y - bf2f(h.y));
    h.z = f2bf(v.z); l.z = f2bf(v.z - bf2f(h.z));
    h.w = f2bf(v.w); l.w = f2bf(v.w - bf2f(h.w));
    reinterpret_cast<ushort4*>(wh + (size_t)n * KP)[t] = h;
    reinterpret_cast<ushort4*>(wl + (size_t)n * KP)[t] = l;
}

// ---------- triangular-masked conversion of G: Ghat[n][k] = G[n][k]*(n>k?2:n==k?1:0) ----------
__global__ __launch_bounds__(256) void convG_kernel(const float* __restrict__ G,
                                                    ushort* __restrict__ gh, ushort* __restrict__ gl) {
    const int n = blockIdx.x, t = threadIdx.x;
    if (t >= 144) return;
    float4 v = make_float4(0.f, 0.f, 0.f, 0.f);
    if (n < CC && t < 138) {
        v = reinterpret_cast<const float4*>(G + (size_t)n * CC)[t];
        const int k0 = t * 4;
        float m0 = (n > k0 + 0) ? 2.f : (n == k0 + 0) ? 1.f : 0.f;
        float m1 = (n > k0 + 1) ? 2.f : (n == k0 + 1) ? 1.f : 0.f;
        float m2 = (n > k0 + 2) ? 2.f : (n == k0 + 2) ? 1.f : 0.f;
        float m3 = (n > k0 + 3) ? 2.f : (n == k0 + 3) ? 1.f : 0.f;
        v = make_float4(v.x * m0, v.y * m1, v.z * m2, v.w * m3);
    }
    ushort4 h, l;
    h.x = f2bf(v.x); l.x = f2bf(v.x - bf2f(h.x));
    h.y = f2bf(v.y); l.y = f2bf(v.y - bf2f(h.y));
    h.z = f2bf(v.z); l.z = f2bf(v.z - bf2f(h.z));
    h.w = f2bf(v.w); l.w = f2bf(v.w - bf2f(h.w));
    reinterpret_cast<ushort4*>(gh + (size_t)n * KP)[t] = h;
    reinterpret_cast<ushort4*>(gl + (size_t)n * KP)[t] = l;
}

// ---------- convert [*][EE] fp32 rows -> bf16 hi/lo [grid][KP2]; rows >= CC zeroed ----------
__global__ __launch_bounds__(256) void w2conv_kernel(const float* __restrict__ src,
                                                     ushort* __restrict__ wh, ushort* __restrict__ wl) {
    const int n = blockIdx.x, t = threadIdx.x;
    for (int i = t; i < KP2 / 4; i += 256) {
        float4 v = make_float4(0.f, 0.f, 0.f, 0.f);
        if (n < CC && i < EE / 4) v = reinterpret_cast<const float4*>(src + (size_t)n * EE)[i];
        ushort4 h, l;
        h.x = f2bf(v.x); l.x = f2bf(v.x - bf2f(h.x));
        h.y = f2bf(v.y); l.y = f2bf(v.y - bf2f(h.y));
        h.z = f2bf(v.z); l.z = f2bf(v.z - bf2f(h.z));
        h.w = f2bf(v.w); l.w = f2bf(v.w - bf2f(h.w));
        reinterpret_cast<ushort4*>(wh + (size_t)n * KP2)[i] = h;
        reinterpret_cast<ushort4*>(wl + (size_t)n * KP2)[i] = l;
    }
}

// ---------- unified split-bf16 MFMA GEMM (128x128, gl_lds staging) ----------
__global__ __launch_bounds__(256) void gemm_mfma(
    const ushort* __restrict__ Ah, const ushort* __restrict__ Al,   // [Mp][Kp]
    const ushort* __restrict__ Bh, const ushort* __restrict__ Bl,   // [Np][Kp]
    const float* __restrict__ rowscale, const float* __restrict__ bias,
    float* __restrict__ C, int ldc, int M, int N, int Kp, int r0) {
    __shared__ ushort As_h[128][32];
    __shared__ ushort As_l[128][32];
    __shared__ ushort Bs_h[128][32];
    __shared__ ushort Bs_l[128][32];
    const int tid = threadIdx.x;
    const int col0 = blockIdx.x * 128;
    const int row0 = blockIdx.y * 128;
    const int wave = tid >> 6, lane = tid & 63;
    const int wr = (wave >> 1) * 64, wc = (wave & 1) * 64;
    const int lrow = lane & 15, kb = (lane >> 4) * 8;

    const int s0 = wave * 32 + (lane >> 2);
    const int skh = (lane & 3) * 8;
    const ushort* gAh0 = Ah + (size_t)(row0 + s0) * Kp + skh;
    const ushort* gAl0 = Al + (size_t)(row0 + s0) * Kp + skh;
    const ushort* gBh0 = Bh + (size_t)(col0 + s0) * Kp + skh;
    const ushort* gBl0 = Bl + (size_t)(col0 + s0) * Kp + skh;
    const size_t rstep = (size_t)16 * Kp;
    ushort* lAh0 = &As_h[wave * 32][0];      ushort* lAh1 = &As_h[wave * 32 + 16][0];
    ushort* lAl0 = &As_l[wave * 32][0];      ushort* lAl1 = &As_l[wave * 32 + 16][0];
    ushort* lBh0 = &Bs_h[wave * 32][0];      ushort* lBh1 = &Bs_h[wave * 32 + 16][0];
    ushort* lBl0 = &Bs_l[wave * 32][0];      ushort* lBl1 = &Bs_l[wave * 32 + 16][0];

    f32x4 acc[4][4];
    const f32x4 zero = {0.f, 0.f, 0.f, 0.f};
#pragma unroll
    for (int i = 0; i < 4; i++)
#pragma unroll
        for (int j = 0; j < 4; j++) acc[i][j] = zero;

    for (int k0 = 0; k0 < Kp; k0 += 32) {
        __syncthreads();
        gl_lds16(gAh0 + k0, lAh0); gl_lds16(gAh0 + rstep + k0, lAh1);
        gl_lds16(gAl0 + k0, lAl0); gl_lds16(gAl0 + rstep + k0, lAl1);
        gl_lds16(gBh0 + k0, lBh0); gl_lds16(gBh0 + rstep + k0, lBh1);
        gl_lds16(gBl0 + k0, lBl0); gl_lds16(gBl0 + rstep + k0, lBl1);
        __syncthreads();
        bf16x8 ah[4], al[4], bh[4], bl[4];
#pragma unroll
        for (int i = 0; i < 4; i++) {
            ah[i] = *reinterpret_cast<const bf16x8*>(&As_h[wr + i * 16 + lrow][kb]);
            al[i] = *reinterpret_cast<const bf16x8*>(&As_l[wr + i * 16 + lrow][kb]);
            bh[i] = *reinterpret_cast<const bf16x8*>(&Bs_h[wc + i * 16 + lrow][kb]);
            bl[i] = *reinterpret_cast<const bf16x8*>(&Bs_l[wc + i * 16 + lrow][kb]);
        }
#pragma unroll
        for (int i = 0; i < 4; i++)
#pragma unroll
            for (int j = 0; j < 4; j++) {
                acc[i][j] = __builtin_amdgcn_mfma_f32_16x16x32_bf16(ah[i], bh[j], acc[i][j], 0, 0, 0);
                acc[i][j] = __builtin_amdgcn_mfma_f32_16x16x32_bf16(ah[i], bl[j], acc[i][j], 0, 0, 0);
                acc[i][j] = __builtin_amdgcn_mfma_f32_16x16x32_bf16(al[i], bh[j], acc[i][j], 0, 0, 0);
            }
    }
#pragma unroll
    for (int i = 0; i < 4; i++) {
        const int gmb = r0 + row0 + wr + i * 16 + (lane >> 4) * 4;
#pragma unroll
        for (int reg = 0; reg < 4; reg++) {
            const int gm = gmb + reg;
            if (gm < M) {
                const float rs = rowscale ? rowscale[gm] : 1.f;
#pragma unroll
                for (int j = 0; j < 4; j++) {
                    const int gn = col0 + wc + j * 16 + lrow;
                    if (gn < N) C[(size_t)gm * ldc + gn] = acc[i][j][reg] * rs + (bias ? bias[gn] : 0.f);
                }
            }
        }
    }
}

// ---------- gemmq: 256x128 tile, 8 waves; y = x@Ghat, fused q; triangular kend ----------
__global__ __launch_bounds__(512) void gemm_mfma_q(
    const ushort* __restrict__ Ah, const ushort* __restrict__ Al,   // x hi/lo [M1][KP]
    const ushort* __restrict__ Bh, const ushort* __restrict__ Bl,   // Ghat hi/lo [640][KP]
    const float* __restrict__ xsrc, float* __restrict__ qpart) {
    __shared__ ushort As_h[256][32];
    __shared__ ushort As_l[256][32];
    __shared__ ushort Bs_h[128][32];
    __shared__ ushort Bs_l[128][32];
    const int tid = threadIdx.x;
    const int col0 = blockIdx.x * 128;
    const int row0 = blockIdx.y * 256;
    const int kend = (KP < col0 + 128) ? KP : (col0 + 128);   // triangular cut
    const int wave = tid >> 6, lane = tid & 63;
    const int wr = (wave >> 1) * 64, wc = (wave & 1) * 64;    // 4x2 wave grid over 256x128
    const int lrow = lane & 15, kb = (lane >> 4) * 8;

    const int s0a = wave * 32 + (lane >> 2);   // A: 8 waves x 32 rows
    const int s0b = wave * 16 + (lane >> 2);   // B: 8 waves x 16 rows
    const int skh = (lane & 3) * 8;
    const ushort* gAh0 = Ah + (size_t)(row0 + s0a) * KP + skh;
    const ushort* gAl0 = Al + (size_t)(row0 + s0a) * KP + skh;
    const ushort* gBh0 = Bh + (size_t)(col0 + s0b) * KP + skh;
    const ushort* gBl0 = Bl + (size_t)(col0 + s0b) * KP + skh;
    const size_t rstep = (size_t)16 * KP;
    ushort* lAh0 = &As_h[wave * 32][0];      ushort* lAh1 = &As_h[wave * 32 + 16][0];
    ushort* lAl0 = &As_l[wave * 32][0];      ushort* lAl1 = &As_l[wave * 32 + 16][0];
    ushort* lBh0 = &Bs_h[wave * 16][0];
    ushort* lBl0 = &Bs_l[wave * 16][0];

    f32x4 acc[4][4];
    const f32x4 zero = {0.f, 0.f, 0.f, 0.f};
#pragma unroll
    for (int i = 0; i < 4; i++)
#pragma unroll
        for (int j = 0; j < 4; j++) acc[i][j] = zero;

    for (int k0 = 0; k0 < kend; k0 += 32) {
        __syncthreads();
        gl_lds16(gAh0 + k0, lAh0); gl_lds16(gAh0 + rstep + k0, lAh1);
        gl_lds16(gAl0 + k0, lAl0); gl_lds16(gAl0 + rstep + k0, lAl1);
        gl_lds16(gBh0 + k0, lBh0);
        gl_lds16(gBl0 + k0, lBl0);
        __syncthreads();
        bf16x8 ah[4], al[4], bh[4], bl[4];
#pragma unroll
        for (int i = 0; i < 4; i++) {
            ah[i] = *reinterpret_cast<const bf16x8*>(&As_h[wr + i * 16 + lrow][kb]);
            al[i] = *reinterpret_cast<const bf16x8*>(&As_l[wr + i * 16 + lrow][kb]);
            bh[i] = *reinterpret_cast<const bf16x8*>(&Bs_h[wc + i * 16 + lrow][kb]);
            bl[i] = *reinterpret_cast<const bf16x8*>(&Bs_l[wc + i * 16 + lrow][kb]);
        }
#pragma unroll
        for (int i = 0; i < 4; i++)
#pragma unroll
            for (int j = 0; j < 4; j++) {
                acc[i][j] = __builtin_amdgcn_mfma_f32_16x16x32_bf16(ah[i], bh[j], acc[i][j], 0, 0, 0);
                acc[i][j] = __builtin_amdgcn_mfma_f32_16x16x32_bf16(ah[i], bl[j], acc[i][j], 0, 0, 0);
                acc[i][j] = __builtin_amdgcn_mfma_f32_16x16x32_bf16(al[i], bh[j], acc[i][j], 0, 0, 0);
            }
    }
    float* qp = qpart + (size_t)blockIdx.x * M1;
#pragma unroll
    for (int i = 0; i < 4; i++) {
#pragma unroll
        for (int reg = 0; reg < 4; reg++) {
            const int gm = row0 + wr + i * 16 + (lane >> 4) * 4 + reg;
            float part = 0.f;
#pragma unroll
            for (int j = 0; j < 4; j++) {
                const int gn = col0 + wc + j * 16 + lrow;
                const float xv = (gn < CC) ? xsrc[(size_t)gm * CC + gn] : 0.f;
                part += acc[i][j][reg] * xv;
            }
#pragma unroll
            for (int o = 1; o < 16; o <<= 1) part += __shfl_xor(part, o, 64);
            if ((lane & 15) == 0) atomicAdd(&qp[gm], part);  // 2 commutative adds/cell: deterministic
        }
    }
}

// ---------- center row -> fp64 normalized (one block per batch) ----------
__global__ __launch_bounds__(256) void center_kernel(const float* __restrict__ x,
                                                     double* __restrict__ xcn) {
    __shared__ double red[4];
    const int b = blockIdx.x, tid = threadIdx.x;
    const float* xc = x + ((size_t)(b * LL + LL / 2)) * CC;
    double s = 0.0;
    for (int c = tid; c < CC; c += 256) { double v = xc[c]; s += v * v; }
#pragma unroll
    for (int o = 32; o > 0; o >>= 1) s += __shfl_down(s, o, 64);
    if ((tid & 63) == 0) red[tid >> 6] = s;
    __syncthreads();
    const double tot = red[0] + red[1] + red[2] + red[3];
    const double invc = 1.0 / (sqrt(tot / (double)CC) + 1e-6);
    for (int c = tid; c < CC; c += 256) xcn[(size_t)b * CC + c] = (double)xc[c] * invc;
}

// ---------- t1[b][e] = <W'_e, xcn_b>, one wave per (b,e) ----------
__global__ __launch_bounds__(256) void gram1_kernel(const float* __restrict__ winp,
                                                    const double* __restrict__ xcn,
                                                    double* __restrict__ t1) {
    const int b = blockIdx.y;
    const int wave = threadIdx.x >> 6, lane = threadIdx.x & 63;
    const int e = blockIdx.x * 4 + wave;
    const float* wr = winp + (size_t)e * CC;
    const double* xb = xcn + (size_t)b * CC;
    double s = 0.0;
    for (int c = lane; c < CC; c += 64) s += (double)wr[c] * xb[c];
#pragma unroll
    for (int o = 32; o > 0; o >>= 1) s += __shfl_down(s, o, 64);
    if (lane == 0) t1[(size_t)b * EE + e] = s;
}

// ---------- g[b][c] = <W'T_c, t1_b>, one wave per (b,c) ----------
__global__ __launch_bounds__(256) void gram2_kernel(const float* __restrict__ winpT,
                                                    const double* __restrict__ t1,
                                                    double* __restrict__ g) {
    const int b = blockIdx.y;
    const int wave = threadIdx.x >> 6, lane = threadIdx.x & 63;
    const int c = blockIdx.x * 4 + wave;
    if (c >= CC) return;
    const float* wr = winpT + (size_t)c * EE;
    const double* tb = t1 + (size_t)b * EE;
    double s = 0.0;
    for (int e = lane; e < EE; e += 64) s += (double)wr[e] * tb[e];
#pragma unroll
    for (int o = 32; o > 0; o >>= 1) s += __shfl_down(s, o, 64);
    if (lane == 0) g[(size_t)b * CC + c] = s;
}

// ---------- top-k; sim computed inline: sim = dval / sqrt(sum qpart) ----------
__global__ __launch_bounds__(1024) void topk_kernel(const double* __restrict__ dval,
                                                    const float* __restrict__ qpart,
                                                    int* __restrict__ idx) {
    __shared__ unsigned long long keys[4096];
    const int b = blockIdx.x;
    for (int i = threadIdx.x; i < 4096; i += 1024) {
        const int r = b * 4096 + i;
        double q = 0.0;
#pragma unroll
        for (int t5 = 0; t5 < NQT; t5++) q += (double)qpart[(size_t)t5 * M1 + r];
        const float sv = (float)(dval[r] / sqrt(fmax(q, 1e-30)));
        unsigned u = __float_as_uint(sv);
        u = (u & 0x80000000u) ? ~u : (u | 0x80000000u);
        keys[i] = ((unsigned long long)(~u) << 32) | (unsigned)i;
    }
    __syncthreads();
    for (int size = 2; size <= 4096; size <<= 1) {
        for (int stride = size >> 1; stride > 0; stride >>= 1) {
#pragma unroll 1
            for (int t = threadIdx.x; t < 2048; t += 1024) {
                int low = t & (stride - 1);
                int pos = ((t - low) << 1) + low;
                bool up = ((pos & size) == 0);
                unsigned long long ka = keys[pos], kb = keys[pos + stride];
                if ((ka > kb) == up) { keys[pos] = kb; keys[pos + stride] = ka; }
            }
            __syncthreads();
        }
    }
    for (int t = threadIdx.x; t < KT; t += 1024) idx[b * KT + t] = (int)(keys[t] & 0xffffffffu);
}

// ---------- gather selected x rows (hi/lo) + inv; rows >= M2 zeroed; pos map ----------
__global__ __launch_bounds__(256) void gatherx_kernel(const ushort* __restrict__ xh,
                                                      const ushort* __restrict__ xl,
                                                      const float* __restrict__ inv,
                                                      const int* __restrict__ idx,
                                                      ushort* __restrict__ sh,
                                                      ushort* __restrict__ sl,
                                                      float* __restrict__ invsel,
                                                      int* __restrict__ pos) {
    const int r = blockIdx.x, t = threadIdx.x;
    if (r >= M2) {
        if (t < 144) {
            reinterpret_cast<ushort4*>(sh + (size_t)r * KP)[t] = make_ushort4(0, 0, 0, 0);
            reinterpret_cast<ushort4*>(sl + (size_t)r * KP)[t] = make_ushort4(0, 0, 0, 0);
        }
        return;
    }
    const int b = r / KT;
    const int src = b * LL + idx[r];
    if (t < 144) {
        reinterpret_cast<ushort4*>(sh + (size_t)r * KP)[t] =
            reinterpret_cast<const ushort4*>(xh + (size_t)src * KP)[t];
        reinterpret_cast<ushort4*>(sl + (size_t)r * KP)[t] =
            reinterpret_cast<const ushort4*>(xl + (size_t)src * KP)[t];
    }
    if (t == 0) {
        invsel[r] = inv[src];
        pos[src] = r;   // reverse map for fused output
    }
}

// ---------- composed taps: K19[m][e] = sum_i conv_w'[e][i] * (sigC[e].A^(m-i).sigB) ----------
__global__ __launch_bounds__(256) void taps19_kernel(const float* __restrict__ A,
                                                     const float* __restrict__ Bp,
                                                     const float* __restrict__ Cp,
                                                     const float* __restrict__ conv_w,
                                                     float* __restrict__ ck19) {
    __shared__ float Ash[256];
    __shared__ float vmat[JT][16];
    const int t = threadIdx.x;
    Ash[t] = A[t];
    __syncthreads();
    if (t < 16) vmat[0][t] = 1.f / (1.f + expf(-Bp[t]));
    __syncthreads();
    for (int j = 1; j < JT; j++) {
        float nv = 0.f;
        if (t < 16) {
#pragma unroll
            for (int s2 = 0; s2 < 16; s2++) nv += Ash[t * 16 + s2] * vmat[j - 1][s2];
        }
        __syncthreads();
        if (t < 16) vmat[j][t] = nv;
        __syncthreads();
    }
    for (int e = t; e < EE; e += 256) {
        float sc[16];
#pragma unroll
        for (int s = 0; s < 16; s++) sc[s] = 1.f / (1.f + expf(-Cp[e * 16 + s]));
        float ck[JT];
#pragma unroll
        for (int j = 0; j < JT; j++) {
            float kk = 0.f;
#pragma unroll
            for (int s = 0; s < 16; s++) kk += sc[s] * vmat[j][s];
            ck[j] = kk;
        }
        float w4[4];
#pragma unroll
        for (int i = 0; i < 4; i++) w4[i] = conv_w[e * 4 + 3 - i];
#pragma unroll
        for (int m = 0; m < JC; m++) {
            float kk = 0.f;
#pragma unroll
            for (int i = 0; i < 4; i++) {
                int jm = m - i;
                if (jm >= 0 && jm < JT) kk += w4[i] * ck[jm];
            }
            ck19[m * EE + e] = kk;
        }
    }
}

// ---------- 19-tap causal depthwise conv on selected rows -> bf16 hi/lo for GEMM2 ----------
__global__ __launch_bounds__(256) void conv19_kernel(const float* __restrict__ xps,
                                                     const float* __restrict__ ck19,
                                                     ushort* __restrict__ oh,
                                                     ushort* __restrict__ ol) {
    const int r = blockIdx.x, t = threadIdx.x;
    ushort* ph = oh + (size_t)r * KP2;
    ushort* pl = ol + (size_t)r * KP2;
    if (r >= M2) {
        for (int e = t; e < KP2; e += 256) { ph[e] = 0; pl[e] = 0; }
        return;
    }
    const int b = r / KT, tt = r - b * KT;
    const int jmax = (tt < JC - 1) ? tt : (JC - 1);
    const float* base = xps + (size_t)r * EE;
    for (int e = t; e < KP2; e += 256) {
        float y = 0.f;
        if (e < EE) {
            const float* bp = base + e;
            for (int j = 0; j <= jmax; j++) y += ck19[j * EE + e] * bp[-(ptrdiff_t)j * EE];
        }
        ushort h = f2bf(y);
        ph[e] = h;
        pl[e] = f2bf(y - bf2f(h));
    }
}

// ---------- fused output: out[r] = x[r] + (pos[r]>=0 ? xproc[pos[r]] : 0), wave-per-row ----------
__global__ __launch_bounds__(256) void outfuse_kernel(const float* __restrict__ x,
                                                      const float* __restrict__ xproc,
                                                      const int* __restrict__ pos,
                                                      float* __restrict__ out) {
    const int wave = threadIdx.x >> 6, lane = threadIdx.x & 63;
    const int r = blockIdx.x * 4 + wave;
    const int p = pos[r];
    const float4* xr = reinterpret_cast<const float4*>(x + (size_t)r * CC);
    float4* orow = reinterpret_cast<float4*>(out + (size_t)r * CC);
    const float4* pr = (p >= 0) ? reinterpret_cast<const float4*>(xproc + (size_t)p * CC) : nullptr;
#pragma unroll
    for (int k = 0; k < 3; k++) {
        const int c = lane + k * 64;
        if (c < 138) {
            float4 v = xr[c];
            if (pr) {
                float4 a = pr[c];
                v = make_float4(v.x + a.x, v.y + a.y, v.z + a.z, v.w + a.w);
            }
            orow[c] = v;
        }
    }
}

extern "C" void kernel_launch(void* const* d_in, const int* in_sizes, int n_in,
                              void* d_out, int out_size, void* d_ws, size_t ws_size,
                              hipStream_t stream) {
    const float* x      = (const float*)d_in[0];
    const float* norm_w = (const float*)d_in[1];
    const float* w_in   = (const float*)d_in[2];
    const float* b_in   = (const float*)d_in[3];
    const float* w_out  = (const float*)d_in[4];
    const float* b_out  = (const float*)d_in[5];
    const float* Amat   = (const float*)d_in[6];
    const float* Bp     = (const float*)d_in[7];
    const float* Cp     = (const float*)d_in[8];
    const float* conv_w = (const float*)d_in[9];
    float* out = (float*)d_out;

    char* wsb = (char*)d_ws;
    size_t off = 0;
    auto take = [&](size_t bytes) {
        void* p = wsb + off;
        off += (bytes + 255) & ~(size_t)255;
        return p;
    };
    ushort* xh    = (ushort*)take((size_t)M1 * KP * 2);       // 37.7 MB
    ushort* xl    = (ushort*)take((size_t)M1 * KP * 2);       // 37.7 MB
    float*  winp  = (float*)take((size_t)EE * CC * 4);
    float*  winpT = (float*)take((size_t)EE * CC * 4);
    ushort* wh    = (ushort*)take((size_t)1152 * KP * 2);
    ushort* wl    = (ushort*)take((size_t)1152 * KP * 2);
    ushort* w2h   = (ushort*)take((size_t)640 * KP2 * 2);
    ushort* w2l   = (ushort*)take((size_t)640 * KP2 * 2);
    ushort* wth   = (ushort*)take((size_t)640 * KP2 * 2);
    ushort* wtl   = (ushort*)take((size_t)640 * KP2 * 2);
    float*  G     = (float*)take((size_t)640 * CC * 4);
    ushort* Gh    = (ushort*)take((size_t)640 * KP * 2);
    ushort* Gl    = (ushort*)take((size_t)640 * KP * 2);
    float*  inv   = (float*)take((size_t)M1 * 4);
    float*  qpart = (float*)take((size_t)NQT * M1 * 4);
    double* dval  = (double*)take((size_t)M1 * 8);
    int*    posm  = (int*)take((size_t)M1 * 4);
    int*    idxb  = (int*)take((size_t)BB * KT * 4);
    double* gbuf  = (double*)take((size_t)BB * CC * 8);
    double* xcn   = (double*)take((size_t)BB * CC * 8);
    double* t1b   = (double*)take((size_t)BB * EE * 8);
    float*  ck19  = (float*)take((size_t)JC * EE * 4);
    ushort* sh    = (ushort*)take((size_t)M2P * KP * 2);
    ushort* sl    = (ushort*)take((size_t)M2P * KP * 2);
    float*  invsel= (float*)take((size_t)M2P * 4);
    float*  xps   = (float*)take((size_t)M2P * EE * 4);
    ushort* o2h   = (ushort*)take((size_t)M2P * KP2 * 2);
    ushort* o2l   = (ushort*)take((size_t)M2P * KP2 * 2);
    float*  xproc = (float*)take((size_t)M2P * CC * 4);
    (void)ws_size;

    // --- prep (order: gram chain first so convx can fuse the d-dot) ---
    zero_kernel<<<(NQT * M1 + 255) / 256, 256, 0, stream>>>(qpart, NQT * M1);
    posinit_kernel<<<(M1 + 255) / 256, 256, 0, stream>>>(posm, M1);
    winp_kernel<<<(EE * CC + 255) / 256, 256, 0, stream>>>(w_in, norm_w, winp, winpT, EE * CC);
    center_kernel<<<BB, 256, 0, stream>>>(x, xcn);
    dim3 gg1(EE / 4, BB);
    gram1_kernel<<<gg1, 256, 0, stream>>>(winp, xcn, t1b);
    dim3 gg2(CC / 4, BB);
    gram2_kernel<<<gg2, 256, 0, stream>>>(winpT, t1b, gbuf);
    convw_kernel<<<1152, 256, 0, stream>>>(winp, EE, wh, wl);
    w2conv_kernel<<<640, 256, 0, stream>>>(w_out, w2h, w2l);
    w2conv_kernel<<<640, 256, 0, stream>>>(winpT, wth, wtl);
    taps19_kernel<<<1, 256, 0, stream>>>(Amat, Bp, Cp, conv_w, ck19);

    // --- convx: bf16 split + inv + fused fp64 numerator dot ---
    convx_kernel<<<M1 / 4, 256, 0, stream>>>(x, gbuf, xh, xl, inv, dval);

    // --- G = W'^T W' (split-bf16), triangular-masked (2L+D) for gemmq ---
    dim3 gG(5, 5);
    gemm_mfma<<<gG, 256, 0, stream>>>(wth, wtl, wth, wtl, nullptr, nullptr, G,
                                      CC, CC, CC, KP2, 0);
    convG_kernel<<<640, 256, 0, stream>>>(G, Gh, Gl);

    // --- q_r = x_r^T G x_r via masked Ghat (256-row tiles, 8 waves) ---
    dim3 gq(NQT, M1 / 256);
    gemm_mfma_q<<<gq, 512, 0, stream>>>(xh, xl, Gh, Gl, x, qpart);

    // --- topk (sim computed inline from dval/qpart) ---
    topk_kernel<<<BB, 1024, 0, stream>>>(dval, qpart, idxb);

    // --- selected rows only: xproj_sel = inv*(x_sel@W'^T) + b_in ---
    gatherx_kernel<<<M2P, 256, 0, stream>>>(xh, xl, inv, idxb, sh, sl, invsel, posm);
    dim3 g1(9, M2P / 128);
    gemm_mfma<<<g1, 256, 0, stream>>>(sh, sl, wh, wl, invsel, b_in, xps,
                                      EE, M2, EE, KP, 0);

    // --- conv4 ∘ ssm16 = single 19-tap depthwise causal conv ---
    conv19_kernel<<<M2P, 256, 0, stream>>>(xps, ck19, o2h, o2l);

    // --- gemm2 ---
    dim3 g3(5, M2P / 128);
    gemm_mfma<<<g3, 256, 0, stream>>>(o2h, o2l, w2h, w2l, nullptr, b_out, xproc,
                                      CC, M2, CC, KP2, 0);

    // --- fused output: out = x (+ xproc on selected rows) ---
    outfuse_kernel<<<M1 / 4, 256, 0, stream>>>(x, xproc, posm, out);
}